// Round 2
// baseline (1608.797 us; speedup 1.0000x reference)
//
#include <hip/hip_runtime.h>
#include <hip/hip_bf16.h>

#define NUSERS 100000
#define NITEMS 50000
#define NN     150001          // total nodes
#define NNZ    3200000         // 2 * NNZ_INTER
#define BATCH  4096
#define DIM    64
#define ND     (NN * DIM)
#define ALPHA  0.25f           // 1/(N_LAYERS+1)
#define INVT   5.0f            // 1/TEMP
#define LAMBDA 0.1f
#define REGC   1.0e-4f
#define SCHUNK 2048
#define SNB    74              // ceil(150001/2048)

__device__ __forceinline__ float wred64(float v) {
  for (int o = 32; o > 0; o >>= 1) v += __shfl_xor(v, o);
  return v;
}

__device__ __forceinline__ float softplusf(float x) {
  // log(1+exp(x))
  return (x > 20.f) ? x : log1pf(__expf(x));
}

// ---------------- zero scratch ----------------
__global__ void k_zero(int* __restrict__ cnt, float* __restrict__ S) {
  int i = blockIdx.x * blockDim.x + threadIdx.x;
  if (i < NN) cnt[i] = 0;
  if (i < 64) S[i] = 0.f;
}

// ---------------- x = concat(user_emb, item_emb); cur = acc = x ----------------
__global__ void k_init(const float* __restrict__ uemb, const float* __restrict__ iemb,
                       float* __restrict__ cur, float* __restrict__ acc) {
  int gid = blockIdx.x * blockDim.x + threadIdx.x;
  if (gid >= ND) return;
  int n = gid >> 6, d = gid & 63;
  float v = (n < NUSERS) ? uemb[gid] : iemb[(n - NUSERS) * DIM + d];
  cur[gid] = v;
  acc[gid] = v;
}

// ---------------- CSR build ----------------
__global__ void k_hist(const int* __restrict__ rows, int* __restrict__ cnt) {
  int e = blockIdx.x * blockDim.x + threadIdx.x;
  if (e < NNZ) atomicAdd(&cnt[rows[e]], 1);
}

__global__ void k_scan1(const int* __restrict__ cnt, int* __restrict__ partial) {
  __shared__ int sm[256];
  int b = blockIdx.x, t = threadIdx.x;
  int base = b * SCHUNK + t * 8;
  int s = 0;
#pragma unroll
  for (int k = 0; k < 8; k++) { int i = base + k; if (i < NN) s += cnt[i]; }
  sm[t] = s; __syncthreads();
  for (int off = 128; off > 0; off >>= 1) { if (t < off) sm[t] += sm[t + off]; __syncthreads(); }
  if (t == 0) partial[b] = sm[0];
}

__global__ void k_scan2(int* __restrict__ partial, int* __restrict__ row_ptr) {
  if (blockIdx.x == 0 && threadIdx.x == 0) {
    int run = 0;
    for (int i = 0; i < SNB; i++) { int v = partial[i]; partial[i] = run; run += v; }
    row_ptr[NN] = run;  // == NNZ
  }
}

__global__ void k_scan3(const int* __restrict__ cnt, const int* __restrict__ partial,
                        int* __restrict__ row_ptr, int* __restrict__ cursor) {
  __shared__ int sm[256];
  int b = blockIdx.x, t = threadIdx.x;
  int base = b * SCHUNK + t * 8;
  int loc[8];
  int s = 0;
#pragma unroll
  for (int k = 0; k < 8; k++) { int i = base + k; int c = (i < NN) ? cnt[i] : 0; loc[k] = c; s += c; }
  sm[t] = s; __syncthreads();
  for (int off = 1; off < 256; off <<= 1) {
    int v = sm[t];
    if (t >= off) v += sm[t - off];
    __syncthreads(); sm[t] = v; __syncthreads();
  }
  int run = sm[t] - s + partial[b];  // exclusive prefix
#pragma unroll
  for (int k = 0; k < 8; k++) {
    int i = base + k;
    if (i < NN) { row_ptr[i] = run; cursor[i] = run; run += loc[k]; }
  }
}

__global__ void k_scatter(const int* __restrict__ rows, const int* __restrict__ cols,
                          const float* __restrict__ vals, int* __restrict__ cursor,
                          int* __restrict__ cols_s, float* __restrict__ vals_s) {
  int e = blockIdx.x * blockDim.x + threadIdx.x;
  if (e >= NNZ) return;
  int slot = atomicAdd(&cursor[rows[e]], 1);
  cols_s[slot] = cols[e];
  vals_s[slot] = vals[e];
}

// ---------------- gather SpMV: one wave per node, lane = dim; fused acc += ----------------
__global__ void k_spmv(const int* __restrict__ row_ptr, const int* __restrict__ cols_s,
                       const float* __restrict__ vals_s, const float* __restrict__ cur,
                       float* __restrict__ nxt, float* __restrict__ acc) {
  int node = blockIdx.x * (blockDim.x >> 6) + (threadIdx.x >> 6);
  if (node >= NN) return;
  node = __builtin_amdgcn_readfirstlane(node);   // force scalar addressing
  int lane = threadIdx.x & 63;
  int beg = row_ptr[node], end = row_ptr[node + 1];
  float s = 0.f;
  int e = beg;
  for (; e + 1 < end; e += 2) {
    int   c0 = cols_s[e],   c1 = cols_s[e + 1];
    float v0 = vals_s[e],   v1 = vals_s[e + 1];
    s = fmaf(v0, cur[c0 * DIM + lane], s);
    s = fmaf(v1, cur[c1 * DIM + lane], s);
  }
  if (e < end) s = fmaf(vals_s[e], cur[cols_s[e] * DIM + lane], s);
  int o = node * DIM + lane;
  nxt[o] = s;
  acc[o] += s;
}

// ---------------- batch gather + reg/beta reductions ----------------
__global__ void k_gather(const float* __restrict__ acc, const int* __restrict__ user,
                         const int* __restrict__ pos, const int* __restrict__ neg,
                         const float* __restrict__ uemb, const float* __restrict__ iemb,
                         const float* __restrict__ beta_u, const float* __restrict__ beta_i,
                         float* __restrict__ ue, float* __restrict__ pe, float* __restrict__ ne,
                         float* __restrict__ S) {
  int gid = blockIdx.x * blockDim.x + threadIdx.x;   // BATCH*64 exact
  int i = gid >> 6, d = gid & 63;
  int u = user[i], p = pos[i], n = neg[i];
  ue[gid] = ALPHA * acc[u * DIM + d];
  pe[gid] = ALPHA * acc[(NUSERS + p) * DIM + d];
  ne[gid] = ALPHA * acc[(NUSERS + n) * DIM + d];
  float ru = uemb[u * DIM + d], rp = iemb[p * DIM + d], rn = iemb[n * DIM + d];
  float r2 = ru * ru + rp * rp + rn * rn;
  r2 = wred64(r2);
  if (d == 0) atomicAdd(&S[0], r2);
  if (d == 1) atomicAdd(&S[1], beta_u[i]);
  if (d == 2) atomicAdd(&S[2], beta_i[i]);
}

__global__ void k_invperm(const int* __restrict__ perm, int* __restrict__ inv) {
  int i = blockIdx.x * blockDim.x + threadIdx.x;
  if (i < BATCH) inv[perm[i]] = i;
}

// ---------------- mixes, scores, row normalization (wave per row) ----------------
__global__ void k_mixnorm(const float* __restrict__ ue, const float* __restrict__ pe,
                          const float* __restrict__ ne, const float* __restrict__ beta_u,
                          const float* __restrict__ beta_i, const int* __restrict__ perm,
                          float* __restrict__ An_u, float* __restrict__ Pn_u,
                          float* __restrict__ An_p, float* __restrict__ Pn_p,
                          float* __restrict__ pos_sc, float* __restrict__ neg_sc,
                          float* __restrict__ nms) {
  int gid = blockIdx.x * blockDim.x + threadIdx.x;   // BATCH*64 exact
  int i = gid >> 6, d = gid & 63;
  int pi = perm[i];
  float uei = ue[i * DIM + d], pei = pe[i * DIM + d], nei = ne[i * DIM + d];
  float ud = ue[pi * DIM + d], pd = pe[pi * DIM + d], nd = ne[pi * DIM + d];
  float bu = beta_u[i], bi = beta_i[i];
  float um = bu * uei + (1.f - bu) * ud;
  float pm = bi * pei + (1.f - bi) * pd;
  float nm = bi * nei + (1.f - bi) * nd;
  float r0 = uei * pei, r1 = uei * nei, r2 = uei * nm;
  float r3 = uei * uei, r4 = um * um, r5 = pei * pei, r6 = pm * pm;
  for (int o = 32; o > 0; o >>= 1) {
    r0 += __shfl_xor(r0, o); r1 += __shfl_xor(r1, o); r2 += __shfl_xor(r2, o);
    r3 += __shfl_xor(r3, o); r4 += __shfl_xor(r4, o); r5 += __shfl_xor(r5, o);
    r6 += __shfl_xor(r6, o);
  }
  if (d == 0) { pos_sc[i] = r0; neg_sc[i] = r1; nms[i] = r2; }
  float inu  = 1.f / fmaxf(sqrtf(r3), 1e-12f);
  float inum = 1.f / fmaxf(sqrtf(r4), 1e-12f);
  float inp  = 1.f / fmaxf(sqrtf(r5), 1e-12f);
  float inpm = 1.f / fmaxf(sqrtf(r6), 1e-12f);
  An_u[i * DIM + d] = uei * inu;
  Pn_u[i * DIM + d] = um * inum;
  An_p[i * DIM + d] = pei * inp;
  Pn_p[i * DIM + d] = pm * inpm;
}

// ---------------- collective-mix vectors c_u, c_p (single block) ----------------
__global__ void k_colvec(const float* __restrict__ ue, const float* __restrict__ pe,
                         const float* __restrict__ cu, const float* __restrict__ cp,
                         float* __restrict__ c_u, float* __restrict__ c_p) {
  __shared__ float smu[4][64], smp[4][64];
  __shared__ float nrm[2];
  int t = threadIdx.x, d = t & 63, q = t >> 6;
  float su = 0.f, sp = 0.f;
  for (int i = q * (BATCH / 4); i < (q + 1) * (BATCH / 4); ++i) {
    su = fmaf(cu[i], ue[i * DIM + d], su);
    sp = fmaf(cp[i], pe[i * DIM + d], sp);
  }
  smu[q][d] = su; smp[q][d] = sp; __syncthreads();
  if (t < 64) {
    smu[0][d] = smu[0][d] + smu[1][d] + smu[2][d] + smu[3][d];
    smp[0][d] = smp[0][d] + smp[1][d] + smp[2][d] + smp[3][d];
  }
  __syncthreads();
  if (t == 0) {
    float a = 0.f, b = 0.f;
    for (int k = 0; k < 64; k++) { a += smu[0][k] * smu[0][k]; b += smp[0][k] * smp[0][k]; }
    nrm[0] = 1.f / fmaxf(sqrtf(a), 1e-12f);
    nrm[1] = 1.f / fmaxf(sqrtf(b), 1e-12f);
  }
  __syncthreads();
  if (t < 64) { c_u[d] = smu[0][d] * nrm[0]; c_p[d] = smp[0][d] * nrm[1]; }
}

// ---------------- per-row sims: dis, col, diag(G), G[r,inv[r]] (wave per row) ----------------
__global__ void k_sims(const float* __restrict__ An_u, const float* __restrict__ Pn_u,
                       const float* __restrict__ An_p, const float* __restrict__ Pn_p,
                       const float* __restrict__ c_u, const float* __restrict__ c_p,
                       const int* __restrict__ perm, const int* __restrict__ inv,
                       float* __restrict__ dis_u, float* __restrict__ col_u,
                       float* __restrict__ posd_u, float* __restrict__ cross_u,
                       float* __restrict__ dis_p, float* __restrict__ col_p,
                       float* __restrict__ posd_p, float* __restrict__ cross_p) {
  int gid = blockIdx.x * blockDim.x + threadIdx.x;
  int r = gid >> 6, d = gid & 63;
  int pr = perm[r], ir = inv[r];
  float au = An_u[r * DIM + d], pu = Pn_u[r * DIM + d];
  float ap = An_p[r * DIM + d], pp = Pn_p[r * DIM + d];
  float r0 = au * An_u[pr * DIM + d];
  float r1 = au * c_u[d];
  float r2 = au * pu;
  float r3 = au * Pn_u[ir * DIM + d];
  float r4 = ap * An_p[pr * DIM + d];
  float r5 = ap * c_p[d];
  float r6 = ap * pp;
  float r7 = ap * Pn_p[ir * DIM + d];
  for (int o = 32; o > 0; o >>= 1) {
    r0 += __shfl_xor(r0, o); r1 += __shfl_xor(r1, o); r2 += __shfl_xor(r2, o);
    r3 += __shfl_xor(r3, o); r4 += __shfl_xor(r4, o); r5 += __shfl_xor(r5, o);
    r6 += __shfl_xor(r6, o); r7 += __shfl_xor(r7, o);
  }
  if (d == 0) {
    dis_u[r] = r0 * INVT; col_u[r] = r1 * INVT; posd_u[r] = r2 * INVT; cross_u[r] = r3 * INVT;
    dis_p[r] = r4 * INVT; col_p[r] = r5 * INVT; posd_p[r] = r6 * INVT; cross_p[r] = r7 * INVT;
  }
}

// ---------------- fused matmul + online row-logsumexp over G = An @ Pn^T / T ----------------
// block = 256 threads = 16 rows x 16 col-threads; tiles of 64 columns staged in LDS.
__global__ __launch_bounds__(256) void k_lse(const float* __restrict__ An,
                                             const float* __restrict__ Pn,
                                             float* __restrict__ m_row,
                                             float* __restrict__ s_row) {
  __shared__ float As[16][65];
  __shared__ float Ps[64][65];
  __shared__ float Ms[256], Ss[256];
  int t = threadIdx.x;
  int rg = t >> 4, tl = t & 15;
  int r0 = blockIdx.x * 16;
  for (int idx = t; idx < 16 * 64; idx += 256) {
    int rr = idx >> 6, d = idx & 63;
    As[rr][d] = An[(r0 + rr) * DIM + d];
  }
  float m = -1e30f, s = 0.f;
  for (int j0 = 0; j0 < BATCH; j0 += 64) {
    __syncthreads();
    for (int idx = t; idx < 64 * 64; idx += 256) {
      int jj = idx >> 6, d = idx & 63;
      Ps[jj][d] = Pn[(j0 + jj) * DIM + d];
    }
    __syncthreads();
    float a0 = 0.f, a1 = 0.f, a2 = 0.f, a3 = 0.f;
#pragma unroll
    for (int k = 0; k < 64; k++) {
      float a = As[rg][k];
      a0 = fmaf(a, Ps[tl][k], a0);
      a1 = fmaf(a, Ps[tl + 16][k], a1);
      a2 = fmaf(a, Ps[tl + 32][k], a2);
      a3 = fmaf(a, Ps[tl + 48][k], a3);
    }
    a0 *= INVT; a1 *= INVT; a2 *= INVT; a3 *= INVT;
    float mx = fmaxf(fmaxf(a0, a1), fmaxf(a2, a3));
    float nm2 = fmaxf(m, mx);
    s = s * __expf(m - nm2) + __expf(a0 - nm2) + __expf(a1 - nm2) +
        __expf(a2 - nm2) + __expf(a3 - nm2);
    m = nm2;
  }
  Ms[t] = m; Ss[t] = s; __syncthreads();
  if (tl == 0) {
    float M = Ms[t], S = Ss[t];
    for (int k = 1; k < 16; k++) {
      float m2 = Ms[t + k], s2 = Ss[t + k];
      float nm2 = fmaxf(M, m2);
      S = S * __expf(M - nm2) + s2 * __expf(m2 - nm2);
      M = nm2;
    }
    m_row[r0 + rg] = M;
    s_row[r0 + rg] = S;
  }
}

// ---------------- final combine (single block) — OUTPUT IS FLOAT32 ----------------
__global__ void k_final(const float* __restrict__ m_u, const float* __restrict__ s_u,
                        const float* __restrict__ dis_u, const float* __restrict__ col_u,
                        const float* __restrict__ posd_u, const float* __restrict__ cross_u,
                        const float* __restrict__ m_p, const float* __restrict__ s_p,
                        const float* __restrict__ dis_p, const float* __restrict__ col_p,
                        const float* __restrict__ posd_p, const float* __restrict__ cross_p,
                        const float* __restrict__ pos_sc, const float* __restrict__ neg_sc,
                        const float* __restrict__ nms, const int* __restrict__ inv,
                        const float* __restrict__ S, float* __restrict__ out) {
  __shared__ float red[6][256];
  int t = threadIdx.x;
  float lpu = 0.f, lnu = 0.f, lpp = 0.f, lnp = 0.f, bp = 0.f, bn = 0.f;
  for (int r = t; r < BATCH; r += 256) {
    int ir = inv[r];
    // user side
    {
      float M = m_u[r], Sv = s_u[r];
      float d2 = col_u[r];
      float d1 = dis_u[r];
      float nm2 = fmaxf(M, fmaxf(d1, d2));
      float ss = Sv * __expf(M - nm2) + __expf(d1 - nm2) + __expf(d2 - nm2);
      lpu += nm2 + logf(ss) - posd_u[r];
      float d1n = dis_u[ir];
      nm2 = fmaxf(M, fmaxf(d1n, d2));
      ss = Sv * __expf(M - nm2) + __expf(d1n - nm2) + __expf(d2 - nm2);
      lnu += nm2 + logf(ss) - cross_u[r];
    }
    // pos side
    {
      float M = m_p[r], Sv = s_p[r];
      float d2 = col_p[r];
      float d1 = dis_p[r];
      float nm2 = fmaxf(M, fmaxf(d1, d2));
      float ss = Sv * __expf(M - nm2) + __expf(d1 - nm2) + __expf(d2 - nm2);
      lpp += nm2 + logf(ss) - posd_p[r];
      float d1n = dis_p[ir];
      nm2 = fmaxf(M, fmaxf(d1n, d2));
      ss = Sv * __expf(M - nm2) + __expf(d1n - nm2) + __expf(d2 - nm2);
      lnp += nm2 + logf(ss) - cross_p[r];
    }
    // bpr
    float ps = pos_sc[r];
    bp += softplusf(neg_sc[r] - ps);
    bn += softplusf(nms[r] - ps);
  }
  red[0][t] = lpu; red[1][t] = lnu; red[2][t] = lpp;
  red[3][t] = lnp; red[4][t] = bp;  red[5][t] = bn;
  __syncthreads();
  for (int off = 128; off > 0; off >>= 1) {
    if (t < off)
      for (int c = 0; c < 6; c++) red[c][t] += red[c][t + off];
    __syncthreads();
  }
  if (t == 0) {
    const float inv_b = 1.f / (float)BATCH;
    float mbu = S[1] * inv_b;            // mean(beta_u)
    float b   = S[2] * inv_b;            // mean(beta_i)
    float cl_u = mbu * (red[0][0] * inv_b) + (1.f - mbu) * (red[1][0] * inv_b);
    float cl_p = b   * (red[2][0] * inv_b) + (1.f - b)   * (red[3][0] * inv_b);
    float main_m = b * (red[4][0] * inv_b) + (1.f - b) * (red[5][0] * inv_b);
    float reg = REGC * S[0] * inv_b;
    float loss = main_m + LAMBDA * (cl_u + cl_p) + reg;
    out[0] = loss;                       // float32 — reference output dtype
  }
}

extern "C" void kernel_launch(void* const* d_in, const int* in_sizes, int n_in,
                              void* d_out, int out_size, void* d_ws, size_t ws_size,
                              hipStream_t stream) {
  const float* uemb   = (const float*)d_in[0];
  const float* iemb   = (const float*)d_in[1];
  const int*   rows   = (const int*)d_in[2];
  const int*   cols   = (const int*)d_in[3];
  const float* vals   = (const float*)d_in[4];
  const int*   user   = (const int*)d_in[5];
  const int*   pos    = (const int*)d_in[6];
  const int*   neg    = (const int*)d_in[7];
  const float* beta_u = (const float*)d_in[8];
  const float* beta_i = (const float*)d_in[9];
  const int*   perm   = (const int*)d_in[10];
  const float* cu     = (const float*)d_in[11];
  const float* cp     = (const float*)d_in[12];

  char* w = (char*)d_ws;
  size_t off = 0;
  auto alloc = [&](size_t bytes) -> char* {
    char* p = w + off;
    off += (bytes + 255) & ~(size_t)255;
    return p;
  };
  float* cur     = (float*)alloc((size_t)ND * 4);
  float* nxt     = (float*)alloc((size_t)ND * 4);
  float* acc     = (float*)alloc((size_t)ND * 4);
  int*   cols_s  = (int*)  alloc((size_t)NNZ * 4);
  float* vals_s  = (float*)alloc((size_t)NNZ * 4);
  int*   row_ptr = (int*)  alloc((size_t)(NN + 1) * 4);
  int*   cnt     = (int*)  alloc((size_t)NN * 4);
  int*   cursor  = (int*)  alloc((size_t)NN * 4);
  int*   partial = (int*)  alloc(4096);
  float* ue      = (float*)alloc((size_t)BATCH * DIM * 4);
  float* pe      = (float*)alloc((size_t)BATCH * DIM * 4);
  float* ne      = (float*)alloc((size_t)BATCH * DIM * 4);
  float* An_u    = (float*)alloc((size_t)BATCH * DIM * 4);
  float* Pn_u    = (float*)alloc((size_t)BATCH * DIM * 4);
  float* An_p    = (float*)alloc((size_t)BATCH * DIM * 4);
  float* Pn_p    = (float*)alloc((size_t)BATCH * DIM * 4);
  float* pos_sc  = (float*)alloc((size_t)BATCH * 4);
  float* neg_sc  = (float*)alloc((size_t)BATCH * 4);
  float* nms     = (float*)alloc((size_t)BATCH * 4);
  float* dis_u   = (float*)alloc((size_t)BATCH * 4);
  float* col_u   = (float*)alloc((size_t)BATCH * 4);
  float* posd_u  = (float*)alloc((size_t)BATCH * 4);
  float* cross_u = (float*)alloc((size_t)BATCH * 4);
  float* m_u     = (float*)alloc((size_t)BATCH * 4);
  float* s_u     = (float*)alloc((size_t)BATCH * 4);
  float* dis_p   = (float*)alloc((size_t)BATCH * 4);
  float* col_p   = (float*)alloc((size_t)BATCH * 4);
  float* posd_p  = (float*)alloc((size_t)BATCH * 4);
  float* cross_p = (float*)alloc((size_t)BATCH * 4);
  float* m_p     = (float*)alloc((size_t)BATCH * 4);
  float* s_p     = (float*)alloc((size_t)BATCH * 4);
  int*   invp    = (int*)  alloc((size_t)BATCH * 4);
  float* c_u     = (float*)alloc(256);
  float* c_p     = (float*)alloc(256);
  float* S       = (float*)alloc(256);

  // 1. zero counters/accumulators
  k_zero<<<(NN + 255) / 256, 256, 0, stream>>>(cnt, S);
  // 2. init cur = acc = x
  k_init<<<(ND + 255) / 256, 256, 0, stream>>>(uemb, iemb, cur, acc);
  // 3. CSR build
  k_hist<<<(NNZ + 255) / 256, 256, 0, stream>>>(rows, cnt);
  k_scan1<<<SNB, 256, 0, stream>>>(cnt, partial);
  k_scan2<<<1, 64, 0, stream>>>(partial, row_ptr);
  k_scan3<<<SNB, 256, 0, stream>>>(cnt, partial, row_ptr, cursor);
  k_scatter<<<(NNZ + 255) / 256, 256, 0, stream>>>(rows, cols, vals, cursor, cols_s, vals_s);
  // 4. three GCN layers (gather SpMV, fused acc accumulation)
  {
    float* a = cur;
    float* b2 = nxt;
    for (int l = 0; l < 3; l++) {
      k_spmv<<<(NN + 3) / 4, 256, 0, stream>>>(row_ptr, cols_s, vals_s, a, b2, acc);
      float* t2 = a; a = b2; b2 = t2;
    }
  }
  // 5. batch gather (+ reg/beta sums)
  k_gather<<<(BATCH * DIM) / 256, 256, 0, stream>>>(acc, user, pos, neg, uemb, iemb,
                                                    beta_u, beta_i, ue, pe, ne, S);
  k_invperm<<<(BATCH + 255) / 256, 256, 0, stream>>>(perm, invp);
  // 6. mixes, scores, normalization
  k_mixnorm<<<(BATCH * DIM) / 256, 256, 0, stream>>>(ue, pe, ne, beta_u, beta_i, perm,
                                                     An_u, Pn_u, An_p, Pn_p,
                                                     pos_sc, neg_sc, nms);
  k_colvec<<<1, 256, 0, stream>>>(ue, pe, cu, cp, c_u, c_p);
  k_sims<<<(BATCH * DIM) / 256, 256, 0, stream>>>(An_u, Pn_u, An_p, Pn_p, c_u, c_p,
                                                  perm, invp,
                                                  dis_u, col_u, posd_u, cross_u,
                                                  dis_p, col_p, posd_p, cross_p);
  // 7. fused matmul + online LSE (user side, pos side)
  k_lse<<<BATCH / 16, 256, 0, stream>>>(An_u, Pn_u, m_u, s_u);
  k_lse<<<BATCH / 16, 256, 0, stream>>>(An_p, Pn_p, m_p, s_p);
  // 8. final combine
  k_final<<<1, 256, 0, stream>>>(m_u, s_u, dis_u, col_u, posd_u, cross_u,
                                 m_p, s_p, dis_p, col_p, posd_p, cross_p,
                                 pos_sc, neg_sc, nms, invp, S,
                                 (float*)d_out);
}

// Round 3
// 1288.268 us; speedup vs baseline: 1.2488x; 1.2488x over previous
//
#include <hip/hip_runtime.h>
#include <hip/hip_bf16.h>

#define NUSERS 100000
#define NITEMS 50000
#define NN     150001          // total nodes
#define NNZ    3200000         // 2 * NNZ_INTER
#define BATCH  4096
#define DIM    64
#define ND     (NN * DIM)
#define ALPHA  0.25f           // 1/(N_LAYERS+1)
#define INVT   5.0f            // 1/TEMP
#define LAMBDA 0.1f
#define REGC   1.0e-4f
#define SCHUNK 2048
#define SNB    74              // ceil(150001/2048)

__device__ __forceinline__ float wred64(float v) {
  for (int o = 32; o > 0; o >>= 1) v += __shfl_xor(v, o);
  return v;
}

__device__ __forceinline__ float softplusf(float x) {
  // log(1+exp(x))
  return (x > 20.f) ? x : log1pf(__expf(x));
}

// ---------------- zero scratch ----------------
__global__ void k_zero(int* __restrict__ cnt, float* __restrict__ S) {
  int i = blockIdx.x * blockDim.x + threadIdx.x;
  if (i < NN) cnt[i] = 0;
  if (i < 256) S[i] = 0.f;
}

// ---------------- x = concat(user_emb, item_emb); cur = acc = x ----------------
__global__ void k_init(const float* __restrict__ uemb, const float* __restrict__ iemb,
                       float* __restrict__ cur, float* __restrict__ acc) {
  int gid = blockIdx.x * blockDim.x + threadIdx.x;
  if (gid >= ND) return;
  int n = gid >> 6, d = gid & 63;
  float v = (n < NUSERS) ? uemb[gid] : iemb[(n - NUSERS) * DIM + d];
  cur[gid] = v;
  acc[gid] = v;
}

// ---------------- CSR build ----------------
__global__ void k_hist(const int* __restrict__ rows, int* __restrict__ cnt) {
  int e = blockIdx.x * blockDim.x + threadIdx.x;
  if (e < NNZ) atomicAdd(&cnt[rows[e]], 1);
}

__global__ void k_scan1(const int* __restrict__ cnt, int* __restrict__ partial) {
  __shared__ int sm[256];
  int b = blockIdx.x, t = threadIdx.x;
  int base = b * SCHUNK + t * 8;
  int s = 0;
#pragma unroll
  for (int k = 0; k < 8; k++) { int i = base + k; if (i < NN) s += cnt[i]; }
  sm[t] = s; __syncthreads();
  for (int off = 128; off > 0; off >>= 1) { if (t < off) sm[t] += sm[t + off]; __syncthreads(); }
  if (t == 0) partial[b] = sm[0];
}

__global__ void k_scan2(int* __restrict__ partial, int* __restrict__ row_ptr) {
  if (blockIdx.x == 0 && threadIdx.x == 0) {
    int run = 0;
    for (int i = 0; i < SNB; i++) { int v = partial[i]; partial[i] = run; run += v; }
    row_ptr[NN] = run;  // == NNZ
  }
}

__global__ void k_scan3(const int* __restrict__ cnt, const int* __restrict__ partial,
                        int* __restrict__ row_ptr, int* __restrict__ cursor) {
  __shared__ int sm[256];
  int b = blockIdx.x, t = threadIdx.x;
  int base = b * SCHUNK + t * 8;
  int loc[8];
  int s = 0;
#pragma unroll
  for (int k = 0; k < 8; k++) { int i = base + k; int c = (i < NN) ? cnt[i] : 0; loc[k] = c; s += c; }
  sm[t] = s; __syncthreads();
  for (int off = 1; off < 256; off <<= 1) {
    int v = sm[t];
    if (t >= off) v += sm[t - off];
    __syncthreads(); sm[t] = v; __syncthreads();
  }
  int run = sm[t] - s + partial[b];  // exclusive prefix
#pragma unroll
  for (int k = 0; k < 8; k++) {
    int i = base + k;
    if (i < NN) { row_ptr[i] = run; cursor[i] = run; run += loc[k]; }
  }
}

// packed scatter: ONE 8-byte store per edge (col,val) — halves partial-line writebacks
__global__ void k_scatter(const int* __restrict__ rows, const int* __restrict__ cols,
                          const float* __restrict__ vals, int* __restrict__ cursor,
                          int2* __restrict__ ev) {
  int e = blockIdx.x * blockDim.x + threadIdx.x;
  if (e >= NNZ) return;
  int slot = atomicAdd(&cursor[rows[e]], 1);
  ev[slot] = make_int2(cols[e], __float_as_int(vals[e]));
}

// ---------------- gather SpMV: one wave per node, lane = dim; fused acc += ----------------
// packed int2 edges; 4x unroll -> 4 independent gathers in flight
__global__ void k_spmv(const int* __restrict__ row_ptr, const int2* __restrict__ ev,
                       const float* __restrict__ cur,
                       float* __restrict__ nxt, float* __restrict__ acc) {
  int node = blockIdx.x * (blockDim.x >> 6) + (threadIdx.x >> 6);
  if (node >= NN) return;
  node = __builtin_amdgcn_readfirstlane(node);   // force scalar addressing
  int lane = threadIdx.x & 63;
  int beg = row_ptr[node], end = row_ptr[node + 1];
  float s = 0.f;
  int e = beg;
  for (; e + 3 < end; e += 4) {
    int2 e0 = ev[e], e1 = ev[e + 1], e2 = ev[e + 2], e3 = ev[e + 3];
    float x0 = cur[e0.x * DIM + lane];
    float x1 = cur[e1.x * DIM + lane];
    float x2 = cur[e2.x * DIM + lane];
    float x3 = cur[e3.x * DIM + lane];
    s = fmaf(__int_as_float(e0.y), x0, s);
    s = fmaf(__int_as_float(e1.y), x1, s);
    s = fmaf(__int_as_float(e2.y), x2, s);
    s = fmaf(__int_as_float(e3.y), x3, s);
  }
  for (; e < end; ++e) {
    int2 e0 = ev[e];
    s = fmaf(__int_as_float(e0.y), cur[e0.x * DIM + lane], s);
  }
  int o = node * DIM + lane;
  nxt[o] = s;
  acc[o] += s;
}

// ---------------- batch gather + reg/beta reductions ----------------
__global__ void k_gather(const float* __restrict__ acc, const int* __restrict__ user,
                         const int* __restrict__ pos, const int* __restrict__ neg,
                         const float* __restrict__ uemb, const float* __restrict__ iemb,
                         const float* __restrict__ beta_u, const float* __restrict__ beta_i,
                         float* __restrict__ ue, float* __restrict__ pe, float* __restrict__ ne,
                         float* __restrict__ S) {
  int gid = blockIdx.x * blockDim.x + threadIdx.x;   // BATCH*64 exact
  int i = gid >> 6, d = gid & 63;
  int u = user[i], p = pos[i], n = neg[i];
  ue[gid] = ALPHA * acc[u * DIM + d];
  pe[gid] = ALPHA * acc[(NUSERS + p) * DIM + d];
  ne[gid] = ALPHA * acc[(NUSERS + n) * DIM + d];
  float ru = uemb[u * DIM + d], rp = iemb[p * DIM + d], rn = iemb[n * DIM + d];
  float r2 = ru * ru + rp * rp + rn * rn;
  r2 = wred64(r2);
  if (d == 0) atomicAdd(&S[0], r2);
  if (d == 1) atomicAdd(&S[1], beta_u[i]);
  if (d == 2) atomicAdd(&S[2], beta_i[i]);
}

__global__ void k_invperm(const int* __restrict__ perm, int* __restrict__ inv) {
  int i = blockIdx.x * blockDim.x + threadIdx.x;
  if (i < BATCH) inv[perm[i]] = i;
}

// ---------------- mixes, scores, row normalization (wave per row) ----------------
__global__ void k_mixnorm(const float* __restrict__ ue, const float* __restrict__ pe,
                          const float* __restrict__ ne, const float* __restrict__ beta_u,
                          const float* __restrict__ beta_i, const int* __restrict__ perm,
                          float* __restrict__ An_u, float* __restrict__ Pn_u,
                          float* __restrict__ An_p, float* __restrict__ Pn_p,
                          float* __restrict__ pos_sc, float* __restrict__ neg_sc,
                          float* __restrict__ nms) {
  int gid = blockIdx.x * blockDim.x + threadIdx.x;   // BATCH*64 exact
  int i = gid >> 6, d = gid & 63;
  int pi = perm[i];
  float uei = ue[i * DIM + d], pei = pe[i * DIM + d], nei = ne[i * DIM + d];
  float ud = ue[pi * DIM + d], pd = pe[pi * DIM + d], nd = ne[pi * DIM + d];
  float bu = beta_u[i], bi = beta_i[i];
  float um = bu * uei + (1.f - bu) * ud;
  float pm = bi * pei + (1.f - bi) * pd;
  float nm = bi * nei + (1.f - bi) * nd;
  float r0 = uei * pei, r1 = uei * nei, r2 = uei * nm;
  float r3 = uei * uei, r4 = um * um, r5 = pei * pei, r6 = pm * pm;
  for (int o = 32; o > 0; o >>= 1) {
    r0 += __shfl_xor(r0, o); r1 += __shfl_xor(r1, o); r2 += __shfl_xor(r2, o);
    r3 += __shfl_xor(r3, o); r4 += __shfl_xor(r4, o); r5 += __shfl_xor(r5, o);
    r6 += __shfl_xor(r6, o);
  }
  if (d == 0) { pos_sc[i] = r0; neg_sc[i] = r1; nms[i] = r2; }
  float inu  = 1.f / fmaxf(sqrtf(r3), 1e-12f);
  float inum = 1.f / fmaxf(sqrtf(r4), 1e-12f);
  float inp  = 1.f / fmaxf(sqrtf(r5), 1e-12f);
  float inpm = 1.f / fmaxf(sqrtf(r6), 1e-12f);
  An_u[i * DIM + d] = uei * inu;
  Pn_u[i * DIM + d] = um * inum;
  An_p[i * DIM + d] = pei * inp;
  Pn_p[i * DIM + d] = pm * inpm;
}

// ---------------- collective-mix: parallel partial sums (64 blocks) ----------------
__global__ void k_colpart(const float* __restrict__ ue, const float* __restrict__ pe,
                          const float* __restrict__ cu, const float* __restrict__ cp,
                          float* __restrict__ S) {
  __shared__ float smu[4][64], smp[4][64];
  int t = threadIdx.x, d = t & 63, q = t >> 6;
  int r0 = blockIdx.x * 64 + q * 16;
  float su = 0.f, sp = 0.f;
#pragma unroll 4
  for (int i = r0; i < r0 + 16; ++i) {
    su = fmaf(cu[i], ue[i * DIM + d], su);
    sp = fmaf(cp[i], pe[i * DIM + d], sp);
  }
  smu[q][d] = su; smp[q][d] = sp;
  __syncthreads();
  if (t < 64) {
    atomicAdd(&S[64 + d],  smu[0][d] + smu[1][d] + smu[2][d] + smu[3][d]);
    atomicAdd(&S[128 + d], smp[0][d] + smp[1][d] + smp[2][d] + smp[3][d]);
  }
}

// normalize the two 64-vectors (2 waves)
__global__ void k_colnorm(const float* __restrict__ S,
                          float* __restrict__ c_u, float* __restrict__ c_p) {
  int t = threadIdx.x;            // 128 threads = 2 waves
  int d = t & 63;
  float v = (t < 64) ? S[64 + d] : S[128 + d];
  float n = wred64(v * v);        // wave-local: wave0=u side, wave1=p side
  float inv = 1.f / fmaxf(sqrtf(n), 1e-12f);
  if (t < 64) c_u[d] = v * inv;
  else        c_p[d] = v * inv;
}

// ---------------- per-row sims: dis, col, diag(G), G[r,inv[r]] (wave per row) ----------------
__global__ void k_sims(const float* __restrict__ An_u, const float* __restrict__ Pn_u,
                       const float* __restrict__ An_p, const float* __restrict__ Pn_p,
                       const float* __restrict__ c_u, const float* __restrict__ c_p,
                       const int* __restrict__ perm, const int* __restrict__ inv,
                       float* __restrict__ dis_u, float* __restrict__ col_u,
                       float* __restrict__ posd_u, float* __restrict__ cross_u,
                       float* __restrict__ dis_p, float* __restrict__ col_p,
                       float* __restrict__ posd_p, float* __restrict__ cross_p) {
  int gid = blockIdx.x * blockDim.x + threadIdx.x;
  int r = gid >> 6, d = gid & 63;
  int pr = perm[r], ir = inv[r];
  float au = An_u[r * DIM + d], pu = Pn_u[r * DIM + d];
  float ap = An_p[r * DIM + d], pp = Pn_p[r * DIM + d];
  float r0 = au * An_u[pr * DIM + d];
  float r1 = au * c_u[d];
  float r2 = au * pu;
  float r3 = au * Pn_u[ir * DIM + d];
  float r4 = ap * An_p[pr * DIM + d];
  float r5 = ap * c_p[d];
  float r6 = ap * pp;
  float r7 = ap * Pn_p[ir * DIM + d];
  for (int o = 32; o > 0; o >>= 1) {
    r0 += __shfl_xor(r0, o); r1 += __shfl_xor(r1, o); r2 += __shfl_xor(r2, o);
    r3 += __shfl_xor(r3, o); r4 += __shfl_xor(r4, o); r5 += __shfl_xor(r5, o);
    r6 += __shfl_xor(r6, o); r7 += __shfl_xor(r7, o);
  }
  if (d == 0) {
    dis_u[r] = r0 * INVT; col_u[r] = r1 * INVT; posd_u[r] = r2 * INVT; cross_u[r] = r3 * INVT;
    dis_p[r] = r4 * INVT; col_p[r] = r5 * INVT; posd_p[r] = r6 * INVT; cross_p[r] = r7 * INVT;
  }
}

// ---------------- fused matmul + online row-logsumexp over G = An @ Pn^T / T ----------------
__global__ __launch_bounds__(256) void k_lse(const float* __restrict__ An,
                                             const float* __restrict__ Pn,
                                             float* __restrict__ m_row,
                                             float* __restrict__ s_row) {
  __shared__ float As[16][65];
  __shared__ float Ps[64][65];
  __shared__ float Ms[256], Ss[256];
  int t = threadIdx.x;
  int rg = t >> 4, tl = t & 15;
  int r0 = blockIdx.x * 16;
  for (int idx = t; idx < 16 * 64; idx += 256) {
    int rr = idx >> 6, d = idx & 63;
    As[rr][d] = An[(r0 + rr) * DIM + d];
  }
  float m = -1e30f, s = 0.f;
  for (int j0 = 0; j0 < BATCH; j0 += 64) {
    __syncthreads();
    for (int idx = t; idx < 64 * 64; idx += 256) {
      int jj = idx >> 6, d = idx & 63;
      Ps[jj][d] = Pn[(j0 + jj) * DIM + d];
    }
    __syncthreads();
    float a0 = 0.f, a1 = 0.f, a2 = 0.f, a3 = 0.f;
#pragma unroll
    for (int k = 0; k < 64; k++) {
      float a = As[rg][k];
      a0 = fmaf(a, Ps[tl][k], a0);
      a1 = fmaf(a, Ps[tl + 16][k], a1);
      a2 = fmaf(a, Ps[tl + 32][k], a2);
      a3 = fmaf(a, Ps[tl + 48][k], a3);
    }
    a0 *= INVT; a1 *= INVT; a2 *= INVT; a3 *= INVT;
    float mx = fmaxf(fmaxf(a0, a1), fmaxf(a2, a3));
    float nm2 = fmaxf(m, mx);
    s = s * __expf(m - nm2) + __expf(a0 - nm2) + __expf(a1 - nm2) +
        __expf(a2 - nm2) + __expf(a3 - nm2);
    m = nm2;
  }
  Ms[t] = m; Ss[t] = s; __syncthreads();
  if (tl == 0) {
    float M = Ms[t], S = Ss[t];
    for (int k = 1; k < 16; k++) {
      float m2 = Ms[t + k], s2 = Ss[t + k];
      float nm2 = fmaxf(M, m2);
      S = S * __expf(M - nm2) + s2 * __expf(m2 - nm2);
      M = nm2;
    }
    m_row[r0 + rg] = M;
    s_row[r0 + rg] = S;
  }
}

// ---------------- final combine (single block) — OUTPUT IS FLOAT32 ----------------
__global__ void k_final(const float* __restrict__ m_u, const float* __restrict__ s_u,
                        const float* __restrict__ dis_u, const float* __restrict__ col_u,
                        const float* __restrict__ posd_u, const float* __restrict__ cross_u,
                        const float* __restrict__ m_p, const float* __restrict__ s_p,
                        const float* __restrict__ dis_p, const float* __restrict__ col_p,
                        const float* __restrict__ posd_p, const float* __restrict__ cross_p,
                        const float* __restrict__ pos_sc, const float* __restrict__ neg_sc,
                        const float* __restrict__ nms, const int* __restrict__ inv,
                        const float* __restrict__ S, float* __restrict__ out) {
  __shared__ float red[6][256];
  int t = threadIdx.x;
  float lpu = 0.f, lnu = 0.f, lpp = 0.f, lnp = 0.f, bp = 0.f, bn = 0.f;
  for (int r = t; r < BATCH; r += 256) {
    int ir = inv[r];
    // user side
    {
      float M = m_u[r], Sv = s_u[r];
      float d2 = col_u[r];
      float d1 = dis_u[r];
      float nm2 = fmaxf(M, fmaxf(d1, d2));
      float ss = Sv * __expf(M - nm2) + __expf(d1 - nm2) + __expf(d2 - nm2);
      lpu += nm2 + logf(ss) - posd_u[r];
      float d1n = dis_u[ir];
      nm2 = fmaxf(M, fmaxf(d1n, d2));
      ss = Sv * __expf(M - nm2) + __expf(d1n - nm2) + __expf(d2 - nm2);
      lnu += nm2 + logf(ss) - cross_u[r];
    }
    // pos side
    {
      float M = m_p[r], Sv = s_p[r];
      float d2 = col_p[r];
      float d1 = dis_p[r];
      float nm2 = fmaxf(M, fmaxf(d1, d2));
      float ss = Sv * __expf(M - nm2) + __expf(d1 - nm2) + __expf(d2 - nm2);
      lpp += nm2 + logf(ss) - posd_p[r];
      float d1n = dis_p[ir];
      nm2 = fmaxf(M, fmaxf(d1n, d2));
      ss = Sv * __expf(M - nm2) + __expf(d1n - nm2) + __expf(d2 - nm2);
      lnp += nm2 + logf(ss) - cross_p[r];
    }
    // bpr
    float ps = pos_sc[r];
    bp += softplusf(neg_sc[r] - ps);
    bn += softplusf(nms[r] - ps);
  }
  red[0][t] = lpu; red[1][t] = lnu; red[2][t] = lpp;
  red[3][t] = lnp; red[4][t] = bp;  red[5][t] = bn;
  __syncthreads();
  for (int off = 128; off > 0; off >>= 1) {
    if (t < off)
      for (int c = 0; c < 6; c++) red[c][t] += red[c][t + off];
    __syncthreads();
  }
  if (t == 0) {
    const float inv_b = 1.f / (float)BATCH;
    float mbu = S[1] * inv_b;            // mean(beta_u)
    float b   = S[2] * inv_b;            // mean(beta_i)
    float cl_u = mbu * (red[0][0] * inv_b) + (1.f - mbu) * (red[1][0] * inv_b);
    float cl_p = b   * (red[2][0] * inv_b) + (1.f - b)   * (red[3][0] * inv_b);
    float main_m = b * (red[4][0] * inv_b) + (1.f - b) * (red[5][0] * inv_b);
    float reg = REGC * S[0] * inv_b;
    float loss = main_m + LAMBDA * (cl_u + cl_p) + reg;
    out[0] = loss;                       // float32 — reference output dtype
  }
}

extern "C" void kernel_launch(void* const* d_in, const int* in_sizes, int n_in,
                              void* d_out, int out_size, void* d_ws, size_t ws_size,
                              hipStream_t stream) {
  const float* uemb   = (const float*)d_in[0];
  const float* iemb   = (const float*)d_in[1];
  const int*   rows   = (const int*)d_in[2];
  const int*   cols   = (const int*)d_in[3];
  const float* vals   = (const float*)d_in[4];
  const int*   user   = (const int*)d_in[5];
  const int*   pos    = (const int*)d_in[6];
  const int*   neg    = (const int*)d_in[7];
  const float* beta_u = (const float*)d_in[8];
  const float* beta_i = (const float*)d_in[9];
  const int*   perm   = (const int*)d_in[10];
  const float* cu     = (const float*)d_in[11];
  const float* cp     = (const float*)d_in[12];

  char* w = (char*)d_ws;
  size_t off = 0;
  auto alloc = [&](size_t bytes) -> char* {
    char* p = w + off;
    off += (bytes + 255) & ~(size_t)255;
    return p;
  };
  float* cur     = (float*)alloc((size_t)ND * 4);
  float* nxt     = (float*)alloc((size_t)ND * 4);
  float* acc     = (float*)alloc((size_t)ND * 4);
  int2*  ev      = (int2*) alloc((size_t)NNZ * 8);
  int*   row_ptr = (int*)  alloc((size_t)(NN + 1) * 4);
  int*   cnt     = (int*)  alloc((size_t)NN * 4);
  int*   cursor  = (int*)  alloc((size_t)NN * 4);
  int*   partial = (int*)  alloc(4096);
  float* ue      = (float*)alloc((size_t)BATCH * DIM * 4);
  float* pe      = (float*)alloc((size_t)BATCH * DIM * 4);
  float* ne      = (float*)alloc((size_t)BATCH * DIM * 4);
  float* An_u    = (float*)alloc((size_t)BATCH * DIM * 4);
  float* Pn_u    = (float*)alloc((size_t)BATCH * DIM * 4);
  float* An_p    = (float*)alloc((size_t)BATCH * DIM * 4);
  float* Pn_p    = (float*)alloc((size_t)BATCH * DIM * 4);
  float* pos_sc  = (float*)alloc((size_t)BATCH * 4);
  float* neg_sc  = (float*)alloc((size_t)BATCH * 4);
  float* nms     = (float*)alloc((size_t)BATCH * 4);
  float* dis_u   = (float*)alloc((size_t)BATCH * 4);
  float* col_u   = (float*)alloc((size_t)BATCH * 4);
  float* posd_u  = (float*)alloc((size_t)BATCH * 4);
  float* cross_u = (float*)alloc((size_t)BATCH * 4);
  float* m_u     = (float*)alloc((size_t)BATCH * 4);
  float* s_u     = (float*)alloc((size_t)BATCH * 4);
  float* dis_p   = (float*)alloc((size_t)BATCH * 4);
  float* col_p   = (float*)alloc((size_t)BATCH * 4);
  float* posd_p  = (float*)alloc((size_t)BATCH * 4);
  float* cross_p = (float*)alloc((size_t)BATCH * 4);
  float* m_p     = (float*)alloc((size_t)BATCH * 4);
  float* s_p     = (float*)alloc((size_t)BATCH * 4);
  int*   invp    = (int*)  alloc((size_t)BATCH * 4);
  float* c_u     = (float*)alloc(256);
  float* c_p     = (float*)alloc(256);
  float* S       = (float*)alloc(1024);   // [0]=reg [1]=sum(beta_u) [2]=sum(beta_i) [64..127]=c_u_raw [128..191]=c_p_raw

  // 1. zero counters/accumulators
  k_zero<<<(NN + 255) / 256, 256, 0, stream>>>(cnt, S);
  // 2. init cur = acc = x
  k_init<<<(ND + 255) / 256, 256, 0, stream>>>(uemb, iemb, cur, acc);
  // 3. CSR build
  k_hist<<<(NNZ + 255) / 256, 256, 0, stream>>>(rows, cnt);
  k_scan1<<<SNB, 256, 0, stream>>>(cnt, partial);
  k_scan2<<<1, 64, 0, stream>>>(partial, row_ptr);
  k_scan3<<<SNB, 256, 0, stream>>>(cnt, partial, row_ptr, cursor);
  k_scatter<<<(NNZ + 255) / 256, 256, 0, stream>>>(rows, cols, vals, cursor, ev);
  // 4. three GCN layers (gather SpMV, fused acc accumulation)
  {
    float* a = cur;
    float* b2 = nxt;
    for (int l = 0; l < 3; l++) {
      k_spmv<<<(NN + 3) / 4, 256, 0, stream>>>(row_ptr, ev, a, b2, acc);
      float* t2 = a; a = b2; b2 = t2;
    }
  }
  // 5. batch gather (+ reg/beta sums)
  k_gather<<<(BATCH * DIM) / 256, 256, 0, stream>>>(acc, user, pos, neg, uemb, iemb,
                                                    beta_u, beta_i, ue, pe, ne, S);
  k_invperm<<<(BATCH + 255) / 256, 256, 0, stream>>>(perm, invp);
  // 6. mixes, scores, normalization
  k_mixnorm<<<(BATCH * DIM) / 256, 256, 0, stream>>>(ue, pe, ne, beta_u, beta_i, perm,
                                                     An_u, Pn_u, An_p, Pn_p,
                                                     pos_sc, neg_sc, nms);
  k_colpart<<<BATCH / 64, 256, 0, stream>>>(ue, pe, cu, cp, S);
  k_colnorm<<<1, 128, 0, stream>>>(S, c_u, c_p);
  k_sims<<<(BATCH * DIM) / 256, 256, 0, stream>>>(An_u, Pn_u, An_p, Pn_p, c_u, c_p,
                                                  perm, invp,
                                                  dis_u, col_u, posd_u, cross_u,
                                                  dis_p, col_p, posd_p, cross_p);
  // 7. fused matmul + online LSE (user side, pos side)
  k_lse<<<BATCH / 16, 256, 0, stream>>>(An_u, Pn_u, m_u, s_u);
  k_lse<<<BATCH / 16, 256, 0, stream>>>(An_p, Pn_p, m_p, s_p);
  // 8. final combine
  k_final<<<1, 256, 0, stream>>>(m_u, s_u, dis_u, col_u, posd_u, cross_u,
                                 m_p, s_p, dis_p, col_p, posd_p, cross_p,
                                 pos_sc, neg_sc, nms, invp, S,
                                 (float*)d_out);
}

// Round 4
// 1126.205 us; speedup vs baseline: 1.4285x; 1.1439x over previous
//
#include <hip/hip_runtime.h>
#include <hip/hip_bf16.h>

#define NUSERS 100000
#define NITEMS 50000
#define NN     150001          // total nodes
#define NNZ    3200000         // 2 * NNZ_INTER
#define BATCH  4096
#define DIM    64
#define ND     (NN * DIM)
#define ALPHA  0.25f           // 1/(N_LAYERS+1)
#define INVT   5.0f            // 1/TEMP
#define LAMBDA 0.1f
#define REGC   1.0e-4f
#define SCHUNK 2048
#define SNB    74              // ceil(150001/2048)
#define BKSH   9               // 512 nodes per bucket
#define NB     293             // ceil(150001/512)
#define ACHUNK 4096            // edges per bucketA block

__device__ __forceinline__ float wred64(float v) {
  for (int o = 32; o > 0; o >>= 1) v += __shfl_xor(v, o);
  return v;
}

__device__ __forceinline__ float softplusf(float x) {
  return (x > 20.f) ? x : log1pf(__expf(x));
}

// ---------------- zero scratch ----------------
__global__ void k_zero(int* __restrict__ cnt, float* __restrict__ S) {
  int i = blockIdx.x * blockDim.x + threadIdx.x;
  if (i < NN) cnt[i] = 0;
  if (i < 256) S[i] = 0.f;
}

// ---------------- x = concat(user_emb, item_emb); cur = acc = x (float4) ----------------
__global__ void k_init4(const float4* __restrict__ uemb, const float4* __restrict__ iemb,
                        float4* __restrict__ cur, float4* __restrict__ acc) {
  int q = blockIdx.x * blockDim.x + threadIdx.x;   // quads: ND/4
  if (q >= ND / 4) return;
  int n = q >> 4;                                   // 16 quads per node
  float4 v = (n < NUSERS) ? uemb[q] : iemb[q - NUSERS * 16];
  cur[q] = v;
  acc[q] = v;
}

// ---------------- CSR build ----------------
__global__ void k_hist(const int* __restrict__ rows, int* __restrict__ cnt) {
  int e = blockIdx.x * blockDim.x + threadIdx.x;
  if (e < NNZ) atomicAdd(&cnt[rows[e]], 1);
}

__global__ void k_scan1(const int* __restrict__ cnt, int* __restrict__ partial) {
  __shared__ int sm[256];
  int b = blockIdx.x, t = threadIdx.x;
  int base = b * SCHUNK + t * 8;
  int s = 0;
#pragma unroll
  for (int k = 0; k < 8; k++) { int i = base + k; if (i < NN) s += cnt[i]; }
  sm[t] = s; __syncthreads();
  for (int off = 128; off > 0; off >>= 1) { if (t < off) sm[t] += sm[t + off]; __syncthreads(); }
  if (t == 0) partial[b] = sm[0];
}

__global__ void k_scan2(int* __restrict__ partial, int* __restrict__ row_ptr) {
  if (blockIdx.x == 0 && threadIdx.x == 0) {
    int run = 0;
    for (int i = 0; i < SNB; i++) { int v = partial[i]; partial[i] = run; run += v; }
    row_ptr[NN] = run;  // == NNZ
  }
}

__global__ void k_scan3(const int* __restrict__ cnt, const int* __restrict__ partial,
                        int* __restrict__ row_ptr) {
  __shared__ int sm[256];
  int b = blockIdx.x, t = threadIdx.x;
  int base = b * SCHUNK + t * 8;
  int loc[8];
  int s = 0;
#pragma unroll
  for (int k = 0; k < 8; k++) { int i = base + k; int c = (i < NN) ? cnt[i] : 0; loc[k] = c; s += c; }
  sm[t] = s; __syncthreads();
  for (int off = 1; off < 256; off <<= 1) {
    int v = sm[t];
    if (t >= off) v += sm[t - off];
    __syncthreads(); sm[t] = v; __syncthreads();
  }
  int run = sm[t] - s + partial[b];  // exclusive prefix
#pragma unroll
  for (int k = 0; k < 8; k++) {
    int i = base + k;
    if (i < NN) { row_ptr[i] = run; run += loc[k]; }
  }
}

__global__ void k_binit(const int* __restrict__ row_ptr, int* __restrict__ bcur) {
  int b = blockIdx.x * blockDim.x + threadIdx.x;
  if (b < NB) bcur[b] = row_ptr[b << BKSH];
}

// ---------------- bucket pass A: LDS counting-sort into 512-node buckets, coalesced flush ----
__global__ __launch_bounds__(256) void k_bucketA(const int* __restrict__ rows,
                                                 const int* __restrict__ cols,
                                                 const float* __restrict__ vals,
                                                 int* __restrict__ bcur,
                                                 int4* __restrict__ tmp) {
  __shared__ int lhist[NB];
  __shared__ int lscan[NB];
  __shared__ int ldelta[NB];
  __shared__ int lcnt[NB];
  __shared__ int4 ent[ACHUNK];
  int t = threadIdx.x;
  int base = blockIdx.x * ACHUNK;
  for (int b = t; b < NB; b += 256) { lhist[b] = 0; lcnt[b] = 0; }
  __syncthreads();
  int rowv[16], colv[16], valv[16], bkt[16];
  int nval = 0;
#pragma unroll
  for (int k = 0; k < 16; k++) {
    int e = base + t + k * 256;                 // coalesced
    if (e < NNZ) {
      rowv[k] = rows[e]; colv[k] = cols[e]; valv[k] = __float_as_int(vals[e]);
      bkt[k] = rowv[k] >> BKSH;
      atomicAdd(&lhist[bkt[k]], 1);
      nval = k + 1;
    }
  }
  __syncthreads();
  if (t == 0) {
    int run = 0;
    for (int b = 0; b < NB; b++) { lscan[b] = run; run += lhist[b]; }
  }
  __syncthreads();
  for (int b = t; b < NB; b += 256) {
    int c = lhist[b];
    int g = (c > 0) ? atomicAdd(&bcur[b], c) : 0;
    ldelta[b] = g - lscan[b];
  }
  __syncthreads();
#pragma unroll
  for (int k = 0; k < 16; k++) {
    if (k < nval) {
      int b = bkt[k];
      int lp = atomicAdd(&lcnt[b], 1);
      ent[lscan[b] + lp] = make_int4(colv[k], valv[k], rowv[k], ldelta[b]);
    }
  }
  __syncthreads();
  int tot = min(ACHUNK, NNZ - base);
  for (int j = t; j < tot; j += 256) {
    int4 E = ent[j];
    tmp[E.w + j] = E;                           // contiguous run per bucket -> full lines
  }
}

// ---------------- bucket pass B: per-bucket final scatter (writes stay in one XCD's L2) ----
__global__ __launch_bounds__(256) void k_bucketB(const int* __restrict__ row_ptr,
                                                 const int4* __restrict__ tmp,
                                                 int2* __restrict__ ev) {
  __shared__ int lcnt[512];
  int b = blockIdx.x;
  int nbase = b << BKSH;
  for (int i = threadIdx.x; i < 512; i += 256) lcnt[i] = 0;
  __syncthreads();
  int beg = row_ptr[nbase];
  int end = (b == NB - 1) ? NNZ : row_ptr[nbase + 512];
  for (int j = beg + threadIdx.x; j < end; j += 256) {
    int4 E = tmp[j];
    int lp = atomicAdd(&lcnt[E.z - nbase], 1);
    ev[row_ptr[E.z] + lp] = make_int2(E.x, E.y);
  }
}

// ---------------- gather SpMV: wave per node, 4 edge-groups x 16 lanes x float4 ----------
__global__ __launch_bounds__(256) void k_spmv(const int* __restrict__ row_ptr,
                                              const int2* __restrict__ ev,
                                              const float* __restrict__ cur,
                                              float* __restrict__ nxt,
                                              float* __restrict__ acc) {
  int node = blockIdx.x * 4 + (threadIdx.x >> 6);
  if (node >= NN) return;
  node = __builtin_amdgcn_readfirstlane(node);
  int lane = threadIdx.x & 63;
  int g = lane >> 4;                 // edge group 0..3
  int d4 = (lane & 15) << 2;         // dim base (float4)
  int beg = row_ptr[node], end = row_ptr[node + 1];
  float4 s = make_float4(0.f, 0.f, 0.f, 0.f);
  int e = beg + g;
  for (; e + 4 < end; e += 8) {
    int2 E0 = ev[e];
    int2 E1 = ev[e + 4];
    float4 x0 = *(const float4*)&cur[E0.x * DIM + d4];
    float4 x1 = *(const float4*)&cur[E1.x * DIM + d4];
    float v0 = __int_as_float(E0.y), v1 = __int_as_float(E1.y);
    s.x = fmaf(v0, x0.x, s.x); s.y = fmaf(v0, x0.y, s.y);
    s.z = fmaf(v0, x0.z, s.z); s.w = fmaf(v0, x0.w, s.w);
    s.x = fmaf(v1, x1.x, s.x); s.y = fmaf(v1, x1.y, s.y);
    s.z = fmaf(v1, x1.z, s.z); s.w = fmaf(v1, x1.w, s.w);
  }
  if (e < end) {
    int2 E0 = ev[e];
    float v0 = __int_as_float(E0.y);
    float4 x0 = *(const float4*)&cur[E0.x * DIM + d4];
    s.x = fmaf(v0, x0.x, s.x); s.y = fmaf(v0, x0.y, s.y);
    s.z = fmaf(v0, x0.z, s.z); s.w = fmaf(v0, x0.w, s.w);
  }
  // reduce across the 4 edge groups
  s.x += __shfl_xor(s.x, 16); s.y += __shfl_xor(s.y, 16);
  s.z += __shfl_xor(s.z, 16); s.w += __shfl_xor(s.w, 16);
  s.x += __shfl_xor(s.x, 32); s.y += __shfl_xor(s.y, 32);
  s.z += __shfl_xor(s.z, 32); s.w += __shfl_xor(s.w, 32);
  if (g == 0) {
    int o = node * DIM + d4;
    *(float4*)&nxt[o] = s;
    float4 a = *(const float4*)&acc[o];
    a.x += s.x; a.y += s.y; a.z += s.z; a.w += s.w;
    *(float4*)&acc[o] = a;
  }
}

// ---------------- batch gather + reg/beta reductions ----------------
__global__ void k_gather(const float* __restrict__ acc, const int* __restrict__ user,
                         const int* __restrict__ pos, const int* __restrict__ neg,
                         const float* __restrict__ uemb, const float* __restrict__ iemb,
                         const float* __restrict__ beta_u, const float* __restrict__ beta_i,
                         float* __restrict__ ue, float* __restrict__ pe, float* __restrict__ ne,
                         float* __restrict__ S) {
  int gid = blockIdx.x * blockDim.x + threadIdx.x;   // BATCH*64 exact
  int i = gid >> 6, d = gid & 63;
  int u = user[i], p = pos[i], n = neg[i];
  ue[gid] = ALPHA * acc[u * DIM + d];
  pe[gid] = ALPHA * acc[(NUSERS + p) * DIM + d];
  ne[gid] = ALPHA * acc[(NUSERS + n) * DIM + d];
  float ru = uemb[u * DIM + d], rp = iemb[p * DIM + d], rn = iemb[n * DIM + d];
  float r2 = ru * ru + rp * rp + rn * rn;
  r2 = wred64(r2);
  if (d == 0) atomicAdd(&S[0], r2);
  if (d == 1) atomicAdd(&S[1], beta_u[i]);
  if (d == 2) atomicAdd(&S[2], beta_i[i]);
}

__global__ void k_invperm(const int* __restrict__ perm, int* __restrict__ inv) {
  int i = blockIdx.x * blockDim.x + threadIdx.x;
  if (i < BATCH) inv[perm[i]] = i;
}

// ---------------- mixes, scores, row normalization (wave per row) ----------------
__global__ void k_mixnorm(const float* __restrict__ ue, const float* __restrict__ pe,
                          const float* __restrict__ ne, const float* __restrict__ beta_u,
                          const float* __restrict__ beta_i, const int* __restrict__ perm,
                          float* __restrict__ An_u, float* __restrict__ Pn_u,
                          float* __restrict__ An_p, float* __restrict__ Pn_p,
                          float* __restrict__ pos_sc, float* __restrict__ neg_sc,
                          float* __restrict__ nms) {
  int gid = blockIdx.x * blockDim.x + threadIdx.x;   // BATCH*64 exact
  int i = gid >> 6, d = gid & 63;
  int pi = perm[i];
  float uei = ue[i * DIM + d], pei = pe[i * DIM + d], nei = ne[i * DIM + d];
  float ud = ue[pi * DIM + d], pd = pe[pi * DIM + d], nd = ne[pi * DIM + d];
  float bu = beta_u[i], bi = beta_i[i];
  float um = bu * uei + (1.f - bu) * ud;
  float pm = bi * pei + (1.f - bi) * pd;
  float nm = bi * nei + (1.f - bi) * nd;
  float r0 = uei * pei, r1 = uei * nei, r2 = uei * nm;
  float r3 = uei * uei, r4 = um * um, r5 = pei * pei, r6 = pm * pm;
  for (int o = 32; o > 0; o >>= 1) {
    r0 += __shfl_xor(r0, o); r1 += __shfl_xor(r1, o); r2 += __shfl_xor(r2, o);
    r3 += __shfl_xor(r3, o); r4 += __shfl_xor(r4, o); r5 += __shfl_xor(r5, o);
    r6 += __shfl_xor(r6, o);
  }
  if (d == 0) { pos_sc[i] = r0; neg_sc[i] = r1; nms[i] = r2; }
  float inu  = 1.f / fmaxf(sqrtf(r3), 1e-12f);
  float inum = 1.f / fmaxf(sqrtf(r4), 1e-12f);
  float inp  = 1.f / fmaxf(sqrtf(r5), 1e-12f);
  float inpm = 1.f / fmaxf(sqrtf(r6), 1e-12f);
  An_u[i * DIM + d] = uei * inu;
  Pn_u[i * DIM + d] = um * inum;
  An_p[i * DIM + d] = pei * inp;
  Pn_p[i * DIM + d] = pm * inpm;
}

// ---------------- collective-mix: parallel partial sums (64 blocks) ----------------
__global__ void k_colpart(const float* __restrict__ ue, const float* __restrict__ pe,
                          const float* __restrict__ cu, const float* __restrict__ cp,
                          float* __restrict__ S) {
  __shared__ float smu[4][64], smp[4][64];
  int t = threadIdx.x, d = t & 63, q = t >> 6;
  int r0 = blockIdx.x * 64 + q * 16;
  float su = 0.f, sp = 0.f;
#pragma unroll 4
  for (int i = r0; i < r0 + 16; ++i) {
    su = fmaf(cu[i], ue[i * DIM + d], su);
    sp = fmaf(cp[i], pe[i * DIM + d], sp);
  }
  smu[q][d] = su; smp[q][d] = sp;
  __syncthreads();
  if (t < 64) {
    atomicAdd(&S[64 + d],  smu[0][d] + smu[1][d] + smu[2][d] + smu[3][d]);
    atomicAdd(&S[128 + d], smp[0][d] + smp[1][d] + smp[2][d] + smp[3][d]);
  }
}

__global__ void k_colnorm(const float* __restrict__ S,
                          float* __restrict__ c_u, float* __restrict__ c_p) {
  int t = threadIdx.x;            // 128 threads = 2 waves
  int d = t & 63;
  float v = (t < 64) ? S[64 + d] : S[128 + d];
  float n = wred64(v * v);        // wave-local: wave0=u side, wave1=p side
  float inv = 1.f / fmaxf(sqrtf(n), 1e-12f);
  if (t < 64) c_u[d] = v * inv;
  else        c_p[d] = v * inv;
}

// ---------------- per-row sims (wave per row) ----------------
__global__ void k_sims(const float* __restrict__ An_u, const float* __restrict__ Pn_u,
                       const float* __restrict__ An_p, const float* __restrict__ Pn_p,
                       const float* __restrict__ c_u, const float* __restrict__ c_p,
                       const int* __restrict__ perm, const int* __restrict__ inv,
                       float* __restrict__ dis_u, float* __restrict__ col_u,
                       float* __restrict__ posd_u, float* __restrict__ cross_u,
                       float* __restrict__ dis_p, float* __restrict__ col_p,
                       float* __restrict__ posd_p, float* __restrict__ cross_p) {
  int gid = blockIdx.x * blockDim.x + threadIdx.x;
  int r = gid >> 6, d = gid & 63;
  int pr = perm[r], ir = inv[r];
  float au = An_u[r * DIM + d], pu = Pn_u[r * DIM + d];
  float ap = An_p[r * DIM + d], pp = Pn_p[r * DIM + d];
  float r0 = au * An_u[pr * DIM + d];
  float r1 = au * c_u[d];
  float r2 = au * pu;
  float r3 = au * Pn_u[ir * DIM + d];
  float r4 = ap * An_p[pr * DIM + d];
  float r5 = ap * c_p[d];
  float r6 = ap * pp;
  float r7 = ap * Pn_p[ir * DIM + d];
  for (int o = 32; o > 0; o >>= 1) {
    r0 += __shfl_xor(r0, o); r1 += __shfl_xor(r1, o); r2 += __shfl_xor(r2, o);
    r3 += __shfl_xor(r3, o); r4 += __shfl_xor(r4, o); r5 += __shfl_xor(r5, o);
    r6 += __shfl_xor(r6, o); r7 += __shfl_xor(r7, o);
  }
  if (d == 0) {
    dis_u[r] = r0 * INVT; col_u[r] = r1 * INVT; posd_u[r] = r2 * INVT; cross_u[r] = r3 * INVT;
    dis_p[r] = r4 * INVT; col_p[r] = r5 * INVT; posd_p[r] = r6 * INVT; cross_p[r] = r7 * INVT;
  }
}

// ---------------- fused matmul + online row-logsumexp over G = An @ Pn^T / T ------------
__global__ __launch_bounds__(256) void k_lse(const float* __restrict__ An,
                                             const float* __restrict__ Pn,
                                             float* __restrict__ m_row,
                                             float* __restrict__ s_row) {
  __shared__ float As[16][65];
  __shared__ float Ps[64][65];
  __shared__ float Ms[256], Ss[256];
  int t = threadIdx.x;
  int rg = t >> 4, tl = t & 15;
  int r0 = blockIdx.x * 16;
  for (int idx = t; idx < 16 * 64; idx += 256) {
    int rr = idx >> 6, d = idx & 63;
    As[rr][d] = An[(r0 + rr) * DIM + d];
  }
  float m = -1e30f, s = 0.f;
  for (int j0 = 0; j0 < BATCH; j0 += 64) {
    __syncthreads();
    for (int idx = t; idx < 64 * 64; idx += 256) {
      int jj = idx >> 6, d = idx & 63;
      Ps[jj][d] = Pn[(j0 + jj) * DIM + d];
    }
    __syncthreads();
    float a0 = 0.f, a1 = 0.f, a2 = 0.f, a3 = 0.f;
#pragma unroll
    for (int k = 0; k < 64; k++) {
      float a = As[rg][k];
      a0 = fmaf(a, Ps[tl][k], a0);
      a1 = fmaf(a, Ps[tl + 16][k], a1);
      a2 = fmaf(a, Ps[tl + 32][k], a2);
      a3 = fmaf(a, Ps[tl + 48][k], a3);
    }
    a0 *= INVT; a1 *= INVT; a2 *= INVT; a3 *= INVT;
    float mx = fmaxf(fmaxf(a0, a1), fmaxf(a2, a3));
    float nm2 = fmaxf(m, mx);
    s = s * __expf(m - nm2) + __expf(a0 - nm2) + __expf(a1 - nm2) +
        __expf(a2 - nm2) + __expf(a3 - nm2);
    m = nm2;
  }
  Ms[t] = m; Ss[t] = s; __syncthreads();
  if (tl == 0) {
    float M = Ms[t], S = Ss[t];
    for (int k = 1; k < 16; k++) {
      float m2 = Ms[t + k], s2 = Ss[t + k];
      float nm2 = fmaxf(M, m2);
      S = S * __expf(M - nm2) + s2 * __expf(m2 - nm2);
      M = nm2;
    }
    m_row[r0 + rg] = M;
    s_row[r0 + rg] = S;
  }
}

// ---------------- final combine (single block) — OUTPUT IS FLOAT32 ----------------
__global__ void k_final(const float* __restrict__ m_u, const float* __restrict__ s_u,
                        const float* __restrict__ dis_u, const float* __restrict__ col_u,
                        const float* __restrict__ posd_u, const float* __restrict__ cross_u,
                        const float* __restrict__ m_p, const float* __restrict__ s_p,
                        const float* __restrict__ dis_p, const float* __restrict__ col_p,
                        const float* __restrict__ posd_p, const float* __restrict__ cross_p,
                        const float* __restrict__ pos_sc, const float* __restrict__ neg_sc,
                        const float* __restrict__ nms, const int* __restrict__ inv,
                        const float* __restrict__ S, float* __restrict__ out) {
  __shared__ float red[6][256];
  int t = threadIdx.x;
  float lpu = 0.f, lnu = 0.f, lpp = 0.f, lnp = 0.f, bp = 0.f, bn = 0.f;
  for (int r = t; r < BATCH; r += 256) {
    int ir = inv[r];
    {
      float M = m_u[r], Sv = s_u[r];
      float d2 = col_u[r];
      float d1 = dis_u[r];
      float nm2 = fmaxf(M, fmaxf(d1, d2));
      float ss = Sv * __expf(M - nm2) + __expf(d1 - nm2) + __expf(d2 - nm2);
      lpu += nm2 + logf(ss) - posd_u[r];
      float d1n = dis_u[ir];
      nm2 = fmaxf(M, fmaxf(d1n, d2));
      ss = Sv * __expf(M - nm2) + __expf(d1n - nm2) + __expf(d2 - nm2);
      lnu += nm2 + logf(ss) - cross_u[r];
    }
    {
      float M = m_p[r], Sv = s_p[r];
      float d2 = col_p[r];
      float d1 = dis_p[r];
      float nm2 = fmaxf(M, fmaxf(d1, d2));
      float ss = Sv * __expf(M - nm2) + __expf(d1 - nm2) + __expf(d2 - nm2);
      lpp += nm2 + logf(ss) - posd_p[r];
      float d1n = dis_p[ir];
      nm2 = fmaxf(M, fmaxf(d1n, d2));
      ss = Sv * __expf(M - nm2) + __expf(d1n - nm2) + __expf(d2 - nm2);
      lnp += nm2 + logf(ss) - cross_p[r];
    }
    float ps = pos_sc[r];
    bp += softplusf(neg_sc[r] - ps);
    bn += softplusf(nms[r] - ps);
  }
  red[0][t] = lpu; red[1][t] = lnu; red[2][t] = lpp;
  red[3][t] = lnp; red[4][t] = bp;  red[5][t] = bn;
  __syncthreads();
  for (int off = 128; off > 0; off >>= 1) {
    if (t < off)
      for (int c = 0; c < 6; c++) red[c][t] += red[c][t + off];
    __syncthreads();
  }
  if (t == 0) {
    const float inv_b = 1.f / (float)BATCH;
    float mbu = S[1] * inv_b;            // mean(beta_u)
    float b   = S[2] * inv_b;            // mean(beta_i)
    float cl_u = mbu * (red[0][0] * inv_b) + (1.f - mbu) * (red[1][0] * inv_b);
    float cl_p = b   * (red[2][0] * inv_b) + (1.f - b)   * (red[3][0] * inv_b);
    float main_m = b * (red[4][0] * inv_b) + (1.f - b) * (red[5][0] * inv_b);
    float reg = REGC * S[0] * inv_b;
    float loss = main_m + LAMBDA * (cl_u + cl_p) + reg;
    out[0] = loss;                       // float32
  }
}

extern "C" void kernel_launch(void* const* d_in, const int* in_sizes, int n_in,
                              void* d_out, int out_size, void* d_ws, size_t ws_size,
                              hipStream_t stream) {
  const float* uemb   = (const float*)d_in[0];
  const float* iemb   = (const float*)d_in[1];
  const int*   rows   = (const int*)d_in[2];
  const int*   cols   = (const int*)d_in[3];
  const float* vals   = (const float*)d_in[4];
  const int*   user   = (const int*)d_in[5];
  const int*   pos    = (const int*)d_in[6];
  const int*   neg    = (const int*)d_in[7];
  const float* beta_u = (const float*)d_in[8];
  const float* beta_i = (const float*)d_in[9];
  const int*   perm   = (const int*)d_in[10];
  const float* cu     = (const float*)d_in[11];
  const float* cp     = (const float*)d_in[12];

  char* w = (char*)d_ws;
  size_t off = 0;
  auto alloc = [&](size_t bytes) -> char* {
    char* p = w + off;
    off += (bytes + 255) & ~(size_t)255;
    return p;
  };
  float* cur     = (float*)alloc((size_t)ND * 4);
  float* nxt     = (float*)alloc((size_t)ND * 4);
  float* acc     = (float*)alloc((size_t)ND * 4);
  int2*  ev      = (int2*) alloc((size_t)NNZ * 8);
  int*   row_ptr = (int*)  alloc((size_t)(NN + 1) * 4);
  int*   cnt     = (int*)  alloc((size_t)NN * 4);
  int*   bcur    = (int*)  alloc((size_t)NB * 4);
  int*   partial = (int*)  alloc(4096);
  float* ue      = (float*)alloc((size_t)BATCH * DIM * 4);
  float* pe      = (float*)alloc((size_t)BATCH * DIM * 4);
  float* ne      = (float*)alloc((size_t)BATCH * DIM * 4);
  float* An_u    = (float*)alloc((size_t)BATCH * DIM * 4);
  float* Pn_u    = (float*)alloc((size_t)BATCH * DIM * 4);
  float* An_p    = (float*)alloc((size_t)BATCH * DIM * 4);
  float* Pn_p    = (float*)alloc((size_t)BATCH * DIM * 4);
  float* pos_sc  = (float*)alloc((size_t)BATCH * 4);
  float* neg_sc  = (float*)alloc((size_t)BATCH * 4);
  float* nms     = (float*)alloc((size_t)BATCH * 4);
  float* dis_u   = (float*)alloc((size_t)BATCH * 4);
  float* col_u   = (float*)alloc((size_t)BATCH * 4);
  float* posd_u  = (float*)alloc((size_t)BATCH * 4);
  float* cross_u = (float*)alloc((size_t)BATCH * 4);
  float* m_u     = (float*)alloc((size_t)BATCH * 4);
  float* s_u     = (float*)alloc((size_t)BATCH * 4);
  float* dis_p   = (float*)alloc((size_t)BATCH * 4);
  float* col_p   = (float*)alloc((size_t)BATCH * 4);
  float* posd_p  = (float*)alloc((size_t)BATCH * 4);
  float* cross_p = (float*)alloc((size_t)BATCH * 4);
  float* m_p     = (float*)alloc((size_t)BATCH * 4);
  float* s_p     = (float*)alloc((size_t)BATCH * 4);
  int*   invp    = (int*)  alloc((size_t)BATCH * 4);
  float* c_u     = (float*)alloc(256);
  float* c_p     = (float*)alloc(256);
  float* S       = (float*)alloc(1024);

  // tmp (int4 per edge, 51.2MB) aliases cur+nxt — dead until k_init4 runs after CSR build
  int4* tmp = (int4*)cur;

  // 1. zero counters
  k_zero<<<(NN + 255) / 256, 256, 0, stream>>>(cnt, S);
  // 2. CSR build (runs BEFORE init so tmp can alias cur/nxt)
  k_hist<<<(NNZ + 255) / 256, 256, 0, stream>>>(rows, cnt);
  k_scan1<<<SNB, 256, 0, stream>>>(cnt, partial);
  k_scan2<<<1, 64, 0, stream>>>(partial, row_ptr);
  k_scan3<<<SNB, 256, 0, stream>>>(cnt, partial, row_ptr);
  k_binit<<<2, 256, 0, stream>>>(row_ptr, bcur);
  k_bucketA<<<(NNZ + ACHUNK - 1) / ACHUNK, 256, 0, stream>>>(rows, cols, vals, bcur, tmp);
  k_bucketB<<<NB, 256, 0, stream>>>(row_ptr, tmp, ev);
  // 3. init cur = acc = x
  k_init4<<<(ND / 4 + 255) / 256, 256, 0, stream>>>((const float4*)uemb, (const float4*)iemb,
                                                    (float4*)cur, (float4*)acc);
  // 4. three GCN layers
  {
    float* a = cur;
    float* b2 = nxt;
    for (int l = 0; l < 3; l++) {
      k_spmv<<<(NN + 3) / 4, 256, 0, stream>>>(row_ptr, ev, a, b2, acc);
      float* t2 = a; a = b2; b2 = t2;
    }
  }
  // 5. batch gather (+ reg/beta sums)
  k_gather<<<(BATCH * DIM) / 256, 256, 0, stream>>>(acc, user, pos, neg, uemb, iemb,
                                                    beta_u, beta_i, ue, pe, ne, S);
  k_invperm<<<(BATCH + 255) / 256, 256, 0, stream>>>(perm, invp);
  // 6. mixes, scores, normalization
  k_mixnorm<<<(BATCH * DIM) / 256, 256, 0, stream>>>(ue, pe, ne, beta_u, beta_i, perm,
                                                     An_u, Pn_u, An_p, Pn_p,
                                                     pos_sc, neg_sc, nms);
  k_colpart<<<BATCH / 64, 256, 0, stream>>>(ue, pe, cu, cp, S);
  k_colnorm<<<1, 128, 0, stream>>>(S, c_u, c_p);
  k_sims<<<(BATCH * DIM) / 256, 256, 0, stream>>>(An_u, Pn_u, An_p, Pn_p, c_u, c_p,
                                                  perm, invp,
                                                  dis_u, col_u, posd_u, cross_u,
                                                  dis_p, col_p, posd_p, cross_p);
  // 7. fused matmul + online LSE (user side, pos side)
  k_lse<<<BATCH / 16, 256, 0, stream>>>(An_u, Pn_u, m_u, s_u);
  k_lse<<<BATCH / 16, 256, 0, stream>>>(An_p, Pn_p, m_p, s_p);
  // 8. final combine
  k_final<<<1, 256, 0, stream>>>(m_u, s_u, dis_u, col_u, posd_u, cross_u,
                                 m_p, s_p, dis_p, col_p, posd_p, cross_p,
                                 pos_sc, neg_sc, nms, invp, S,
                                 (float*)d_out);
}

// Round 5
// 825.701 us; speedup vs baseline: 1.9484x; 1.3639x over previous
//
#include <hip/hip_runtime.h>
#include <hip/hip_bf16.h>

#define NUSERS 100000
#define NITEMS 50000
#define NN     150001          // total nodes
#define NNZ    3200000         // 2 * NNZ_INTER
#define BATCH  4096
#define DIM    64
#define ND     (NN * DIM)
#define ALPHA  0.25f           // 1/(N_LAYERS+1)
#define INVT   5.0f            // 1/TEMP
#define LAMBDA 0.1f
#define REGC   1.0e-4f
#define SCHUNK 2048
#define SNB    74              // ceil(150001/2048)
#define BKSH   9               // 512 nodes per bucket
#define NB     293             // ceil(150001/512)
#define ACHUNK 4096            // edges per bucketA block
#define M0     5.0f            // fixed LSE shift: logits = sim/T ∈ [-5,5]

typedef __attribute__((ext_vector_type(8))) short v8s;    // 8 bf16 (4 VGPRs)
typedef __attribute__((ext_vector_type(4))) float f32x4;  // MFMA acc

__device__ __forceinline__ float wred64(float v) {
  for (int o = 32; o > 0; o >>= 1) v += __shfl_xor(v, o);
  return v;
}

__device__ __forceinline__ float softplusf(float x) {
  return (x > 20.f) ? x : log1pf(__expf(x));
}

__device__ __forceinline__ unsigned short bf16r(float v) {
  unsigned x = __float_as_uint(v);
  return (unsigned short)((x + 0x7fff + ((x >> 16) & 1)) >> 16);   // RNE
}

// ---------------- zero scratch + preset LSE state ----------------
__global__ void k_zero(int* __restrict__ cnt, float* __restrict__ S,
                       float* __restrict__ m_u, float* __restrict__ s_u,
                       float* __restrict__ m_p, float* __restrict__ s_p) {
  int i = blockIdx.x * blockDim.x + threadIdx.x;
  if (i < NN) cnt[i] = 0;
  if (i < 256) S[i] = 0.f;
  if (i < BATCH) { s_u[i] = 0.f; s_p[i] = 0.f; m_u[i] = M0; m_p[i] = M0; }
}

// ---------------- x = concat(user_emb, item_emb); cur = acc = x (float4) ----------------
__global__ void k_init4(const float4* __restrict__ uemb, const float4* __restrict__ iemb,
                        float4* __restrict__ cur, float4* __restrict__ acc) {
  int q = blockIdx.x * blockDim.x + threadIdx.x;   // quads: ND/4
  if (q >= ND / 4) return;
  int n = q >> 4;                                   // 16 quads per node
  float4 v = (n < NUSERS) ? uemb[q] : iemb[q - NUSERS * 16];
  cur[q] = v;
  acc[q] = v;
}

// ---------------- CSR build ----------------
__global__ void k_hist(const int* __restrict__ rows, int* __restrict__ cnt) {
  int e = blockIdx.x * blockDim.x + threadIdx.x;
  if (e < NNZ) atomicAdd(&cnt[rows[e]], 1);
}

__global__ void k_scan1(const int* __restrict__ cnt, int* __restrict__ partial) {
  __shared__ int sm[256];
  int b = blockIdx.x, t = threadIdx.x;
  int base = b * SCHUNK + t * 8;
  int s = 0;
#pragma unroll
  for (int k = 0; k < 8; k++) { int i = base + k; if (i < NN) s += cnt[i]; }
  sm[t] = s; __syncthreads();
  for (int off = 128; off > 0; off >>= 1) { if (t < off) sm[t] += sm[t + off]; __syncthreads(); }
  if (t == 0) partial[b] = sm[0];
}

__global__ void k_scan2(int* __restrict__ partial, int* __restrict__ row_ptr) {
  if (blockIdx.x == 0 && threadIdx.x == 0) {
    int run = 0;
    for (int i = 0; i < SNB; i++) { int v = partial[i]; partial[i] = run; run += v; }
    row_ptr[NN] = run;  // == NNZ
  }
}

__global__ void k_scan3(const int* __restrict__ cnt, const int* __restrict__ partial,
                        int* __restrict__ row_ptr) {
  __shared__ int sm[256];
  int b = blockIdx.x, t = threadIdx.x;
  int base = b * SCHUNK + t * 8;
  int loc[8];
  int s = 0;
#pragma unroll
  for (int k = 0; k < 8; k++) { int i = base + k; int c = (i < NN) ? cnt[i] : 0; loc[k] = c; s += c; }
  sm[t] = s; __syncthreads();
  for (int off = 1; off < 256; off <<= 1) {
    int v = sm[t];
    if (t >= off) v += sm[t - off];
    __syncthreads(); sm[t] = v; __syncthreads();
  }
  int run = sm[t] - s + partial[b];  // exclusive prefix
#pragma unroll
  for (int k = 0; k < 8; k++) {
    int i = base + k;
    if (i < NN) { row_ptr[i] = run; run += loc[k]; }
  }
}

__global__ void k_binit(const int* __restrict__ row_ptr, int* __restrict__ bcur) {
  int b = blockIdx.x * blockDim.x + threadIdx.x;
  if (b < NB) bcur[b] = row_ptr[b << BKSH];
}

// ---------------- bucket pass A: LDS counting-sort into 512-node buckets, coalesced flush ----
__global__ __launch_bounds__(256) void k_bucketA(const int* __restrict__ rows,
                                                 const int* __restrict__ cols,
                                                 const float* __restrict__ vals,
                                                 int* __restrict__ bcur,
                                                 int4* __restrict__ tmp) {
  __shared__ int lhist[NB];
  __shared__ int lscan[NB];
  __shared__ int ldelta[NB];
  __shared__ int lcnt[NB];
  __shared__ int4 ent[ACHUNK];
  int t = threadIdx.x;
  int base = blockIdx.x * ACHUNK;
  for (int b = t; b < NB; b += 256) { lhist[b] = 0; lcnt[b] = 0; }
  __syncthreads();
  int rowv[16], colv[16], valv[16], bkt[16];
  int nval = 0;
#pragma unroll
  for (int k = 0; k < 16; k++) {
    int e = base + t + k * 256;                 // coalesced
    if (e < NNZ) {
      rowv[k] = rows[e]; colv[k] = cols[e]; valv[k] = __float_as_int(vals[e]);
      bkt[k] = rowv[k] >> BKSH;
      atomicAdd(&lhist[bkt[k]], 1);
      nval = k + 1;
    }
  }
  __syncthreads();
  if (t == 0) {
    int run = 0;
    for (int b = 0; b < NB; b++) { lscan[b] = run; run += lhist[b]; }
  }
  __syncthreads();
  for (int b = t; b < NB; b += 256) {
    int c = lhist[b];
    int g = (c > 0) ? atomicAdd(&bcur[b], c) : 0;
    ldelta[b] = g - lscan[b];
  }
  __syncthreads();
#pragma unroll
  for (int k = 0; k < 16; k++) {
    if (k < nval) {
      int b = bkt[k];
      int lp = atomicAdd(&lcnt[b], 1);
      ent[lscan[b] + lp] = make_int4(colv[k], valv[k], rowv[k], ldelta[b]);
    }
  }
  __syncthreads();
  int tot = min(ACHUNK, NNZ - base);
  for (int j = t; j < tot; j += 256) {
    int4 E = ent[j];
    tmp[E.w + j] = E;                           // contiguous run per bucket -> full lines
  }
}

// ---------------- bucket pass B: per-bucket final scatter (writes stay in one XCD's L2) ----
__global__ __launch_bounds__(256) void k_bucketB(const int* __restrict__ row_ptr,
                                                 const int4* __restrict__ tmp,
                                                 int2* __restrict__ ev) {
  __shared__ int lcnt[512];
  int b = blockIdx.x;
  int nbase = b << BKSH;
  for (int i = threadIdx.x; i < 512; i += 256) lcnt[i] = 0;
  __syncthreads();
  int beg = row_ptr[nbase];
  int end = (b == NB - 1) ? NNZ : row_ptr[nbase + 512];
  for (int j = beg + threadIdx.x; j < end; j += 256) {
    int4 E = tmp[j];
    int lp = atomicAdd(&lcnt[E.z - nbase], 1);
    ev[row_ptr[E.z] + lp] = make_int2(E.x, E.y);
  }
}

// ---------------- gather SpMV: wave per node, 4 edge-groups x 16 lanes x float4 ----------
__global__ __launch_bounds__(256) void k_spmv(const int* __restrict__ row_ptr,
                                              const int2* __restrict__ ev,
                                              const float* __restrict__ cur,
                                              float* __restrict__ nxt,
                                              float* __restrict__ acc) {
  int node = blockIdx.x * 4 + (threadIdx.x >> 6);
  if (node >= NN) return;
  node = __builtin_amdgcn_readfirstlane(node);
  int lane = threadIdx.x & 63;
  int g = lane >> 4;                 // edge group 0..3
  int d4 = (lane & 15) << 2;         // dim base (float4)
  int beg = row_ptr[node], end = row_ptr[node + 1];
  float4 s = make_float4(0.f, 0.f, 0.f, 0.f);
  int e = beg + g;
  for (; e + 4 < end; e += 8) {
    int2 E0 = ev[e];
    int2 E1 = ev[e + 4];
    float4 x0 = *(const float4*)&cur[E0.x * DIM + d4];
    float4 x1 = *(const float4*)&cur[E1.x * DIM + d4];
    float v0 = __int_as_float(E0.y), v1 = __int_as_float(E1.y);
    s.x = fmaf(v0, x0.x, s.x); s.y = fmaf(v0, x0.y, s.y);
    s.z = fmaf(v0, x0.z, s.z); s.w = fmaf(v0, x0.w, s.w);
    s.x = fmaf(v1, x1.x, s.x); s.y = fmaf(v1, x1.y, s.y);
    s.z = fmaf(v1, x1.z, s.z); s.w = fmaf(v1, x1.w, s.w);
  }
  if (e < end) {
    int2 E0 = ev[e];
    float v0 = __int_as_float(E0.y);
    float4 x0 = *(const float4*)&cur[E0.x * DIM + d4];
    s.x = fmaf(v0, x0.x, s.x); s.y = fmaf(v0, x0.y, s.y);
    s.z = fmaf(v0, x0.z, s.z); s.w = fmaf(v0, x0.w, s.w);
  }
  // reduce across the 4 edge groups
  s.x += __shfl_xor(s.x, 16); s.y += __shfl_xor(s.y, 16);
  s.z += __shfl_xor(s.z, 16); s.w += __shfl_xor(s.w, 16);
  s.x += __shfl_xor(s.x, 32); s.y += __shfl_xor(s.y, 32);
  s.z += __shfl_xor(s.z, 32); s.w += __shfl_xor(s.w, 32);
  if (g == 0) {
    int o = node * DIM + d4;
    *(float4*)&nxt[o] = s;
    float4 a = *(const float4*)&acc[o];
    a.x += s.x; a.y += s.y; a.z += s.z; a.w += s.w;
    *(float4*)&acc[o] = a;
  }
}

// ---------------- batch gather + reg/beta reductions ----------------
__global__ void k_gather(const float* __restrict__ acc, const int* __restrict__ user,
                         const int* __restrict__ pos, const int* __restrict__ neg,
                         const float* __restrict__ uemb, const float* __restrict__ iemb,
                         const float* __restrict__ beta_u, const float* __restrict__ beta_i,
                         float* __restrict__ ue, float* __restrict__ pe, float* __restrict__ ne,
                         float* __restrict__ S) {
  int gid = blockIdx.x * blockDim.x + threadIdx.x;   // BATCH*64 exact
  int i = gid >> 6, d = gid & 63;
  int u = user[i], p = pos[i], n = neg[i];
  ue[gid] = ALPHA * acc[u * DIM + d];
  pe[gid] = ALPHA * acc[(NUSERS + p) * DIM + d];
  ne[gid] = ALPHA * acc[(NUSERS + n) * DIM + d];
  float ru = uemb[u * DIM + d], rp = iemb[p * DIM + d], rn = iemb[n * DIM + d];
  float r2 = ru * ru + rp * rp + rn * rn;
  r2 = wred64(r2);
  if (d == 0) atomicAdd(&S[0], r2);
  if (d == 1) atomicAdd(&S[1], beta_u[i]);
  if (d == 2) atomicAdd(&S[2], beta_i[i]);
}

__global__ void k_invperm(const int* __restrict__ perm, int* __restrict__ inv) {
  int i = blockIdx.x * blockDim.x + threadIdx.x;
  if (i < BATCH) inv[perm[i]] = i;
}

// ---------------- mixes, scores, row normalization (wave per row); also emit bf16 ----------
__global__ void k_mixnorm(const float* __restrict__ ue, const float* __restrict__ pe,
                          const float* __restrict__ ne, const float* __restrict__ beta_u,
                          const float* __restrict__ beta_i, const int* __restrict__ perm,
                          float* __restrict__ An_u, float* __restrict__ Pn_u,
                          float* __restrict__ An_p, float* __restrict__ Pn_p,
                          unsigned short* __restrict__ An_uh, unsigned short* __restrict__ Pn_uh,
                          unsigned short* __restrict__ An_ph, unsigned short* __restrict__ Pn_ph,
                          float* __restrict__ pos_sc, float* __restrict__ neg_sc,
                          float* __restrict__ nms) {
  int gid = blockIdx.x * blockDim.x + threadIdx.x;   // BATCH*64 exact
  int i = gid >> 6, d = gid & 63;
  int pi = perm[i];
  float uei = ue[i * DIM + d], pei = pe[i * DIM + d], nei = ne[i * DIM + d];
  float ud = ue[pi * DIM + d], pd = pe[pi * DIM + d], nd = ne[pi * DIM + d];
  float bu = beta_u[i], bi = beta_i[i];
  float um = bu * uei + (1.f - bu) * ud;
  float pm = bi * pei + (1.f - bi) * pd;
  float nm = bi * nei + (1.f - bi) * nd;
  float r0 = uei * pei, r1 = uei * nei, r2 = uei * nm;
  float r3 = uei * uei, r4 = um * um, r5 = pei * pei, r6 = pm * pm;
  for (int o = 32; o > 0; o >>= 1) {
    r0 += __shfl_xor(r0, o); r1 += __shfl_xor(r1, o); r2 += __shfl_xor(r2, o);
    r3 += __shfl_xor(r3, o); r4 += __shfl_xor(r4, o); r5 += __shfl_xor(r5, o);
    r6 += __shfl_xor(r6, o);
  }
  if (d == 0) { pos_sc[i] = r0; neg_sc[i] = r1; nms[i] = r2; }
  float inu  = 1.f / fmaxf(sqrtf(r3), 1e-12f);
  float inum = 1.f / fmaxf(sqrtf(r4), 1e-12f);
  float inp  = 1.f / fmaxf(sqrtf(r5), 1e-12f);
  float inpm = 1.f / fmaxf(sqrtf(r6), 1e-12f);
  float a0 = uei * inu, p0 = um * inum, a1 = pei * inp, p1 = pm * inpm;
  An_u[gid] = a0;  Pn_u[gid] = p0;  An_p[gid] = a1;  Pn_p[gid] = p1;
  An_uh[gid] = bf16r(a0); Pn_uh[gid] = bf16r(p0);
  An_ph[gid] = bf16r(a1); Pn_ph[gid] = bf16r(p1);
}

// ---------------- collective-mix: parallel partial sums (64 blocks) ----------------
__global__ void k_colpart(const float* __restrict__ ue, const float* __restrict__ pe,
                          const float* __restrict__ cu, const float* __restrict__ cp,
                          float* __restrict__ S) {
  __shared__ float smu[4][64], smp[4][64];
  int t = threadIdx.x, d = t & 63, q = t >> 6;
  int r0 = blockIdx.x * 64 + q * 16;
  float su = 0.f, sp = 0.f;
#pragma unroll 4
  for (int i = r0; i < r0 + 16; ++i) {
    su = fmaf(cu[i], ue[i * DIM + d], su);
    sp = fmaf(cp[i], pe[i * DIM + d], sp);
  }
  smu[q][d] = su; smp[q][d] = sp;
  __syncthreads();
  if (t < 64) {
    atomicAdd(&S[64 + d],  smu[0][d] + smu[1][d] + smu[2][d] + smu[3][d]);
    atomicAdd(&S[128 + d], smp[0][d] + smp[1][d] + smp[2][d] + smp[3][d]);
  }
}

__global__ void k_colnorm(const float* __restrict__ S,
                          float* __restrict__ c_u, float* __restrict__ c_p) {
  int t = threadIdx.x;            // 128 threads = 2 waves
  int d = t & 63;
  float v = (t < 64) ? S[64 + d] : S[128 + d];
  float n = wred64(v * v);        // wave-local: wave0=u side, wave1=p side
  float inv = 1.f / fmaxf(sqrtf(n), 1e-12f);
  if (t < 64) c_u[d] = v * inv;
  else        c_p[d] = v * inv;
}

// ---------------- per-row sims (wave per row) ----------------
__global__ void k_sims(const float* __restrict__ An_u, const float* __restrict__ Pn_u,
                       const float* __restrict__ An_p, const float* __restrict__ Pn_p,
                       const float* __restrict__ c_u, const float* __restrict__ c_p,
                       const int* __restrict__ perm, const int* __restrict__ inv,
                       float* __restrict__ dis_u, float* __restrict__ col_u,
                       float* __restrict__ posd_u, float* __restrict__ cross_u,
                       float* __restrict__ dis_p, float* __restrict__ col_p,
                       float* __restrict__ posd_p, float* __restrict__ cross_p) {
  int gid = blockIdx.x * blockDim.x + threadIdx.x;
  int r = gid >> 6, d = gid & 63;
  int pr = perm[r], ir = inv[r];
  float au = An_u[r * DIM + d], pu = Pn_u[r * DIM + d];
  float ap = An_p[r * DIM + d], pp = Pn_p[r * DIM + d];
  float r0 = au * An_u[pr * DIM + d];
  float r1 = au * c_u[d];
  float r2 = au * pu;
  float r3 = au * Pn_u[ir * DIM + d];
  float r4 = ap * An_p[pr * DIM + d];
  float r5 = ap * c_p[d];
  float r6 = ap * pp;
  float r7 = ap * Pn_p[ir * DIM + d];
  for (int o = 32; o > 0; o >>= 1) {
    r0 += __shfl_xor(r0, o); r1 += __shfl_xor(r1, o); r2 += __shfl_xor(r2, o);
    r3 += __shfl_xor(r3, o); r4 += __shfl_xor(r4, o); r5 += __shfl_xor(r5, o);
    r6 += __shfl_xor(r6, o); r7 += __shfl_xor(r7, o);
  }
  if (d == 0) {
    dis_u[r] = r0 * INVT; col_u[r] = r1 * INVT; posd_u[r] = r2 * INVT; cross_u[r] = r3 * INVT;
    dis_p[r] = r4 * INVT; col_p[r] = r5 * INVT; posd_p[r] = r6 * INVT; cross_p[r] = r7 * INVT;
  }
}

// ---------------- MFMA fused matmul + fixed-shift sumexp over G = An @ Pn^T / T ----------
// wave = 16 rows; block = 4 waves = 64 rows; col dim split 8 ways -> grid 512 blocks.
// logits bounded by INVT => fixed shift M0; partials combine by atomicAdd.
__global__ __launch_bounds__(256) void k_lse_mfma(const unsigned short* __restrict__ Anh,
                                                  const unsigned short* __restrict__ Pnh,
                                                  float* __restrict__ s_row) {
  const float C1 = INVT * 1.4426950408889634f;   // INVT*log2(e)
  int rb = blockIdx.x >> 3, cb = blockIdx.x & 7;
  int w = threadIdx.x >> 6, lane = threadIdx.x & 63;
  int r0 = rb * 64 + w * 16;
  int arow = r0 + (lane & 15);
  int koff = (lane >> 4) * 8;
  v8s a_lo = *(const v8s*)&Anh[arow * DIM + koff];
  v8s a_hi = *(const v8s*)&Anh[arow * DIM + koff + 32];
  float s0 = 0.f, s1 = 0.f, s2 = 0.f, s3 = 0.f;
  int cbase = cb * 512;
#pragma unroll 2
  for (int c0 = cbase; c0 < cbase + 512; c0 += 16) {
    int brow = c0 + (lane & 15);
    v8s b_lo = *(const v8s*)&Pnh[brow * DIM + koff];
    v8s b_hi = *(const v8s*)&Pnh[brow * DIM + koff + 32];
    f32x4 acc = {0.f, 0.f, 0.f, 0.f};
    acc = __builtin_amdgcn_mfma_f32_16x16x32_bf16(a_lo, b_lo, acc, 0, 0, 0);
    acc = __builtin_amdgcn_mfma_f32_16x16x32_bf16(a_hi, b_hi, acc, 0, 0, 0);
    s0 += exp2f(fmaf(acc[0], C1, -C1));
    s1 += exp2f(fmaf(acc[1], C1, -C1));
    s2 += exp2f(fmaf(acc[2], C1, -C1));
    s3 += exp2f(fmaf(acc[3], C1, -C1));
  }
  // sum the 16 col-slots of each row (C/D: col=lane&15, row=(lane>>4)*4+reg)
  for (int o = 1; o <= 8; o <<= 1) {
    s0 += __shfl_xor(s0, o); s1 += __shfl_xor(s1, o);
    s2 += __shfl_xor(s2, o); s3 += __shfl_xor(s3, o);
  }
  if ((lane & 15) == 0) {
    int rq = r0 + (lane >> 4) * 4;
    atomicAdd(&s_row[rq + 0], s0);
    atomicAdd(&s_row[rq + 1], s1);
    atomicAdd(&s_row[rq + 2], s2);
    atomicAdd(&s_row[rq + 3], s3);
  }
}

// ---------------- final combine (single block) — OUTPUT IS FLOAT32 ----------------
__global__ void k_final(const float* __restrict__ m_u, const float* __restrict__ s_u,
                        const float* __restrict__ dis_u, const float* __restrict__ col_u,
                        const float* __restrict__ posd_u, const float* __restrict__ cross_u,
                        const float* __restrict__ m_p, const float* __restrict__ s_p,
                        const float* __restrict__ dis_p, const float* __restrict__ col_p,
                        const float* __restrict__ posd_p, const float* __restrict__ cross_p,
                        const float* __restrict__ pos_sc, const float* __restrict__ neg_sc,
                        const float* __restrict__ nms, const int* __restrict__ inv,
                        const float* __restrict__ S, float* __restrict__ out) {
  __shared__ float red[6][256];
  int t = threadIdx.x;
  float lpu = 0.f, lnu = 0.f, lpp = 0.f, lnp = 0.f, bp = 0.f, bn = 0.f;
  for (int r = t; r < BATCH; r += 256) {
    int ir = inv[r];
    {
      float M = m_u[r], Sv = s_u[r];
      float d2 = col_u[r];
      float d1 = dis_u[r];
      float nm2 = fmaxf(M, fmaxf(d1, d2));
      float ss = Sv * __expf(M - nm2) + __expf(d1 - nm2) + __expf(d2 - nm2);
      lpu += nm2 + logf(ss) - posd_u[r];
      float d1n = dis_u[ir];
      nm2 = fmaxf(M, fmaxf(d1n, d2));
      ss = Sv * __expf(M - nm2) + __expf(d1n - nm2) + __expf(d2 - nm2);
      lnu += nm2 + logf(ss) - cross_u[r];
    }
    {
      float M = m_p[r], Sv = s_p[r];
      float d2 = col_p[r];
      float d1 = dis_p[r];
      float nm2 = fmaxf(M, fmaxf(d1, d2));
      float ss = Sv * __expf(M - nm2) + __expf(d1 - nm2) + __expf(d2 - nm2);
      lpp += nm2 + logf(ss) - posd_p[r];
      float d1n = dis_p[ir];
      nm2 = fmaxf(M, fmaxf(d1n, d2));
      ss = Sv * __expf(M - nm2) + __expf(d1n - nm2) + __expf(d2 - nm2);
      lnp += nm2 + logf(ss) - cross_p[r];
    }
    float ps = pos_sc[r];
    bp += softplusf(neg_sc[r] - ps);
    bn += softplusf(nms[r] - ps);
  }
  red[0][t] = lpu; red[1][t] = lnu; red[2][t] = lpp;
  red[3][t] = lnp; red[4][t] = bp;  red[5][t] = bn;
  __syncthreads();
  for (int off = 128; off > 0; off >>= 1) {
    if (t < off)
      for (int c = 0; c < 6; c++) red[c][t] += red[c][t + off];
    __syncthreads();
  }
  if (t == 0) {
    const float inv_b = 1.f / (float)BATCH;
    float mbu = S[1] * inv_b;            // mean(beta_u)
    float b   = S[2] * inv_b;            // mean(beta_i)
    float cl_u = mbu * (red[0][0] * inv_b) + (1.f - mbu) * (red[1][0] * inv_b);
    float cl_p = b   * (red[2][0] * inv_b) + (1.f - b)   * (red[3][0] * inv_b);
    float main_m = b * (red[4][0] * inv_b) + (1.f - b) * (red[5][0] * inv_b);
    float reg = REGC * S[0] * inv_b;
    float loss = main_m + LAMBDA * (cl_u + cl_p) + reg;
    out[0] = loss;                       // float32
  }
}

extern "C" void kernel_launch(void* const* d_in, const int* in_sizes, int n_in,
                              void* d_out, int out_size, void* d_ws, size_t ws_size,
                              hipStream_t stream) {
  const float* uemb   = (const float*)d_in[0];
  const float* iemb   = (const float*)d_in[1];
  const int*   rows   = (const int*)d_in[2];
  const int*   cols   = (const int*)d_in[3];
  const float* vals   = (const float*)d_in[4];
  const int*   user   = (const int*)d_in[5];
  const int*   pos    = (const int*)d_in[6];
  const int*   neg    = (const int*)d_in[7];
  const float* beta_u = (const float*)d_in[8];
  const float* beta_i = (const float*)d_in[9];
  const int*   perm   = (const int*)d_in[10];
  const float* cu     = (const float*)d_in[11];
  const float* cp     = (const float*)d_in[12];

  char* w = (char*)d_ws;
  size_t off = 0;
  auto alloc = [&](size_t bytes) -> char* {
    char* p = w + off;
    off += (bytes + 255) & ~(size_t)255;
    return p;
  };
  float* cur     = (float*)alloc((size_t)ND * 4);
  float* nxt     = (float*)alloc((size_t)ND * 4);
  float* acc     = (float*)alloc((size_t)ND * 4);
  int2*  ev      = (int2*) alloc((size_t)NNZ * 8);
  int*   row_ptr = (int*)  alloc((size_t)(NN + 1) * 4);
  int*   cnt     = (int*)  alloc((size_t)NN * 4);
  int*   bcur    = (int*)  alloc((size_t)NB * 4);
  int*   partial = (int*)  alloc(4096);
  float* ue      = (float*)alloc((size_t)BATCH * DIM * 4);
  float* pe      = (float*)alloc((size_t)BATCH * DIM * 4);
  float* ne      = (float*)alloc((size_t)BATCH * DIM * 4);
  float* An_u    = (float*)alloc((size_t)BATCH * DIM * 4);
  float* Pn_u    = (float*)alloc((size_t)BATCH * DIM * 4);
  float* An_p    = (float*)alloc((size_t)BATCH * DIM * 4);
  float* Pn_p    = (float*)alloc((size_t)BATCH * DIM * 4);
  unsigned short* An_uh = (unsigned short*)alloc((size_t)BATCH * DIM * 2);
  unsigned short* Pn_uh = (unsigned short*)alloc((size_t)BATCH * DIM * 2);
  unsigned short* An_ph = (unsigned short*)alloc((size_t)BATCH * DIM * 2);
  unsigned short* Pn_ph = (unsigned short*)alloc((size_t)BATCH * DIM * 2);
  float* pos_sc  = (float*)alloc((size_t)BATCH * 4);
  float* neg_sc  = (float*)alloc((size_t)BATCH * 4);
  float* nms     = (float*)alloc((size_t)BATCH * 4);
  float* dis_u   = (float*)alloc((size_t)BATCH * 4);
  float* col_u   = (float*)alloc((size_t)BATCH * 4);
  float* posd_u  = (float*)alloc((size_t)BATCH * 4);
  float* cross_u = (float*)alloc((size_t)BATCH * 4);
  float* m_u     = (float*)alloc((size_t)BATCH * 4);
  float* s_u     = (float*)alloc((size_t)BATCH * 4);
  float* dis_p   = (float*)alloc((size_t)BATCH * 4);
  float* col_p   = (float*)alloc((size_t)BATCH * 4);
  float* posd_p  = (float*)alloc((size_t)BATCH * 4);
  float* cross_p = (float*)alloc((size_t)BATCH * 4);
  float* m_p     = (float*)alloc((size_t)BATCH * 4);
  float* s_p     = (float*)alloc((size_t)BATCH * 4);
  int*   invp    = (int*)  alloc((size_t)BATCH * 4);
  float* c_u     = (float*)alloc(256);
  float* c_p     = (float*)alloc(256);
  float* S       = (float*)alloc(1024);

  // tmp (int4 per edge, 51.2MB) aliases cur+nxt — dead until k_init4 runs after CSR build
  int4* tmp = (int4*)cur;

  // 1. zero counters + preset LSE state (m=M0, s=0)
  k_zero<<<(NN + 255) / 256, 256, 0, stream>>>(cnt, S, m_u, s_u, m_p, s_p);
  // 2. CSR build (runs BEFORE init so tmp can alias cur/nxt)
  k_hist<<<(NNZ + 255) / 256, 256, 0, stream>>>(rows, cnt);
  k_scan1<<<SNB, 256, 0, stream>>>(cnt, partial);
  k_scan2<<<1, 64, 0, stream>>>(partial, row_ptr);
  k_scan3<<<SNB, 256, 0, stream>>>(cnt, partial, row_ptr);
  k_binit<<<2, 256, 0, stream>>>(row_ptr, bcur);
  k_bucketA<<<(NNZ + ACHUNK - 1) / ACHUNK, 256, 0, stream>>>(rows, cols, vals, bcur, tmp);
  k_bucketB<<<NB, 256, 0, stream>>>(row_ptr, tmp, ev);
  // 3. init cur = acc = x
  k_init4<<<(ND / 4 + 255) / 256, 256, 0, stream>>>((const float4*)uemb, (const float4*)iemb,
                                                    (float4*)cur, (float4*)acc);
  // 4. three GCN layers
  {
    float* a = cur;
    float* b2 = nxt;
    for (int l = 0; l < 3; l++) {
      k_spmv<<<(NN + 3) / 4, 256, 0, stream>>>(row_ptr, ev, a, b2, acc);
      float* t2 = a; a = b2; b2 = t2;
    }
  }
  // 5. batch gather (+ reg/beta sums)
  k_gather<<<(BATCH * DIM) / 256, 256, 0, stream>>>(acc, user, pos, neg, uemb, iemb,
                                                    beta_u, beta_i, ue, pe, ne, S);
  k_invperm<<<(BATCH + 255) / 256, 256, 0, stream>>>(perm, invp);
  // 6. mixes, scores, normalization (+ bf16 copies for MFMA)
  k_mixnorm<<<(BATCH * DIM) / 256, 256, 0, stream>>>(ue, pe, ne, beta_u, beta_i, perm,
                                                     An_u, Pn_u, An_p, Pn_p,
                                                     An_uh, Pn_uh, An_ph, Pn_ph,
                                                     pos_sc, neg_sc, nms);
  k_colpart<<<BATCH / 64, 256, 0, stream>>>(ue, pe, cu, cp, S);
  k_colnorm<<<1, 128, 0, stream>>>(S, c_u, c_p);
  k_sims<<<(BATCH * DIM) / 256, 256, 0, stream>>>(An_u, Pn_u, An_p, Pn_p, c_u, c_p,
                                                  perm, invp,
                                                  dis_u, col_u, posd_u, cross_u,
                                                  dis_p, col_p, posd_p, cross_p);
  // 7. MFMA matmul + fixed-shift sumexp (user side, pos side)
  k_lse_mfma<<<512, 256, 0, stream>>>(An_uh, Pn_uh, s_u);
  k_lse_mfma<<<512, 256, 0, stream>>>(An_ph, Pn_ph, s_p);
  // 8. final combine
  k_final<<<1, 256, 0, stream>>>(m_u, s_u, dis_u, col_u, posd_u, cross_u,
                                 m_p, s_p, dis_p, col_p, posd_p, cross_p,
                                 pos_sc, neg_sc, nms, invp, S,
                                 (float*)d_out);
}

// Round 6
// 582.739 us; speedup vs baseline: 2.7608x; 1.4169x over previous
//
#include <hip/hip_runtime.h>
#include <hip/hip_bf16.h>

#define NUSERS 100000
#define NITEMS 50000
#define NN     150001          // total nodes
#define NNZ    3200000         // 2 * NNZ_INTER
#define BATCH  4096
#define DIM    64
#define ND     (NN * DIM)
#define ALPHA  0.25f           // 1/(N_LAYERS+1)
#define INVT   5.0f            // 1/TEMP
#define LAMBDA 0.1f
#define REGC   1.0e-4f
#define SCHUNK 2048
#define SNB    74              // ceil(150001/2048)
#define BKSH   9               // 512 nodes per bucket
#define NB     293             // ceil(150001/512)
#define ACHUNK 4096            // edges per bucketA block
#define M0     5.0f            // fixed LSE shift: logits = sim/T ∈ [-5,5]
#define NGB    1024            // k_gather blocks

typedef __attribute__((ext_vector_type(8))) short v8s;    // 8 bf16 (4 VGPRs)
typedef __attribute__((ext_vector_type(4))) float f32x4;  // MFMA acc

__device__ __forceinline__ float wred64(float v) {
  for (int o = 32; o > 0; o >>= 1) v += __shfl_xor(v, o);
  return v;
}

__device__ __forceinline__ float softplusf(float x) {
  return (x > 20.f) ? x : log1pf(__expf(x));
}

__device__ __forceinline__ unsigned short bf16r(float v) {
  unsigned x = __float_as_uint(v);
  return (unsigned short)((x + 0x7fff + ((x >> 16) & 1)) >> 16);   // RNE
}

__device__ __forceinline__ float bf2f(unsigned short h) {
  return __uint_as_float((unsigned)h << 16);
}

// ---------------- zero scratch + preset LSE state ----------------
__global__ void k_zero(int* __restrict__ cnt, float* __restrict__ S,
                       float* __restrict__ m_u, float* __restrict__ s_u,
                       float* __restrict__ m_p, float* __restrict__ s_p) {
  int i = blockIdx.x * blockDim.x + threadIdx.x;
  if (i < NN) cnt[i] = 0;
  if (i < 256) S[i] = 0.f;
  if (i < BATCH) { s_u[i] = 0.f; s_p[i] = 0.f; m_u[i] = M0; m_p[i] = M0; }
}

// ---------------- x = concat(user_emb, item_emb); cur_h = bf16(x); acc = x ----------------
__global__ void k_inith(const float4* __restrict__ uemb, const float4* __restrict__ iemb,
                        ushort4* __restrict__ cur_h, float4* __restrict__ acc) {
  int q = blockIdx.x * blockDim.x + threadIdx.x;   // quads: ND/4
  if (q >= ND / 4) return;
  int n = q >> 4;                                   // 16 quads per node
  float4 v = (n < NUSERS) ? uemb[q] : iemb[q - NUSERS * 16];
  acc[q] = v;
  ushort4 h;
  h.x = bf16r(v.x); h.y = bf16r(v.y); h.z = bf16r(v.z); h.w = bf16r(v.w);
  cur_h[q] = h;
}

// ---------------- CSR build ----------------
__global__ void k_hist(const int* __restrict__ rows, int* __restrict__ cnt) {
  int e = blockIdx.x * blockDim.x + threadIdx.x;
  if (e < NNZ) atomicAdd(&cnt[rows[e]], 1);
}

__global__ void k_scan1(const int* __restrict__ cnt, int* __restrict__ partial) {
  __shared__ int sm[256];
  int b = blockIdx.x, t = threadIdx.x;
  int base = b * SCHUNK + t * 8;
  int s = 0;
#pragma unroll
  for (int k = 0; k < 8; k++) { int i = base + k; if (i < NN) s += cnt[i]; }
  sm[t] = s; __syncthreads();
  for (int off = 128; off > 0; off >>= 1) { if (t < off) sm[t] += sm[t + off]; __syncthreads(); }
  if (t == 0) partial[b] = sm[0];
}

__global__ void k_scan2(int* __restrict__ partial, int* __restrict__ row_ptr) {
  if (blockIdx.x == 0 && threadIdx.x == 0) {
    int run = 0;
    for (int i = 0; i < SNB; i++) { int v = partial[i]; partial[i] = run; run += v; }
    row_ptr[NN] = run;  // == NNZ
  }
}

__global__ void k_scan3(const int* __restrict__ cnt, const int* __restrict__ partial,
                        int* __restrict__ row_ptr) {
  __shared__ int sm[256];
  int b = blockIdx.x, t = threadIdx.x;
  int base = b * SCHUNK + t * 8;
  int loc[8];
  int s = 0;
#pragma unroll
  for (int k = 0; k < 8; k++) { int i = base + k; int c = (i < NN) ? cnt[i] : 0; loc[k] = c; s += c; }
  sm[t] = s; __syncthreads();
  for (int off = 1; off < 256; off <<= 1) {
    int v = sm[t];
    if (t >= off) v += sm[t - off];
    __syncthreads(); sm[t] = v; __syncthreads();
  }
  int run = sm[t] - s + partial[b];  // exclusive prefix
#pragma unroll
  for (int k = 0; k < 8; k++) {
    int i = base + k;
    if (i < NN) { row_ptr[i] = run; run += loc[k]; }
  }
}

__global__ void k_binit(const int* __restrict__ row_ptr, int* __restrict__ bcur) {
  int b = blockIdx.x * blockDim.x + threadIdx.x;
  if (b < NB) bcur[b] = row_ptr[b << BKSH];
}

// ---------------- bucket pass A: LDS counting-sort into 512-node buckets, coalesced flush ----
__global__ __launch_bounds__(256) void k_bucketA(const int* __restrict__ rows,
                                                 const int* __restrict__ cols,
                                                 const float* __restrict__ vals,
                                                 int* __restrict__ bcur,
                                                 int4* __restrict__ tmp) {
  __shared__ int lhist[NB];
  __shared__ int lscan[NB];
  __shared__ int ldelta[NB];
  __shared__ int lcnt[NB];
  __shared__ int4 ent[ACHUNK];
  int t = threadIdx.x;
  int base = blockIdx.x * ACHUNK;
  for (int b = t; b < NB; b += 256) { lhist[b] = 0; lcnt[b] = 0; }
  __syncthreads();
  int rowv[16], colv[16], valv[16], bkt[16];
  int nval = 0;
#pragma unroll
  for (int k = 0; k < 16; k++) {
    int e = base + t + k * 256;                 // coalesced
    if (e < NNZ) {
      rowv[k] = rows[e]; colv[k] = cols[e]; valv[k] = __float_as_int(vals[e]);
      bkt[k] = rowv[k] >> BKSH;
      atomicAdd(&lhist[bkt[k]], 1);
      nval = k + 1;
    }
  }
  __syncthreads();
  if (t == 0) {
    int run = 0;
    for (int b = 0; b < NB; b++) { lscan[b] = run; run += lhist[b]; }
  }
  __syncthreads();
  for (int b = t; b < NB; b += 256) {
    int c = lhist[b];
    int g = (c > 0) ? atomicAdd(&bcur[b], c) : 0;
    ldelta[b] = g - lscan[b];
  }
  __syncthreads();
#pragma unroll
  for (int k = 0; k < 16; k++) {
    if (k < nval) {
      int b = bkt[k];
      int lp = atomicAdd(&lcnt[b], 1);
      ent[lscan[b] + lp] = make_int4(colv[k], valv[k], rowv[k], ldelta[b]);
    }
  }
  __syncthreads();
  int tot = min(ACHUNK, NNZ - base);
  for (int j = t; j < tot; j += 256) {
    int4 E = ent[j];
    tmp[E.w + j] = E;                           // contiguous run per bucket -> full lines
  }
}

// ---------------- bucket pass B: per-bucket final scatter (writes stay in one XCD's L2) ----
__global__ __launch_bounds__(256) void k_bucketB(const int* __restrict__ row_ptr,
                                                 const int4* __restrict__ tmp,
                                                 int2* __restrict__ ev) {
  __shared__ int lcnt[512];
  int b = blockIdx.x;
  int nbase = b << BKSH;
  for (int i = threadIdx.x; i < 512; i += 256) lcnt[i] = 0;
  __syncthreads();
  int beg = row_ptr[nbase];
  int end = (b == NB - 1) ? NNZ : row_ptr[nbase + 512];
  for (int j = beg + threadIdx.x; j < end; j += 256) {
    int4 E = tmp[j];
    int lp = atomicAdd(&lcnt[E.z - nbase], 1);
    ev[row_ptr[E.z] + lp] = make_int2(E.x, E.y);
  }
}

// ---------------- gather SpMV (bf16 in, bf16+fp32 out): wave/node, 4 grp x 16 lanes x 4 dims
__global__ __launch_bounds__(256) void k_spmv_h(const int* __restrict__ row_ptr,
                                                const int2* __restrict__ ev,
                                                const unsigned short* __restrict__ cur_h,
                                                unsigned short* __restrict__ nxt_h,
                                                float* __restrict__ acc) {
  int node = blockIdx.x * 4 + (threadIdx.x >> 6);
  if (node >= NN) return;
  node = __builtin_amdgcn_readfirstlane(node);
  int lane = threadIdx.x & 63;
  int g = lane >> 4;                 // edge group 0..3 (edges ≡ g mod 4)
  int d4 = (lane & 15) << 2;         // 4 dims per lane
  int beg = row_ptr[node], end = row_ptr[node + 1];
  float4 s = make_float4(0.f, 0.f, 0.f, 0.f);
  int e = beg + g;
  for (; e + 12 < end; e += 16) {    // 4 edges in flight per lane
    int2 E0 = ev[e], E1 = ev[e + 4], E2 = ev[e + 8], E3 = ev[e + 12];
    ushort4 h0 = *(const ushort4*)&cur_h[E0.x * DIM + d4];
    ushort4 h1 = *(const ushort4*)&cur_h[E1.x * DIM + d4];
    ushort4 h2 = *(const ushort4*)&cur_h[E2.x * DIM + d4];
    ushort4 h3 = *(const ushort4*)&cur_h[E3.x * DIM + d4];
    float v0 = __int_as_float(E0.y), v1 = __int_as_float(E1.y);
    float v2 = __int_as_float(E2.y), v3 = __int_as_float(E3.y);
    s.x = fmaf(v0, bf2f(h0.x), s.x); s.y = fmaf(v0, bf2f(h0.y), s.y);
    s.z = fmaf(v0, bf2f(h0.z), s.z); s.w = fmaf(v0, bf2f(h0.w), s.w);
    s.x = fmaf(v1, bf2f(h1.x), s.x); s.y = fmaf(v1, bf2f(h1.y), s.y);
    s.z = fmaf(v1, bf2f(h1.z), s.z); s.w = fmaf(v1, bf2f(h1.w), s.w);
    s.x = fmaf(v2, bf2f(h2.x), s.x); s.y = fmaf(v2, bf2f(h2.y), s.y);
    s.z = fmaf(v2, bf2f(h2.z), s.z); s.w = fmaf(v2, bf2f(h2.w), s.w);
    s.x = fmaf(v3, bf2f(h3.x), s.x); s.y = fmaf(v3, bf2f(h3.y), s.y);
    s.z = fmaf(v3, bf2f(h3.z), s.z); s.w = fmaf(v3, bf2f(h3.w), s.w);
  }
  for (; e < end; e += 4) {
    int2 E0 = ev[e];
    float v0 = __int_as_float(E0.y);
    ushort4 h0 = *(const ushort4*)&cur_h[E0.x * DIM + d4];
    s.x = fmaf(v0, bf2f(h0.x), s.x); s.y = fmaf(v0, bf2f(h0.y), s.y);
    s.z = fmaf(v0, bf2f(h0.z), s.z); s.w = fmaf(v0, bf2f(h0.w), s.w);
  }
  // reduce across the 4 edge groups
  s.x += __shfl_xor(s.x, 16); s.y += __shfl_xor(s.y, 16);
  s.z += __shfl_xor(s.z, 16); s.w += __shfl_xor(s.w, 16);
  s.x += __shfl_xor(s.x, 32); s.y += __shfl_xor(s.y, 32);
  s.z += __shfl_xor(s.z, 32); s.w += __shfl_xor(s.w, 32);
  if (g == 0) {
    int o = node * DIM + d4;
    ushort4 hn;
    hn.x = bf16r(s.x); hn.y = bf16r(s.y); hn.z = bf16r(s.z); hn.w = bf16r(s.w);
    *(ushort4*)&nxt_h[o] = hn;
    float4 a = *(const float4*)&acc[o];
    a.x += s.x; a.y += s.y; a.z += s.z; a.w += s.w;
    *(float4*)&acc[o] = a;
  }
}

// ---------------- batch gather + per-block reg partial (NO global atomics) ----------------
__global__ void k_gather(const float* __restrict__ acc, const int* __restrict__ user,
                         const int* __restrict__ pos, const int* __restrict__ neg,
                         const float* __restrict__ uemb, const float* __restrict__ iemb,
                         float* __restrict__ ue, float* __restrict__ pe, float* __restrict__ ne,
                         float* __restrict__ partR) {
  __shared__ float sred[256];
  int t = threadIdx.x;
  int gid = blockIdx.x * 256 + t;    // BATCH*64 exact
  int i = gid >> 6, d = gid & 63;
  int u = user[i], p = pos[i], n = neg[i];
  ue[gid] = ALPHA * acc[u * DIM + d];
  pe[gid] = ALPHA * acc[(NUSERS + p) * DIM + d];
  ne[gid] = ALPHA * acc[(NUSERS + n) * DIM + d];
  float ru = uemb[u * DIM + d], rp = iemb[p * DIM + d], rn = iemb[n * DIM + d];
  sred[t] = ru * ru + rp * rp + rn * rn;
  __syncthreads();
  for (int off = 128; off > 0; off >>= 1) {
    if (t < off) sred[t] += sred[t + off];
    __syncthreads();
  }
  if (t == 0) partR[blockIdx.x] = sred[0];
}

// ---------------- small sums: S[0]=reg partials, S[1]=sum(beta_u), S[2]=sum(beta_i) -------
__global__ void k_small(const float* __restrict__ beta_u, const float* __restrict__ beta_i,
                        const float* __restrict__ partR, float* __restrict__ S) {
  __shared__ float a[256], b[256], c[256];
  int t = threadIdx.x;
  float su = 0.f, si = 0.f, sr = 0.f;
  for (int j = t; j < BATCH; j += 256) { su += beta_u[j]; si += beta_i[j]; }
  for (int j = t; j < NGB; j += 256) sr += partR[j];
  a[t] = su; b[t] = si; c[t] = sr;
  __syncthreads();
  for (int off = 128; off > 0; off >>= 1) {
    if (t < off) { a[t] += a[t + off]; b[t] += b[t + off]; c[t] += c[t + off]; }
    __syncthreads();
  }
  if (t == 0) { S[0] = c[0]; S[1] = a[0]; S[2] = b[0]; }
}

__global__ void k_invperm(const int* __restrict__ perm, int* __restrict__ inv) {
  int i = blockIdx.x * blockDim.x + threadIdx.x;
  if (i < BATCH) inv[perm[i]] = i;
}

// ---------------- mixes, scores, row normalization (wave per row); also emit bf16 ----------
__global__ void k_mixnorm(const float* __restrict__ ue, const float* __restrict__ pe,
                          const float* __restrict__ ne, const float* __restrict__ beta_u,
                          const float* __restrict__ beta_i, const int* __restrict__ perm,
                          float* __restrict__ An_u, float* __restrict__ Pn_u,
                          float* __restrict__ An_p, float* __restrict__ Pn_p,
                          unsigned short* __restrict__ An_uh, unsigned short* __restrict__ Pn_uh,
                          unsigned short* __restrict__ An_ph, unsigned short* __restrict__ Pn_ph,
                          float* __restrict__ pos_sc, float* __restrict__ neg_sc,
                          float* __restrict__ nms) {
  int gid = blockIdx.x * blockDim.x + threadIdx.x;   // BATCH*64 exact
  int i = gid >> 6, d = gid & 63;
  int pi = perm[i];
  float uei = ue[i * DIM + d], pei = pe[i * DIM + d], nei = ne[i * DIM + d];
  float ud = ue[pi * DIM + d], pd = pe[pi * DIM + d], nd = ne[pi * DIM + d];
  float bu = beta_u[i], bi = beta_i[i];
  float um = bu * uei + (1.f - bu) * ud;
  float pm = bi * pei + (1.f - bi) * pd;
  float nm = bi * nei + (1.f - bi) * nd;
  float r0 = uei * pei, r1 = uei * nei, r2 = uei * nm;
  float r3 = uei * uei, r4 = um * um, r5 = pei * pei, r6 = pm * pm;
  for (int o = 32; o > 0; o >>= 1) {
    r0 += __shfl_xor(r0, o); r1 += __shfl_xor(r1, o); r2 += __shfl_xor(r2, o);
    r3 += __shfl_xor(r3, o); r4 += __shfl_xor(r4, o); r5 += __shfl_xor(r5, o);
    r6 += __shfl_xor(r6, o);
  }
  if (d == 0) { pos_sc[i] = r0; neg_sc[i] = r1; nms[i] = r2; }
  float inu  = 1.f / fmaxf(sqrtf(r3), 1e-12f);
  float inum = 1.f / fmaxf(sqrtf(r4), 1e-12f);
  float inp  = 1.f / fmaxf(sqrtf(r5), 1e-12f);
  float inpm = 1.f / fmaxf(sqrtf(r6), 1e-12f);
  float a0 = uei * inu, p0 = um * inum, a1 = pei * inp, p1 = pm * inpm;
  An_u[gid] = a0;  Pn_u[gid] = p0;  An_p[gid] = a1;  Pn_p[gid] = p1;
  An_uh[gid] = bf16r(a0); Pn_uh[gid] = bf16r(p0);
  An_ph[gid] = bf16r(a1); Pn_ph[gid] = bf16r(p1);
}

// ---------------- collective-mix: parallel partial sums (64 blocks) ----------------
__global__ void k_colpart(const float* __restrict__ ue, const float* __restrict__ pe,
                          const float* __restrict__ cu, const float* __restrict__ cp,
                          float* __restrict__ S) {
  __shared__ float smu[4][64], smp[4][64];
  int t = threadIdx.x, d = t & 63, q = t >> 6;
  int r0 = blockIdx.x * 64 + q * 16;
  float su = 0.f, sp = 0.f;
#pragma unroll 4
  for (int i = r0; i < r0 + 16; ++i) {
    su = fmaf(cu[i], ue[i * DIM + d], su);
    sp = fmaf(cp[i], pe[i * DIM + d], sp);
  }
  smu[q][d] = su; smp[q][d] = sp;
  __syncthreads();
  if (t < 64) {
    atomicAdd(&S[64 + d],  smu[0][d] + smu[1][d] + smu[2][d] + smu[3][d]);
    atomicAdd(&S[128 + d], smp[0][d] + smp[1][d] + smp[2][d] + smp[3][d]);
  }
}

__global__ void k_colnorm(const float* __restrict__ S,
                          float* __restrict__ c_u, float* __restrict__ c_p) {
  int t = threadIdx.x;            // 128 threads = 2 waves
  int d = t & 63;
  float v = (t < 64) ? S[64 + d] : S[128 + d];
  float n = wred64(v * v);        // wave-local: wave0=u side, wave1=p side
  float inv = 1.f / fmaxf(sqrtf(n), 1e-12f);
  if (t < 64) c_u[d] = v * inv;
  else        c_p[d] = v * inv;
}

// ---------------- per-row sims (wave per row) ----------------
__global__ void k_sims(const float* __restrict__ An_u, const float* __restrict__ Pn_u,
                       const float* __restrict__ An_p, const float* __restrict__ Pn_p,
                       const float* __restrict__ c_u, const float* __restrict__ c_p,
                       const int* __restrict__ perm, const int* __restrict__ inv,
                       float* __restrict__ dis_u, float* __restrict__ col_u,
                       float* __restrict__ posd_u, float* __restrict__ cross_u,
                       float* __restrict__ dis_p, float* __restrict__ col_p,
                       float* __restrict__ posd_p, float* __restrict__ cross_p) {
  int gid = blockIdx.x * blockDim.x + threadIdx.x;
  int r = gid >> 6, d = gid & 63;
  int pr = perm[r], ir = inv[r];
  float au = An_u[r * DIM + d], pu = Pn_u[r * DIM + d];
  float ap = An_p[r * DIM + d], pp = Pn_p[r * DIM + d];
  float r0 = au * An_u[pr * DIM + d];
  float r1 = au * c_u[d];
  float r2 = au * pu;
  float r3 = au * Pn_u[ir * DIM + d];
  float r4 = ap * An_p[pr * DIM + d];
  float r5 = ap * c_p[d];
  float r6 = ap * pp;
  float r7 = ap * Pn_p[ir * DIM + d];
  for (int o = 32; o > 0; o >>= 1) {
    r0 += __shfl_xor(r0, o); r1 += __shfl_xor(r1, o); r2 += __shfl_xor(r2, o);
    r3 += __shfl_xor(r3, o); r4 += __shfl_xor(r4, o); r5 += __shfl_xor(r5, o);
    r6 += __shfl_xor(r6, o); r7 += __shfl_xor(r7, o);
  }
  if (d == 0) {
    dis_u[r] = r0 * INVT; col_u[r] = r1 * INVT; posd_u[r] = r2 * INVT; cross_u[r] = r3 * INVT;
    dis_p[r] = r4 * INVT; col_p[r] = r5 * INVT; posd_p[r] = r6 * INVT; cross_p[r] = r7 * INVT;
  }
}

// ---------------- MFMA fused matmul + fixed-shift sumexp over G = An @ Pn^T / T ----------
__global__ __launch_bounds__(256) void k_lse_mfma(const unsigned short* __restrict__ Anh,
                                                  const unsigned short* __restrict__ Pnh,
                                                  float* __restrict__ s_row) {
  const float C1 = INVT * 1.4426950408889634f;   // INVT*log2(e)
  int rb = blockIdx.x >> 3, cb = blockIdx.x & 7;
  int w = threadIdx.x >> 6, lane = threadIdx.x & 63;
  int r0 = rb * 64 + w * 16;
  int arow = r0 + (lane & 15);
  int koff = (lane >> 4) * 8;
  v8s a_lo = *(const v8s*)&Anh[arow * DIM + koff];
  v8s a_hi = *(const v8s*)&Anh[arow * DIM + koff + 32];
  float s0 = 0.f, s1 = 0.f, s2 = 0.f, s3 = 0.f;
  int cbase = cb * 512;
#pragma unroll 2
  for (int c0 = cbase; c0 < cbase + 512; c0 += 16) {
    int brow = c0 + (lane & 15);
    v8s b_lo = *(const v8s*)&Pnh[brow * DIM + koff];
    v8s b_hi = *(const v8s*)&Pnh[brow * DIM + koff + 32];
    f32x4 acc = {0.f, 0.f, 0.f, 0.f};
    acc = __builtin_amdgcn_mfma_f32_16x16x32_bf16(a_lo, b_lo, acc, 0, 0, 0);
    acc = __builtin_amdgcn_mfma_f32_16x16x32_bf16(a_hi, b_hi, acc, 0, 0, 0);
    s0 += exp2f(fmaf(acc[0], C1, -C1));
    s1 += exp2f(fmaf(acc[1], C1, -C1));
    s2 += exp2f(fmaf(acc[2], C1, -C1));
    s3 += exp2f(fmaf(acc[3], C1, -C1));
  }
  // sum the 16 col-slots of each row (C/D: col=lane&15, row=(lane>>4)*4+reg)
  for (int o = 1; o <= 8; o <<= 1) {
    s0 += __shfl_xor(s0, o); s1 += __shfl_xor(s1, o);
    s2 += __shfl_xor(s2, o); s3 += __shfl_xor(s3, o);
  }
  if ((lane & 15) == 0) {
    int rq = r0 + (lane >> 4) * 4;
    atomicAdd(&s_row[rq + 0], s0);
    atomicAdd(&s_row[rq + 1], s1);
    atomicAdd(&s_row[rq + 2], s2);
    atomicAdd(&s_row[rq + 3], s3);
  }
}

// ---------------- final combine (single block) — OUTPUT IS FLOAT32 ----------------
__global__ void k_final(const float* __restrict__ m_u, const float* __restrict__ s_u,
                        const float* __restrict__ dis_u, const float* __restrict__ col_u,
                        const float* __restrict__ posd_u, const float* __restrict__ cross_u,
                        const float* __restrict__ m_p, const float* __restrict__ s_p,
                        const float* __restrict__ dis_p, const float* __restrict__ col_p,
                        const float* __restrict__ posd_p, const float* __restrict__ cross_p,
                        const float* __restrict__ pos_sc, const float* __restrict__ neg_sc,
                        const float* __restrict__ nms, const int* __restrict__ inv,
                        const float* __restrict__ S, float* __restrict__ out) {
  __shared__ float red[6][256];
  int t = threadIdx.x;
  float lpu = 0.f, lnu = 0.f, lpp = 0.f, lnp = 0.f, bp = 0.f, bn = 0.f;
  for (int r = t; r < BATCH; r += 256) {
    int ir = inv[r];
    {
      float M = m_u[r], Sv = s_u[r];
      float d2 = col_u[r];
      float d1 = dis_u[r];
      float nm2 = fmaxf(M, fmaxf(d1, d2));
      float ss = Sv * __expf(M - nm2) + __expf(d1 - nm2) + __expf(d2 - nm2);
      lpu += nm2 + logf(ss) - posd_u[r];
      float d1n = dis_u[ir];
      nm2 = fmaxf(M, fmaxf(d1n, d2));
      ss = Sv * __expf(M - nm2) + __expf(d1n - nm2) + __expf(d2 - nm2);
      lnu += nm2 + logf(ss) - cross_u[r];
    }
    {
      float M = m_p[r], Sv = s_p[r];
      float d2 = col_p[r];
      float d1 = dis_p[r];
      float nm2 = fmaxf(M, fmaxf(d1, d2));
      float ss = Sv * __expf(M - nm2) + __expf(d1 - nm2) + __expf(d2 - nm2);
      lpp += nm2 + logf(ss) - posd_p[r];
      float d1n = dis_p[ir];
      nm2 = fmaxf(M, fmaxf(d1n, d2));
      ss = Sv * __expf(M - nm2) + __expf(d1n - nm2) + __expf(d2 - nm2);
      lnp += nm2 + logf(ss) - cross_p[r];
    }
    float ps = pos_sc[r];
    bp += softplusf(neg_sc[r] - ps);
    bn += softplusf(nms[r] - ps);
  }
  red[0][t] = lpu; red[1][t] = lnu; red[2][t] = lpp;
  red[3][t] = lnp; red[4][t] = bp;  red[5][t] = bn;
  __syncthreads();
  for (int off = 128; off > 0; off >>= 1) {
    if (t < off)
      for (int c = 0; c < 6; c++) red[c][t] += red[c][t + off];
    __syncthreads();
  }
  if (t == 0) {
    const float inv_b = 1.f / (float)BATCH;
    float mbu = S[1] * inv_b;            // mean(beta_u)
    float b   = S[2] * inv_b;            // mean(beta_i)
    float cl_u = mbu * (red[0][0] * inv_b) + (1.f - mbu) * (red[1][0] * inv_b);
    float cl_p = b   * (red[2][0] * inv_b) + (1.f - b)   * (red[3][0] * inv_b);
    float main_m = b * (red[4][0] * inv_b) + (1.f - b) * (red[5][0] * inv_b);
    float reg = REGC * S[0] * inv_b;
    float loss = main_m + LAMBDA * (cl_u + cl_p) + reg;
    out[0] = loss;                       // float32
  }
}

extern "C" void kernel_launch(void* const* d_in, const int* in_sizes, int n_in,
                              void* d_out, int out_size, void* d_ws, size_t ws_size,
                              hipStream_t stream) {
  const float* uemb   = (const float*)d_in[0];
  const float* iemb   = (const float*)d_in[1];
  const int*   rows   = (const int*)d_in[2];
  const int*   cols   = (const int*)d_in[3];
  const float* vals   = (const float*)d_in[4];
  const int*   user   = (const int*)d_in[5];
  const int*   pos    = (const int*)d_in[6];
  const int*   neg    = (const int*)d_in[7];
  const float* beta_u = (const float*)d_in[8];
  const float* beta_i = (const float*)d_in[9];
  const int*   perm   = (const int*)d_in[10];
  const float* cu     = (const float*)d_in[11];
  const float* cp     = (const float*)d_in[12];

  char* w = (char*)d_ws;
  size_t off = 0;
  auto alloc = [&](size_t bytes) -> char* {
    char* p = w + off;
    off += (bytes + 255) & ~(size_t)255;
    return p;
  };
  unsigned short* cur_h = (unsigned short*)alloc((size_t)ND * 2);
  unsigned short* nxt_h = (unsigned short*)alloc((size_t)ND * 2);
  float* acc     = (float*)alloc((size_t)ND * 4);
  int2*  ev      = (int2*) alloc((size_t)NNZ * 8);
  int*   row_ptr = (int*)  alloc((size_t)(NN + 1) * 4);
  int*   cnt     = (int*)  alloc((size_t)NN * 4);
  int*   bcur    = (int*)  alloc((size_t)NB * 4);
  int*   partial = (int*)  alloc(4096);
  float* partR   = (float*)alloc((size_t)NGB * 4);
  float* ue      = (float*)alloc((size_t)BATCH * DIM * 4);
  float* pe      = (float*)alloc((size_t)BATCH * DIM * 4);
  float* ne      = (float*)alloc((size_t)BATCH * DIM * 4);
  float* An_u    = (float*)alloc((size_t)BATCH * DIM * 4);
  float* Pn_u    = (float*)alloc((size_t)BATCH * DIM * 4);
  float* An_p    = (float*)alloc((size_t)BATCH * DIM * 4);
  float* Pn_p    = (float*)alloc((size_t)BATCH * DIM * 4);
  unsigned short* An_uh = (unsigned short*)alloc((size_t)BATCH * DIM * 2);
  unsigned short* Pn_uh = (unsigned short*)alloc((size_t)BATCH * DIM * 2);
  unsigned short* An_ph = (unsigned short*)alloc((size_t)BATCH * DIM * 2);
  unsigned short* Pn_ph = (unsigned short*)alloc((size_t)BATCH * DIM * 2);
  float* pos_sc  = (float*)alloc((size_t)BATCH * 4);
  float* neg_sc  = (float*)alloc((size_t)BATCH * 4);
  float* nms     = (float*)alloc((size_t)BATCH * 4);
  float* dis_u   = (float*)alloc((size_t)BATCH * 4);
  float* col_u   = (float*)alloc((size_t)BATCH * 4);
  float* posd_u  = (float*)alloc((size_t)BATCH * 4);
  float* cross_u = (float*)alloc((size_t)BATCH * 4);
  float* m_u     = (float*)alloc((size_t)BATCH * 4);
  float* s_u     = (float*)alloc((size_t)BATCH * 4);
  float* dis_p   = (float*)alloc((size_t)BATCH * 4);
  float* col_p   = (float*)alloc((size_t)BATCH * 4);
  float* posd_p  = (float*)alloc((size_t)BATCH * 4);
  float* cross_p = (float*)alloc((size_t)BATCH * 4);
  float* m_p     = (float*)alloc((size_t)BATCH * 4);
  float* s_p     = (float*)alloc((size_t)BATCH * 4);
  int*   invp    = (int*)  alloc((size_t)BATCH * 4);
  float* c_u     = (float*)alloc(256);
  float* c_p     = (float*)alloc(256);
  float* S       = (float*)alloc(1024);

  // tmp (int4 per edge, 51.2MB) aliases cur_h+nxt_h+acc (76.8MB) — dead until k_inith,
  // which runs AFTER the CSR build.
  int4* tmp = (int4*)cur_h;

  // 1. zero counters + preset LSE state (m=M0, s=0)
  k_zero<<<(NN + 255) / 256, 256, 0, stream>>>(cnt, S, m_u, s_u, m_p, s_p);
  // 2. CSR build
  k_hist<<<(NNZ + 255) / 256, 256, 0, stream>>>(rows, cnt);
  k_scan1<<<SNB, 256, 0, stream>>>(cnt, partial);
  k_scan2<<<1, 64, 0, stream>>>(partial, row_ptr);
  k_scan3<<<SNB, 256, 0, stream>>>(cnt, partial, row_ptr);
  k_binit<<<2, 256, 0, stream>>>(row_ptr, bcur);
  k_bucketA<<<(NNZ + ACHUNK - 1) / ACHUNK, 256, 0, stream>>>(rows, cols, vals, bcur, tmp);
  k_bucketB<<<NB, 256, 0, stream>>>(row_ptr, tmp, ev);
  // 3. init cur_h = bf16(x), acc = x
  k_inith<<<(ND / 4 + 255) / 256, 256, 0, stream>>>((const float4*)uemb, (const float4*)iemb,
                                                    (ushort4*)cur_h, (float4*)acc);
  // 4. three GCN layers (bf16 propagation, fp32 accumulation)
  {
    unsigned short* a = cur_h;
    unsigned short* b2 = nxt_h;
    for (int l = 0; l < 3; l++) {
      k_spmv_h<<<(NN + 3) / 4, 256, 0, stream>>>(row_ptr, ev, a, b2, acc);
      unsigned short* t2 = a; a = b2; b2 = t2;
    }
  }
  // 5. batch gather (+ per-block reg partials) then small sums
  k_gather<<<NGB, 256, 0, stream>>>(acc, user, pos, neg, uemb, iemb, ue, pe, ne, partR);
  k_small<<<1, 256, 0, stream>>>(beta_u, beta_i, partR, S);
  k_invperm<<<(BATCH + 255) / 256, 256, 0, stream>>>(perm, invp);
  // 6. mixes, scores, normalization (+ bf16 copies for MFMA)
  k_mixnorm<<<(BATCH * DIM) / 256, 256, 0, stream>>>(ue, pe, ne, beta_u, beta_i, perm,
                                                     An_u, Pn_u, An_p, Pn_p,
                                                     An_uh, Pn_uh, An_ph, Pn_ph,
                                                     pos_sc, neg_sc, nms);
  k_colpart<<<BATCH / 64, 256, 0, stream>>>(ue, pe, cu, cp, S);
  k_colnorm<<<1, 128, 0, stream>>>(S, c_u, c_p);
  k_sims<<<(BATCH * DIM) / 256, 256, 0, stream>>>(An_u, Pn_u, An_p, Pn_p, c_u, c_p,
                                                  perm, invp,
                                                  dis_u, col_u, posd_u, cross_u,
                                                  dis_p, col_p, posd_p, cross_p);
  // 7. MFMA matmul + fixed-shift sumexp (user side, pos side)
  k_lse_mfma<<<512, 256, 0, stream>>>(An_uh, Pn_uh, s_u);
  k_lse_mfma<<<512, 256, 0, stream>>>(An_ph, Pn_ph, s_p);
  // 8. final combine
  k_final<<<1, 256, 0, stream>>>(m_u, s_u, dis_u, col_u, posd_u, cross_u,
                                 m_p, s_p, dis_p, col_p, posd_p, cross_p,
                                 pos_sc, neg_sc, nms, invp, S,
                                 (float*)d_out);
}

// Round 7
// 452.995 us; speedup vs baseline: 3.5515x; 1.2864x over previous
//
#include <hip/hip_runtime.h>
#include <hip/hip_bf16.h>

#define NUSERS 100000
#define NITEMS 50000
#define NN     150001          // total nodes
#define NNZ    3200000         // 2 * NNZ_INTER
#define BATCH  4096
#define DIM    64
#define ND     (NN * DIM)
#define ALPHA  0.25f           // 1/(N_LAYERS+1)
#define INVT   5.0f            // 1/TEMP
#define LAMBDA 0.1f
#define REGC   1.0e-4f
#define BKSH   9               // 512 nodes per bucket
#define NB     293             // ceil(150001/512)
#define ACHUNK 4096            // edges per bucketA block
#define M0     5.0f            // fixed LSE shift: logits = sim/T ∈ [-5,5]
#define NGB    1024            // k_gather blocks
#define BHB    256             // k_bhist blocks

typedef __attribute__((ext_vector_type(8))) short v8s;    // 8 bf16 (4 VGPRs)
typedef __attribute__((ext_vector_type(4))) float f32x4;  // MFMA acc

__device__ __forceinline__ float wred64(float v) {
  for (int o = 32; o > 0; o >>= 1) v += __shfl_xor(v, o);
  return v;
}

__device__ __forceinline__ float softplusf(float x) {
  return (x > 20.f) ? x : log1pf(__expf(x));
}

__device__ __forceinline__ unsigned short bf16r(float v) {
  unsigned x = __float_as_uint(v);
  return (unsigned short)((x + 0x7fff + ((x >> 16) & 1)) >> 16);   // RNE
}

__device__ __forceinline__ float bf2f(unsigned short h) {
  return __uint_as_float((unsigned)h << 16);
}

// ---------------- zero scratch + preset LSE state ----------------
__global__ void k_zero(int* __restrict__ bhist, float* __restrict__ S,
                       float* __restrict__ m_u, float* __restrict__ s_u,
                       float* __restrict__ m_p, float* __restrict__ s_p) {
  int i = blockIdx.x * blockDim.x + threadIdx.x;
  if (i < NB) bhist[i] = 0;
  if (i < 256) S[i] = 0.f;
  if (i < BATCH) { s_u[i] = 0.f; s_p[i] = 0.f; m_u[i] = M0; m_p[i] = M0; }
}

// ---------------- x = concat(user_emb, item_emb); cur_h = bf16(x); acc = x ----------------
__global__ void k_inith(const float4* __restrict__ uemb, const float4* __restrict__ iemb,
                        ushort4* __restrict__ cur_h, float4* __restrict__ acc) {
  int q = blockIdx.x * blockDim.x + threadIdx.x;   // quads: ND/4
  if (q >= ND / 4) return;
  int n = q >> 4;                                   // 16 quads per node
  float4 v = (n < NUSERS) ? uemb[q] : iemb[q - NUSERS * 16];
  acc[q] = v;
  ushort4 h;
  h.x = bf16r(v.x); h.y = bf16r(v.y); h.z = bf16r(v.z); h.w = bf16r(v.w);
  cur_h[q] = h;
}

// ---------------- bucket histogram: LDS-private, 293 global atomics per block -----------
__global__ __launch_bounds__(256) void k_bhist(const int* __restrict__ rows,
                                               int* __restrict__ bhist) {
  __shared__ int lh[NB];
  int t = threadIdx.x;
  for (int i = t; i < NB; i += 256) lh[i] = 0;
  __syncthreads();
  const int per = (NNZ + BHB - 1) / BHB;
  int base = blockIdx.x * per;
  int end = min(base + per, NNZ);
  for (int e = base + t; e < end; e += 256)
    atomicAdd(&lh[rows[e] >> BKSH], 1);
  __syncthreads();
  for (int i = t; i < NB; i += 256) {
    int c = lh[i];
    if (c) atomicAdd(&bhist[i], c);
  }
}

// ---------------- bucket scan (one block, 512 threads) ----------------
__global__ __launch_bounds__(512) void k_bscan(const int* __restrict__ bhist,
                                               int* __restrict__ bbase, int* __restrict__ bcur,
                                               int* __restrict__ row_ptr) {
  __shared__ int sc[512];
  int t = threadIdx.x;
  int v = (t < NB) ? bhist[t] : 0;
  sc[t] = v;
  __syncthreads();
  for (int off = 1; off < 512; off <<= 1) {
    int u = (t >= off) ? sc[t - off] : 0;
    __syncthreads();
    sc[t] += u;
    __syncthreads();
  }
  int ex = sc[t] - v;                  // exclusive prefix
  if (t < NB) { bbase[t] = ex; bcur[t] = ex; }
  if (t == NB - 1) { bbase[NB] = ex + v; row_ptr[NN] = ex + v; }  // == NNZ
}

// ---------------- bucket pass A: LDS counting-sort into 512-node buckets, coalesced flush ----
__global__ __launch_bounds__(256) void k_bucketA(const int* __restrict__ rows,
                                                 const int* __restrict__ cols,
                                                 const float* __restrict__ vals,
                                                 int* __restrict__ bcur,
                                                 int4* __restrict__ tmp) {
  __shared__ int lhist[NB];
  __shared__ int lscan[NB];
  __shared__ int ldelta[NB];
  __shared__ int lcnt[NB];
  __shared__ int4 ent[ACHUNK];
  int t = threadIdx.x;
  int base = blockIdx.x * ACHUNK;
  for (int b = t; b < NB; b += 256) { lhist[b] = 0; lcnt[b] = 0; }
  __syncthreads();
  int rowv[16], colv[16], valv[16], bkt[16];
  int nval = 0;
#pragma unroll
  for (int k = 0; k < 16; k++) {
    int e = base + t + k * 256;                 // coalesced
    if (e < NNZ) {
      rowv[k] = rows[e]; colv[k] = cols[e]; valv[k] = __float_as_int(vals[e]);
      bkt[k] = rowv[k] >> BKSH;
      atomicAdd(&lhist[bkt[k]], 1);
      nval = k + 1;
    }
  }
  __syncthreads();
  if (t == 0) {
    int run = 0;
    for (int b = 0; b < NB; b++) { lscan[b] = run; run += lhist[b]; }
  }
  __syncthreads();
  for (int b = t; b < NB; b += 256) {
    int c = lhist[b];
    int g = (c > 0) ? atomicAdd(&bcur[b], c) : 0;
    ldelta[b] = g - lscan[b];
  }
  __syncthreads();
#pragma unroll
  for (int k = 0; k < 16; k++) {
    if (k < nval) {
      int b = bkt[k];
      int lp = atomicAdd(&lcnt[b], 1);
      ent[lscan[b] + lp] = make_int4(colv[k], valv[k], rowv[k], ldelta[b]);
    }
  }
  __syncthreads();
  int tot = min(ACHUNK, NNZ - base);
  for (int j = t; j < tot; j += 256) {
    int4 E = ent[j];
    tmp[E.w + j] = E;                           // contiguous run per bucket -> full lines
  }
}

// ---------------- bucket pass B: per-bucket row_ptr build + final scatter ----------------
// 512 threads = 1 thread per node slot; LDS hist + scan replaces the global histogram.
__global__ __launch_bounds__(512) void k_bucketB(const int* __restrict__ bbase,
                                                 const int4* __restrict__ tmp,
                                                 int2* __restrict__ ev,
                                                 int* __restrict__ row_ptr) {
  __shared__ int h[512], sc[512], c2[512], rstart[512];
  int b = blockIdx.x, t = threadIdx.x;
  int nbase = b << BKSH;
  h[t] = 0; c2[t] = 0;
  __syncthreads();
  int beg = bbase[b], end = bbase[b + 1];
  for (int j = beg + t; j < end; j += 512)
    atomicAdd(&h[tmp[j].z - nbase], 1);
  __syncthreads();
  int v = h[t];
  sc[t] = v;
  __syncthreads();
  for (int off = 1; off < 512; off <<= 1) {
    int u = (t >= off) ? sc[t - off] : 0;
    __syncthreads();
    sc[t] += u;
    __syncthreads();
  }
  int rp = beg + sc[t] - v;            // exclusive scan -> row start
  rstart[t] = rp;
  int node = nbase + t;
  if (node < NN) row_ptr[node] = rp;
  __syncthreads();
  for (int j = beg + t; j < end; j += 512) {
    int4 E = tmp[j];
    int ln = E.z - nbase;
    int lp = atomicAdd(&c2[ln], 1);
    ev[rstart[ln] + lp] = make_int2(E.x, E.y);
  }
}

// ---------------- gather SpMV (bf16 in, bf16+fp32 out): wave/node, 4 grp x 16 lanes x 4 dims
__global__ __launch_bounds__(256) void k_spmv_h(const int* __restrict__ row_ptr,
                                                const int2* __restrict__ ev,
                                                const unsigned short* __restrict__ cur_h,
                                                unsigned short* __restrict__ nxt_h,
                                                float* __restrict__ acc) {
  int node = blockIdx.x * 4 + (threadIdx.x >> 6);
  if (node >= NN) return;
  node = __builtin_amdgcn_readfirstlane(node);
  int lane = threadIdx.x & 63;
  int g = lane >> 4;                 // edge group 0..3 (edges ≡ g mod 4)
  int d4 = (lane & 15) << 2;         // 4 dims per lane
  int beg = row_ptr[node], end = row_ptr[node + 1];
  float4 s = make_float4(0.f, 0.f, 0.f, 0.f);
  int e = beg + g;
  for (; e + 12 < end; e += 16) {    // 4 edges in flight per lane
    int2 E0 = ev[e], E1 = ev[e + 4], E2 = ev[e + 8], E3 = ev[e + 12];
    ushort4 h0 = *(const ushort4*)&cur_h[E0.x * DIM + d4];
    ushort4 h1 = *(const ushort4*)&cur_h[E1.x * DIM + d4];
    ushort4 h2 = *(const ushort4*)&cur_h[E2.x * DIM + d4];
    ushort4 h3 = *(const ushort4*)&cur_h[E3.x * DIM + d4];
    float v0 = __int_as_float(E0.y), v1 = __int_as_float(E1.y);
    float v2 = __int_as_float(E2.y), v3 = __int_as_float(E3.y);
    s.x = fmaf(v0, bf2f(h0.x), s.x); s.y = fmaf(v0, bf2f(h0.y), s.y);
    s.z = fmaf(v0, bf2f(h0.z), s.z); s.w = fmaf(v0, bf2f(h0.w), s.w);
    s.x = fmaf(v1, bf2f(h1.x), s.x); s.y = fmaf(v1, bf2f(h1.y), s.y);
    s.z = fmaf(v1, bf2f(h1.z), s.z); s.w = fmaf(v1, bf2f(h1.w), s.w);
    s.x = fmaf(v2, bf2f(h2.x), s.x); s.y = fmaf(v2, bf2f(h2.y), s.y);
    s.z = fmaf(v2, bf2f(h2.z), s.z); s.w = fmaf(v2, bf2f(h2.w), s.w);
    s.x = fmaf(v3, bf2f(h3.x), s.x); s.y = fmaf(v3, bf2f(h3.y), s.y);
    s.z = fmaf(v3, bf2f(h3.z), s.z); s.w = fmaf(v3, bf2f(h3.w), s.w);
  }
  for (; e < end; e += 4) {
    int2 E0 = ev[e];
    float v0 = __int_as_float(E0.y);
    ushort4 h0 = *(const ushort4*)&cur_h[E0.x * DIM + d4];
    s.x = fmaf(v0, bf2f(h0.x), s.x); s.y = fmaf(v0, bf2f(h0.y), s.y);
    s.z = fmaf(v0, bf2f(h0.z), s.z); s.w = fmaf(v0, bf2f(h0.w), s.w);
  }
  // reduce across the 4 edge groups
  s.x += __shfl_xor(s.x, 16); s.y += __shfl_xor(s.y, 16);
  s.z += __shfl_xor(s.z, 16); s.w += __shfl_xor(s.w, 16);
  s.x += __shfl_xor(s.x, 32); s.y += __shfl_xor(s.y, 32);
  s.z += __shfl_xor(s.z, 32); s.w += __shfl_xor(s.w, 32);
  if (g == 0) {
    int o = node * DIM + d4;
    ushort4 hn;
    hn.x = bf16r(s.x); hn.y = bf16r(s.y); hn.z = bf16r(s.z); hn.w = bf16r(s.w);
    *(ushort4*)&nxt_h[o] = hn;
    float4 a = *(const float4*)&acc[o];
    a.x += s.x; a.y += s.y; a.z += s.z; a.w += s.w;
    *(float4*)&acc[o] = a;
  }
}

// ---------------- batch gather + per-block reg partial (NO global atomics) ----------------
__global__ void k_gather(const float* __restrict__ acc, const int* __restrict__ user,
                         const int* __restrict__ pos, const int* __restrict__ neg,
                         const float* __restrict__ uemb, const float* __restrict__ iemb,
                         float* __restrict__ ue, float* __restrict__ pe, float* __restrict__ ne,
                         float* __restrict__ partR) {
  __shared__ float sred[256];
  int t = threadIdx.x;
  int gid = blockIdx.x * 256 + t;    // BATCH*64 exact
  int i = gid >> 6, d = gid & 63;
  int u = user[i], p = pos[i], n = neg[i];
  ue[gid] = ALPHA * acc[u * DIM + d];
  pe[gid] = ALPHA * acc[(NUSERS + p) * DIM + d];
  ne[gid] = ALPHA * acc[(NUSERS + n) * DIM + d];
  float ru = uemb[u * DIM + d], rp = iemb[p * DIM + d], rn = iemb[n * DIM + d];
  sred[t] = ru * ru + rp * rp + rn * rn;
  __syncthreads();
  for (int off = 128; off > 0; off >>= 1) {
    if (t < off) sred[t] += sred[t + off];
    __syncthreads();
  }
  if (t == 0) partR[blockIdx.x] = sred[0];
}

// ---------------- small sums: S[0]=reg partials, S[1]=sum(beta_u), S[2]=sum(beta_i) -------
__global__ void k_small(const float* __restrict__ beta_u, const float* __restrict__ beta_i,
                        const float* __restrict__ partR, float* __restrict__ S) {
  __shared__ float a[256], b[256], c[256];
  int t = threadIdx.x;
  float su = 0.f, si = 0.f, sr = 0.f;
  for (int j = t; j < BATCH; j += 256) { su += beta_u[j]; si += beta_i[j]; }
  for (int j = t; j < NGB; j += 256) sr += partR[j];
  a[t] = su; b[t] = si; c[t] = sr;
  __syncthreads();
  for (int off = 128; off > 0; off >>= 1) {
    if (t < off) { a[t] += a[t + off]; b[t] += b[t + off]; c[t] += c[t + off]; }
    __syncthreads();
  }
  if (t == 0) { S[0] = c[0]; S[1] = a[0]; S[2] = b[0]; }
}

__global__ void k_invperm(const int* __restrict__ perm, int* __restrict__ inv) {
  int i = blockIdx.x * blockDim.x + threadIdx.x;
  if (i < BATCH) inv[perm[i]] = i;
}

// ---------------- mixes, scores, row normalization (wave per row); also emit bf16 ----------
__global__ void k_mixnorm(const float* __restrict__ ue, const float* __restrict__ pe,
                          const float* __restrict__ ne, const float* __restrict__ beta_u,
                          const float* __restrict__ beta_i, const int* __restrict__ perm,
                          float* __restrict__ An_u, float* __restrict__ Pn_u,
                          float* __restrict__ An_p, float* __restrict__ Pn_p,
                          unsigned short* __restrict__ An_uh, unsigned short* __restrict__ Pn_uh,
                          unsigned short* __restrict__ An_ph, unsigned short* __restrict__ Pn_ph,
                          float* __restrict__ pos_sc, float* __restrict__ neg_sc,
                          float* __restrict__ nms) {
  int gid = blockIdx.x * blockDim.x + threadIdx.x;   // BATCH*64 exact
  int i = gid >> 6, d = gid & 63;
  int pi = perm[i];
  float uei = ue[i * DIM + d], pei = pe[i * DIM + d], nei = ne[i * DIM + d];
  float ud = ue[pi * DIM + d], pd = pe[pi * DIM + d], nd = ne[pi * DIM + d];
  float bu = beta_u[i], bi = beta_i[i];
  float um = bu * uei + (1.f - bu) * ud;
  float pm = bi * pei + (1.f - bi) * pd;
  float nm = bi * nei + (1.f - bi) * nd;
  float r0 = uei * pei, r1 = uei * nei, r2 = uei * nm;
  float r3 = uei * uei, r4 = um * um, r5 = pei * pei, r6 = pm * pm;
  for (int o = 32; o > 0; o >>= 1) {
    r0 += __shfl_xor(r0, o); r1 += __shfl_xor(r1, o); r2 += __shfl_xor(r2, o);
    r3 += __shfl_xor(r3, o); r4 += __shfl_xor(r4, o); r5 += __shfl_xor(r5, o);
    r6 += __shfl_xor(r6, o);
  }
  if (d == 0) { pos_sc[i] = r0; neg_sc[i] = r1; nms[i] = r2; }
  float inu  = 1.f / fmaxf(sqrtf(r3), 1e-12f);
  float inum = 1.f / fmaxf(sqrtf(r4), 1e-12f);
  float inp  = 1.f / fmaxf(sqrtf(r5), 1e-12f);
  float inpm = 1.f / fmaxf(sqrtf(r6), 1e-12f);
  float a0 = uei * inu, p0 = um * inum, a1 = pei * inp, p1 = pm * inpm;
  An_u[gid] = a0;  Pn_u[gid] = p0;  An_p[gid] = a1;  Pn_p[gid] = p1;
  An_uh[gid] = bf16r(a0); Pn_uh[gid] = bf16r(p0);
  An_ph[gid] = bf16r(a1); Pn_ph[gid] = bf16r(p1);
}

// ---------------- collective-mix: parallel partial sums (64 blocks) ----------------
__global__ void k_colpart(const float* __restrict__ ue, const float* __restrict__ pe,
                          const float* __restrict__ cu, const float* __restrict__ cp,
                          float* __restrict__ S) {
  __shared__ float smu[4][64], smp[4][64];
  int t = threadIdx.x, d = t & 63, q = t >> 6;
  int r0 = blockIdx.x * 64 + q * 16;
  float su = 0.f, sp = 0.f;
#pragma unroll 4
  for (int i = r0; i < r0 + 16; ++i) {
    su = fmaf(cu[i], ue[i * DIM + d], su);
    sp = fmaf(cp[i], pe[i * DIM + d], sp);
  }
  smu[q][d] = su; smp[q][d] = sp;
  __syncthreads();
  if (t < 64) {
    atomicAdd(&S[64 + d],  smu[0][d] + smu[1][d] + smu[2][d] + smu[3][d]);
    atomicAdd(&S[128 + d], smp[0][d] + smp[1][d] + smp[2][d] + smp[3][d]);
  }
}

__global__ void k_colnorm(const float* __restrict__ S,
                          float* __restrict__ c_u, float* __restrict__ c_p) {
  int t = threadIdx.x;            // 128 threads = 2 waves
  int d = t & 63;
  float v = (t < 64) ? S[64 + d] : S[128 + d];
  float n = wred64(v * v);        // wave-local: wave0=u side, wave1=p side
  float inv = 1.f / fmaxf(sqrtf(n), 1e-12f);
  if (t < 64) c_u[d] = v * inv;
  else        c_p[d] = v * inv;
}

// ---------------- per-row sims (wave per row) ----------------
__global__ void k_sims(const float* __restrict__ An_u, const float* __restrict__ Pn_u,
                       const float* __restrict__ An_p, const float* __restrict__ Pn_p,
                       const float* __restrict__ c_u, const float* __restrict__ c_p,
                       const int* __restrict__ perm, const int* __restrict__ inv,
                       float* __restrict__ dis_u, float* __restrict__ col_u,
                       float* __restrict__ posd_u, float* __restrict__ cross_u,
                       float* __restrict__ dis_p, float* __restrict__ col_p,
                       float* __restrict__ posd_p, float* __restrict__ cross_p) {
  int gid = blockIdx.x * blockDim.x + threadIdx.x;
  int r = gid >> 6, d = gid & 63;
  int pr = perm[r], ir = inv[r];
  float au = An_u[r * DIM + d], pu = Pn_u[r * DIM + d];
  float ap = An_p[r * DIM + d], pp = Pn_p[r * DIM + d];
  float r0 = au * An_u[pr * DIM + d];
  float r1 = au * c_u[d];
  float r2 = au * pu;
  float r3 = au * Pn_u[ir * DIM + d];
  float r4 = ap * An_p[pr * DIM + d];
  float r5 = ap * c_p[d];
  float r6 = ap * pp;
  float r7 = ap * Pn_p[ir * DIM + d];
  for (int o = 32; o > 0; o >>= 1) {
    r0 += __shfl_xor(r0, o); r1 += __shfl_xor(r1, o); r2 += __shfl_xor(r2, o);
    r3 += __shfl_xor(r3, o); r4 += __shfl_xor(r4, o); r5 += __shfl_xor(r5, o);
    r6 += __shfl_xor(r6, o); r7 += __shfl_xor(r7, o);
  }
  if (d == 0) {
    dis_u[r] = r0 * INVT; col_u[r] = r1 * INVT; posd_u[r] = r2 * INVT; cross_u[r] = r3 * INVT;
    dis_p[r] = r4 * INVT; col_p[r] = r5 * INVT; posd_p[r] = r6 * INVT; cross_p[r] = r7 * INVT;
  }
}

// ---------------- MFMA fused matmul + fixed-shift sumexp over G = An @ Pn^T / T ----------
__global__ __launch_bounds__(256) void k_lse_mfma(const unsigned short* __restrict__ Anh,
                                                  const unsigned short* __restrict__ Pnh,
                                                  float* __restrict__ s_row) {
  const float C1 = INVT * 1.4426950408889634f;   // INVT*log2(e)
  int rb = blockIdx.x >> 3, cb = blockIdx.x & 7;
  int w = threadIdx.x >> 6, lane = threadIdx.x & 63;
  int r0 = rb * 64 + w * 16;
  int arow = r0 + (lane & 15);
  int koff = (lane >> 4) * 8;
  v8s a_lo = *(const v8s*)&Anh[arow * DIM + koff];
  v8s a_hi = *(const v8s*)&Anh[arow * DIM + koff + 32];
  float s0 = 0.f, s1 = 0.f, s2 = 0.f, s3 = 0.f;
  int cbase = cb * 512;
#pragma unroll 2
  for (int c0 = cbase; c0 < cbase + 512; c0 += 16) {
    int brow = c0 + (lane & 15);
    v8s b_lo = *(const v8s*)&Pnh[brow * DIM + koff];
    v8s b_hi = *(const v8s*)&Pnh[brow * DIM + koff + 32];
    f32x4 acc = {0.f, 0.f, 0.f, 0.f};
    acc = __builtin_amdgcn_mfma_f32_16x16x32_bf16(a_lo, b_lo, acc, 0, 0, 0);
    acc = __builtin_amdgcn_mfma_f32_16x16x32_bf16(a_hi, b_hi, acc, 0, 0, 0);
    s0 += exp2f(fmaf(acc[0], C1, -C1));
    s1 += exp2f(fmaf(acc[1], C1, -C1));
    s2 += exp2f(fmaf(acc[2], C1, -C1));
    s3 += exp2f(fmaf(acc[3], C1, -C1));
  }
  // sum the 16 col-slots of each row (C/D: col=lane&15, row=(lane>>4)*4+reg)
  for (int o = 1; o <= 8; o <<= 1) {
    s0 += __shfl_xor(s0, o); s1 += __shfl_xor(s1, o);
    s2 += __shfl_xor(s2, o); s3 += __shfl_xor(s3, o);
  }
  if ((lane & 15) == 0) {
    int rq = r0 + (lane >> 4) * 4;
    atomicAdd(&s_row[rq + 0], s0);
    atomicAdd(&s_row[rq + 1], s1);
    atomicAdd(&s_row[rq + 2], s2);
    atomicAdd(&s_row[rq + 3], s3);
  }
}

// ---------------- final combine (single block) — OUTPUT IS FLOAT32 ----------------
__global__ void k_final(const float* __restrict__ m_u, const float* __restrict__ s_u,
                        const float* __restrict__ dis_u, const float* __restrict__ col_u,
                        const float* __restrict__ posd_u, const float* __restrict__ cross_u,
                        const float* __restrict__ m_p, const float* __restrict__ s_p,
                        const float* __restrict__ dis_p, const float* __restrict__ col_p,
                        const float* __restrict__ posd_p, const float* __restrict__ cross_p,
                        const float* __restrict__ pos_sc, const float* __restrict__ neg_sc,
                        const float* __restrict__ nms, const int* __restrict__ inv,
                        const float* __restrict__ S, float* __restrict__ out) {
  __shared__ float red[6][256];
  int t = threadIdx.x;
  float lpu = 0.f, lnu = 0.f, lpp = 0.f, lnp = 0.f, bp = 0.f, bn = 0.f;
  for (int r = t; r < BATCH; r += 256) {
    int ir = inv[r];
    {
      float M = m_u[r], Sv = s_u[r];
      float d2 = col_u[r];
      float d1 = dis_u[r];
      float nm2 = fmaxf(M, fmaxf(d1, d2));
      float ss = Sv * __expf(M - nm2) + __expf(d1 - nm2) + __expf(d2 - nm2);
      lpu += nm2 + logf(ss) - posd_u[r];
      float d1n = dis_u[ir];
      nm2 = fmaxf(M, fmaxf(d1n, d2));
      ss = Sv * __expf(M - nm2) + __expf(d1n - nm2) + __expf(d2 - nm2);
      lnu += nm2 + logf(ss) - cross_u[r];
    }
    {
      float M = m_p[r], Sv = s_p[r];
      float d2 = col_p[r];
      float d1 = dis_p[r];
      float nm2 = fmaxf(M, fmaxf(d1, d2));
      float ss = Sv * __expf(M - nm2) + __expf(d1 - nm2) + __expf(d2 - nm2);
      lpp += nm2 + logf(ss) - posd_p[r];
      float d1n = dis_p[ir];
      nm2 = fmaxf(M, fmaxf(d1n, d2));
      ss = Sv * __expf(M - nm2) + __expf(d1n - nm2) + __expf(d2 - nm2);
      lnp += nm2 + logf(ss) - cross_p[r];
    }
    float ps = pos_sc[r];
    bp += softplusf(neg_sc[r] - ps);
    bn += softplusf(nms[r] - ps);
  }
  red[0][t] = lpu; red[1][t] = lnu; red[2][t] = lpp;
  red[3][t] = lnp; red[4][t] = bp;  red[5][t] = bn;
  __syncthreads();
  for (int off = 128; off > 0; off >>= 1) {
    if (t < off)
      for (int c = 0; c < 6; c++) red[c][t] += red[c][t + off];
    __syncthreads();
  }
  if (t == 0) {
    const float inv_b = 1.f / (float)BATCH;
    float mbu = S[1] * inv_b;            // mean(beta_u)
    float b   = S[2] * inv_b;            // mean(beta_i)
    float cl_u = mbu * (red[0][0] * inv_b) + (1.f - mbu) * (red[1][0] * inv_b);
    float cl_p = b   * (red[2][0] * inv_b) + (1.f - b)   * (red[3][0] * inv_b);
    float main_m = b * (red[4][0] * inv_b) + (1.f - b) * (red[5][0] * inv_b);
    float reg = REGC * S[0] * inv_b;
    float loss = main_m + LAMBDA * (cl_u + cl_p) + reg;
    out[0] = loss;                       // float32
  }
}

extern "C" void kernel_launch(void* const* d_in, const int* in_sizes, int n_in,
                              void* d_out, int out_size, void* d_ws, size_t ws_size,
                              hipStream_t stream) {
  const float* uemb   = (const float*)d_in[0];
  const float* iemb   = (const float*)d_in[1];
  const int*   rows   = (const int*)d_in[2];
  const int*   cols   = (const int*)d_in[3];
  const float* vals   = (const float*)d_in[4];
  const int*   user   = (const int*)d_in[5];
  const int*   pos    = (const int*)d_in[6];
  const int*   neg    = (const int*)d_in[7];
  const float* beta_u = (const float*)d_in[8];
  const float* beta_i = (const float*)d_in[9];
  const int*   perm   = (const int*)d_in[10];
  const float* cu     = (const float*)d_in[11];
  const float* cp     = (const float*)d_in[12];

  char* w = (char*)d_ws;
  size_t off = 0;
  auto alloc = [&](size_t bytes) -> char* {
    char* p = w + off;
    off += (bytes + 255) & ~(size_t)255;
    return p;
  };
  unsigned short* cur_h = (unsigned short*)alloc((size_t)ND * 2);
  unsigned short* nxt_h = (unsigned short*)alloc((size_t)ND * 2);
  float* acc     = (float*)alloc((size_t)ND * 4);
  int2*  ev      = (int2*) alloc((size_t)NNZ * 8);
  int*   row_ptr = (int*)  alloc((size_t)(NN + 1) * 4);
  int*   bhist   = (int*)  alloc((size_t)NB * 4);
  int*   bbase   = (int*)  alloc((size_t)(NB + 1) * 4);
  int*   bcur    = (int*)  alloc((size_t)NB * 4);
  float* partR   = (float*)alloc((size_t)NGB * 4);
  float* ue      = (float*)alloc((size_t)BATCH * DIM * 4);
  float* pe      = (float*)alloc((size_t)BATCH * DIM * 4);
  float* ne      = (float*)alloc((size_t)BATCH * DIM * 4);
  float* An_u    = (float*)alloc((size_t)BATCH * DIM * 4);
  float* Pn_u    = (float*)alloc((size_t)BATCH * DIM * 4);
  float* An_p    = (float*)alloc((size_t)BATCH * DIM * 4);
  float* Pn_p    = (float*)alloc((size_t)BATCH * DIM * 4);
  unsigned short* An_uh = (unsigned short*)alloc((size_t)BATCH * DIM * 2);
  unsigned short* Pn_uh = (unsigned short*)alloc((size_t)BATCH * DIM * 2);
  unsigned short* An_ph = (unsigned short*)alloc((size_t)BATCH * DIM * 2);
  unsigned short* Pn_ph = (unsigned short*)alloc((size_t)BATCH * DIM * 2);
  float* pos_sc  = (float*)alloc((size_t)BATCH * 4);
  float* neg_sc  = (float*)alloc((size_t)BATCH * 4);
  float* nms     = (float*)alloc((size_t)BATCH * 4);
  float* dis_u   = (float*)alloc((size_t)BATCH * 4);
  float* col_u   = (float*)alloc((size_t)BATCH * 4);
  float* posd_u  = (float*)alloc((size_t)BATCH * 4);
  float* cross_u = (float*)alloc((size_t)BATCH * 4);
  float* m_u     = (float*)alloc((size_t)BATCH * 4);
  float* s_u     = (float*)alloc((size_t)BATCH * 4);
  float* dis_p   = (float*)alloc((size_t)BATCH * 4);
  float* col_p   = (float*)alloc((size_t)BATCH * 4);
  float* posd_p  = (float*)alloc((size_t)BATCH * 4);
  float* cross_p = (float*)alloc((size_t)BATCH * 4);
  float* m_p     = (float*)alloc((size_t)BATCH * 4);
  float* s_p     = (float*)alloc((size_t)BATCH * 4);
  int*   invp    = (int*)  alloc((size_t)BATCH * 4);
  float* c_u     = (float*)alloc(256);
  float* c_p     = (float*)alloc(256);
  float* S       = (float*)alloc(1024);

  // tmp (int4 per edge, 51.2MB) aliases cur_h+nxt_h+acc — dead until k_inith,
  // which runs AFTER the CSR build.
  int4* tmp = (int4*)cur_h;

  // 1. zero bucket hist + preset LSE state (m=M0, s=0)
  k_zero<<<(NN + 255) / 256, 256, 0, stream>>>(bhist, S, m_u, s_u, m_p, s_p);
  // 2. CSR build: bucket hist -> scan -> 2-pass bucket sort (row_ptr built in pass B)
  k_bhist<<<BHB, 256, 0, stream>>>(rows, bhist);
  k_bscan<<<1, 512, 0, stream>>>(bhist, bbase, bcur, row_ptr);
  k_bucketA<<<(NNZ + ACHUNK - 1) / ACHUNK, 256, 0, stream>>>(rows, cols, vals, bcur, tmp);
  k_bucketB<<<NB, 512, 0, stream>>>(bbase, tmp, ev, row_ptr);
  // 3. init cur_h = bf16(x), acc = x
  k_inith<<<(ND / 4 + 255) / 256, 256, 0, stream>>>((const float4*)uemb, (const float4*)iemb,
                                                    (ushort4*)cur_h, (float4*)acc);
  // 4. three GCN layers (bf16 propagation, fp32 accumulation)
  {
    unsigned short* a = cur_h;
    unsigned short* b2 = nxt_h;
    for (int l = 0; l < 3; l++) {
      k_spmv_h<<<(NN + 3) / 4, 256, 0, stream>>>(row_ptr, ev, a, b2, acc);
      unsigned short* t2 = a; a = b2; b2 = t2;
    }
  }
  // 5. batch gather (+ per-block reg partials) then small sums
  k_gather<<<NGB, 256, 0, stream>>>(acc, user, pos, neg, uemb, iemb, ue, pe, ne, partR);
  k_small<<<1, 256, 0, stream>>>(beta_u, beta_i, partR, S);
  k_invperm<<<(BATCH + 255) / 256, 256, 0, stream>>>(perm, invp);
  // 6. mixes, scores, normalization (+ bf16 copies for MFMA)
  k_mixnorm<<<(BATCH * DIM) / 256, 256, 0, stream>>>(ue, pe, ne, beta_u, beta_i, perm,
                                                     An_u, Pn_u, An_p, Pn_p,
                                                     An_uh, Pn_uh, An_ph, Pn_ph,
                                                     pos_sc, neg_sc, nms);
  k_colpart<<<BATCH / 64, 256, 0, stream>>>(ue, pe, cu, cp, S);
  k_colnorm<<<1, 128, 0, stream>>>(S, c_u, c_p);
  k_sims<<<(BATCH * DIM) / 256, 256, 0, stream>>>(An_u, Pn_u, An_p, Pn_p, c_u, c_p,
                                                  perm, invp,
                                                  dis_u, col_u, posd_u, cross_u,
                                                  dis_p, col_p, posd_p, cross_p);
  // 7. MFMA matmul + fixed-shift sumexp (user side, pos side)
  k_lse_mfma<<<512, 256, 0, stream>>>(An_uh, Pn_uh, s_u);
  k_lse_mfma<<<512, 256, 0, stream>>>(An_ph, Pn_ph, s_p);
  // 8. final combine
  k_final<<<1, 256, 0, stream>>>(m_u, s_u, dis_u, col_u, posd_u, cross_u,
                                 m_p, s_p, dis_p, col_p, posd_p, cross_p,
                                 pos_sc, neg_sc, nms, invp, S,
                                 (float*)d_out);
}

// Round 8
// 413.756 us; speedup vs baseline: 3.8883x; 1.0948x over previous
//
#include <hip/hip_runtime.h>
#include <hip/hip_bf16.h>

#define NUSERS 100000
#define NITEMS 50000
#define NN     150001          // total nodes
#define NNZ    3200000         // 2 * NNZ_INTER
#define BATCH  4096
#define DIM    64
#define ND     (NN * DIM)
#define ALPHA  0.25f           // 1/(N_LAYERS+1)
#define INVT   5.0f            // 1/TEMP
#define LAMBDA 0.1f
#define REGC   1.0e-4f
#define BKSH   9               // 512 nodes per bucket
#define NB     293             // ceil(150001/512)
#define ACHUNK 4096            // edges per bucketA block
#define M0     5.0f            // fixed LSE shift: logits = sim/T ∈ [-5,5]
#define NGB    256             // k_gather blocks (BATCH*16/256)
#define BHB    256             // k_bhist blocks
#define CMASK  0x3FFFF         // 18-bit col mask

typedef __attribute__((ext_vector_type(8))) short v8s;    // 8 bf16 (4 VGPRs)
typedef __attribute__((ext_vector_type(4))) float f32x4;  // MFMA acc

__device__ __forceinline__ float wred64(float v) {
  for (int o = 32; o > 0; o >>= 1) v += __shfl_xor(v, o);
  return v;
}

__device__ __forceinline__ float softplusf(float x) {
  return (x > 20.f) ? x : log1pf(__expf(x));
}

__device__ __forceinline__ unsigned short bf16r(float v) {
  unsigned x = __float_as_uint(v);
  return (unsigned short)((x + 0x7fff + ((x >> 16) & 1)) >> 16);   // RNE
}

__device__ __forceinline__ float bf2f(unsigned short h) {
  return __uint_as_float((unsigned)h << 16);
}

__device__ __forceinline__ float4 us4f(ushort4 h) {
  return make_float4(bf2f(h.x), bf2f(h.y), bf2f(h.z), bf2f(h.w));
}

// ---------------- zero scratch + preset LSE state ----------------
__global__ void k_zero(int* __restrict__ bhist, float* __restrict__ S,
                       float* __restrict__ m_u, float* __restrict__ s_u,
                       float* __restrict__ m_p, float* __restrict__ s_p) {
  int i = blockIdx.x * blockDim.x + threadIdx.x;
  if (i < NB) bhist[i] = 0;
  if (i < 256) S[i] = 0.f;
  if (i < BATCH) { s_u[i] = 0.f; s_p[i] = 0.f; m_u[i] = M0; m_p[i] = M0; }
}

// ---------------- x0h = bf16(concat(user_emb, item_emb)) ----------------
__global__ void k_inith(const float4* __restrict__ uemb, const float4* __restrict__ iemb,
                        ushort4* __restrict__ x0h) {
  int q = blockIdx.x * blockDim.x + threadIdx.x;   // quads: ND/4
  if (q >= ND / 4) return;
  int n = q >> 4;                                   // 16 quads per node
  float4 v = (n < NUSERS) ? uemb[q] : iemb[q - NUSERS * 16];
  ushort4 h;
  h.x = bf16r(v.x); h.y = bf16r(v.y); h.z = bf16r(v.z); h.w = bf16r(v.w);
  x0h[q] = h;
}

// ---------------- bucket histogram: LDS-private, 293 global atomics per block -----------
__global__ __launch_bounds__(256) void k_bhist(const int* __restrict__ rows,
                                               int* __restrict__ bhist) {
  __shared__ int lh[NB];
  int t = threadIdx.x;
  for (int i = t; i < NB; i += 256) lh[i] = 0;
  __syncthreads();
  const int per = (NNZ + BHB - 1) / BHB;
  int base = blockIdx.x * per;
  int end = min(base + per, NNZ);
  for (int e = base + t; e < end; e += 256)
    atomicAdd(&lh[rows[e] >> BKSH], 1);
  __syncthreads();
  for (int i = t; i < NB; i += 256) {
    int c = lh[i];
    if (c) atomicAdd(&bhist[i], c);
  }
}

// ---------------- bucket scan (one block, 512 threads) ----------------
__global__ __launch_bounds__(512) void k_bscan(const int* __restrict__ bhist,
                                               int* __restrict__ bbase, int* __restrict__ bcur,
                                               int* __restrict__ row_ptr) {
  __shared__ int sc[512];
  int t = threadIdx.x;
  int v = (t < NB) ? bhist[t] : 0;
  sc[t] = v;
  __syncthreads();
  for (int off = 1; off < 512; off <<= 1) {
    int u = (t >= off) ? sc[t - off] : 0;
    __syncthreads();
    sc[t] += u;
    __syncthreads();
  }
  int ex = sc[t] - v;                  // exclusive prefix
  if (t < NB) { bbase[t] = ex; bcur[t] = ex; }
  if (t == NB - 1) { bbase[NB] = ex + v; row_ptr[NN] = ex + v; }  // == NNZ
}

// ---------------- bucket pass A: LDS counting-sort, packed int2 output ----------------
// packed word: col | (row&511)<<18   (col < 2^18, row-local < 2^9)
__global__ __launch_bounds__(256) void k_bucketA(const int* __restrict__ rows,
                                                 const int* __restrict__ cols,
                                                 const float* __restrict__ vals,
                                                 int* __restrict__ bcur,
                                                 int2* __restrict__ tmp) {
  __shared__ int lhist[NB];
  __shared__ int lscan[NB];
  __shared__ int ldelta[NB];
  __shared__ int lcnt[NB];
  __shared__ int4 ent[ACHUNK];        // x=packed col/rowlocal, y=val, z=ldelta
  int t = threadIdx.x;
  int base = blockIdx.x * ACHUNK;
  for (int b = t; b < NB; b += 256) { lhist[b] = 0; lcnt[b] = 0; }
  __syncthreads();
  int pkv[16], valv[16], bkt[16];
  int nval = 0;
#pragma unroll
  for (int k = 0; k < 16; k++) {
    int e = base + t + k * 256;                 // coalesced
    if (e < NNZ) {
      int r = rows[e];
      pkv[k] = cols[e] | ((r & 511) << 18);
      valv[k] = __float_as_int(vals[e]);
      bkt[k] = r >> BKSH;
      atomicAdd(&lhist[bkt[k]], 1);
      nval = k + 1;
    }
  }
  __syncthreads();
  if (t == 0) {
    int run = 0;
    for (int b = 0; b < NB; b++) { lscan[b] = run; run += lhist[b]; }
  }
  __syncthreads();
  for (int b = t; b < NB; b += 256) {
    int c = lhist[b];
    int g = (c > 0) ? atomicAdd(&bcur[b], c) : 0;
    ldelta[b] = g - lscan[b];
  }
  __syncthreads();
#pragma unroll
  for (int k = 0; k < 16; k++) {
    if (k < nval) {
      int b = bkt[k];
      int lp = atomicAdd(&lcnt[b], 1);
      ent[lscan[b] + lp] = make_int4(pkv[k], valv[k], ldelta[b], 0);
    }
  }
  __syncthreads();
  int tot = min(ACHUNK, NNZ - base);
  for (int j = t; j < tot; j += 256) {
    int4 E = ent[j];
    tmp[E.z + j] = make_int2(E.x, E.y);        // contiguous run per bucket -> full lines
  }
}

// ---------------- bucket pass B: per-bucket row_ptr build + final scatter ----------------
__global__ __launch_bounds__(512) void k_bucketB(const int* __restrict__ bbase,
                                                 const int2* __restrict__ tmp,
                                                 int2* __restrict__ ev,
                                                 int* __restrict__ row_ptr) {
  __shared__ int h[512], sc[512], c2[512], rstart[512];
  int b = blockIdx.x, t = threadIdx.x;
  int nbase = b << BKSH;
  h[t] = 0; c2[t] = 0;
  __syncthreads();
  int beg = bbase[b], end = bbase[b + 1];
  for (int j = beg + t; j < end; j += 512)
    atomicAdd(&h[tmp[j].x >> 18], 1);
  __syncthreads();
  int v = h[t];
  sc[t] = v;
  __syncthreads();
  for (int off = 1; off < 512; off <<= 1) {
    int u = (t >= off) ? sc[t - off] : 0;
    __syncthreads();
    sc[t] += u;
    __syncthreads();
  }
  int rp = beg + sc[t] - v;            // exclusive scan -> row start
  rstart[t] = rp;
  int node = nbase + t;
  if (node < NN) row_ptr[node] = rp;
  __syncthreads();
  for (int j = beg + t; j < end; j += 512) {
    int2 E = tmp[j];
    int ln = E.x >> 18;
    int lp = atomicAdd(&c2[ln], 1);
    ev[rstart[ln] + lp] = make_int2(E.x & CMASK, E.y);
  }
}

// ---------------- gather SpMV (bf16 in/out, NO acc): wave/node, 4 grp x 16 lanes x 4 dims
__global__ __launch_bounds__(256) void k_spmv_h(const int* __restrict__ row_ptr,
                                                const int2* __restrict__ ev,
                                                const unsigned short* __restrict__ cur_h,
                                                unsigned short* __restrict__ nxt_h) {
  int node = blockIdx.x * 4 + (threadIdx.x >> 6);
  if (node >= NN) return;
  node = __builtin_amdgcn_readfirstlane(node);
  int lane = threadIdx.x & 63;
  int g = lane >> 4;                 // edge group 0..3 (edges ≡ g mod 4)
  int d4 = (lane & 15) << 2;         // 4 dims per lane
  int beg = row_ptr[node], end = row_ptr[node + 1];
  float4 s = make_float4(0.f, 0.f, 0.f, 0.f);
  int e = beg + g;
  for (; e + 12 < end; e += 16) {    // 4 edges in flight per lane
    int2 E0 = ev[e], E1 = ev[e + 4], E2 = ev[e + 8], E3 = ev[e + 12];
    ushort4 h0 = *(const ushort4*)&cur_h[E0.x * DIM + d4];
    ushort4 h1 = *(const ushort4*)&cur_h[E1.x * DIM + d4];
    ushort4 h2 = *(const ushort4*)&cur_h[E2.x * DIM + d4];
    ushort4 h3 = *(const ushort4*)&cur_h[E3.x * DIM + d4];
    float v0 = __int_as_float(E0.y), v1 = __int_as_float(E1.y);
    float v2 = __int_as_float(E2.y), v3 = __int_as_float(E3.y);
    s.x = fmaf(v0, bf2f(h0.x), s.x); s.y = fmaf(v0, bf2f(h0.y), s.y);
    s.z = fmaf(v0, bf2f(h0.z), s.z); s.w = fmaf(v0, bf2f(h0.w), s.w);
    s.x = fmaf(v1, bf2f(h1.x), s.x); s.y = fmaf(v1, bf2f(h1.y), s.y);
    s.z = fmaf(v1, bf2f(h1.z), s.z); s.w = fmaf(v1, bf2f(h1.w), s.w);
    s.x = fmaf(v2, bf2f(h2.x), s.x); s.y = fmaf(v2, bf2f(h2.y), s.y);
    s.z = fmaf(v2, bf2f(h2.z), s.z); s.w = fmaf(v2, bf2f(h2.w), s.w);
    s.x = fmaf(v3, bf2f(h3.x), s.x); s.y = fmaf(v3, bf2f(h3.y), s.y);
    s.z = fmaf(v3, bf2f(h3.z), s.z); s.w = fmaf(v3, bf2f(h3.w), s.w);
  }
  for (; e < end; e += 4) {
    int2 E0 = ev[e];
    float v0 = __int_as_float(E0.y);
    ushort4 h0 = *(const ushort4*)&cur_h[E0.x * DIM + d4];
    s.x = fmaf(v0, bf2f(h0.x), s.x); s.y = fmaf(v0, bf2f(h0.y), s.y);
    s.z = fmaf(v0, bf2f(h0.z), s.z); s.w = fmaf(v0, bf2f(h0.w), s.w);
  }
  // reduce across the 4 edge groups
  s.x += __shfl_xor(s.x, 16); s.y += __shfl_xor(s.y, 16);
  s.z += __shfl_xor(s.z, 16); s.w += __shfl_xor(s.w, 16);
  s.x += __shfl_xor(s.x, 32); s.y += __shfl_xor(s.y, 32);
  s.z += __shfl_xor(s.z, 32); s.w += __shfl_xor(s.w, 32);
  if (g == 0) {
    ushort4 hn;
    hn.x = bf16r(s.x); hn.y = bf16r(s.y); hn.z = bf16r(s.z); hn.w = bf16r(s.w);
    *(ushort4*)&nxt_h[node * DIM + d4] = hn;
  }
}

// ---------------- batch gather: ue/pe/ne = ALPHA*(x0 + x1 + x2 + x3) + reg partials ------
__global__ __launch_bounds__(256) void k_gather(const float4* __restrict__ uemb4,
                                                const float4* __restrict__ iemb4,
                                                const ushort4* __restrict__ x1h,
                                                const ushort4* __restrict__ x2h,
                                                const ushort4* __restrict__ x3h,
                                                const int* __restrict__ user,
                                                const int* __restrict__ pos,
                                                const int* __restrict__ neg,
                                                float4* __restrict__ ue4,
                                                float4* __restrict__ pe4,
                                                float4* __restrict__ ne4,
                                                float* __restrict__ partR) {
  __shared__ float sred[256];
  int t = threadIdx.x;
  int gid = blockIdx.x * 256 + t;    // BATCH*16 exact
  int i = gid >> 4, q = gid & 15;
  int u = user[i], p = pos[i], n = neg[i];
  int qu = u * 16 + q;
  int qp = (NUSERS + p) * 16 + q;
  int qn = (NUSERS + n) * 16 + q;
  float4 eu = uemb4[qu];                       // x0 user (also reg term)
  float4 ep = iemb4[p * 16 + q];               // x0 pos  (also reg term)
  float4 en = iemb4[n * 16 + q];               // x0 neg  (also reg term)
  float4 a1 = us4f(x1h[qu]), a2 = us4f(x2h[qu]), a3 = us4f(x3h[qu]);
  float4 b1 = us4f(x1h[qp]), b2 = us4f(x2h[qp]), b3 = us4f(x3h[qp]);
  float4 c1 = us4f(x1h[qn]), c2 = us4f(x2h[qn]), c3 = us4f(x3h[qn]);
  float4 su = make_float4(ALPHA * (eu.x + a1.x + a2.x + a3.x),
                          ALPHA * (eu.y + a1.y + a2.y + a3.y),
                          ALPHA * (eu.z + a1.z + a2.z + a3.z),
                          ALPHA * (eu.w + a1.w + a2.w + a3.w));
  float4 sp = make_float4(ALPHA * (ep.x + b1.x + b2.x + b3.x),
                          ALPHA * (ep.y + b1.y + b2.y + b3.y),
                          ALPHA * (ep.z + b1.z + b2.z + b3.z),
                          ALPHA * (ep.w + b1.w + b2.w + b3.w));
  float4 sn = make_float4(ALPHA * (en.x + c1.x + c2.x + c3.x),
                          ALPHA * (en.y + c1.y + c2.y + c3.y),
                          ALPHA * (en.z + c1.z + c2.z + c3.z),
                          ALPHA * (en.w + c1.w + c2.w + c3.w));
  ue4[gid] = su;  pe4[gid] = sp;  ne4[gid] = sn;
  sred[t] = eu.x * eu.x + eu.y * eu.y + eu.z * eu.z + eu.w * eu.w
          + ep.x * ep.x + ep.y * ep.y + ep.z * ep.z + ep.w * ep.w
          + en.x * en.x + en.y * en.y + en.z * en.z + en.w * en.w;
  __syncthreads();
  for (int off = 128; off > 0; off >>= 1) {
    if (t < off) sred[t] += sred[t + off];
    __syncthreads();
  }
  if (t == 0) partR[blockIdx.x] = sred[0];
}

// ---------------- small sums: S[0]=reg partials, S[1]=sum(beta_u), S[2]=sum(beta_i) -------
__global__ void k_small(const float* __restrict__ beta_u, const float* __restrict__ beta_i,
                        const float* __restrict__ partR, float* __restrict__ S) {
  __shared__ float a[256], b[256], c[256];
  int t = threadIdx.x;
  float su = 0.f, si = 0.f, sr = 0.f;
  for (int j = t; j < BATCH; j += 256) { su += beta_u[j]; si += beta_i[j]; }
  for (int j = t; j < NGB; j += 256) sr += partR[j];
  a[t] = su; b[t] = si; c[t] = sr;
  __syncthreads();
  for (int off = 128; off > 0; off >>= 1) {
    if (t < off) { a[t] += a[t + off]; b[t] += b[t + off]; c[t] += c[t + off]; }
    __syncthreads();
  }
  if (t == 0) { S[0] = c[0]; S[1] = a[0]; S[2] = b[0]; }
}

__global__ void k_invperm(const int* __restrict__ perm, int* __restrict__ inv) {
  int i = blockIdx.x * blockDim.x + threadIdx.x;
  if (i < BATCH) inv[perm[i]] = i;
}

// ---------------- mixes, scores, row normalization (wave per row); also emit bf16 ----------
__global__ void k_mixnorm(const float* __restrict__ ue, const float* __restrict__ pe,
                          const float* __restrict__ ne, const float* __restrict__ beta_u,
                          const float* __restrict__ beta_i, const int* __restrict__ perm,
                          float* __restrict__ An_u, float* __restrict__ Pn_u,
                          float* __restrict__ An_p, float* __restrict__ Pn_p,
                          unsigned short* __restrict__ An_uh, unsigned short* __restrict__ Pn_uh,
                          unsigned short* __restrict__ An_ph, unsigned short* __restrict__ Pn_ph,
                          float* __restrict__ pos_sc, float* __restrict__ neg_sc,
                          float* __restrict__ nms) {
  int gid = blockIdx.x * blockDim.x + threadIdx.x;   // BATCH*64 exact
  int i = gid >> 6, d = gid & 63;
  int pi = perm[i];
  float uei = ue[i * DIM + d], pei = pe[i * DIM + d], nei = ne[i * DIM + d];
  float ud = ue[pi * DIM + d], pd = pe[pi * DIM + d], nd = ne[pi * DIM + d];
  float bu = beta_u[i], bi = beta_i[i];
  float um = bu * uei + (1.f - bu) * ud;
  float pm = bi * pei + (1.f - bi) * pd;
  float nm = bi * nei + (1.f - bi) * nd;
  float r0 = uei * pei, r1 = uei * nei, r2 = uei * nm;
  float r3 = uei * uei, r4 = um * um, r5 = pei * pei, r6 = pm * pm;
  for (int o = 32; o > 0; o >>= 1) {
    r0 += __shfl_xor(r0, o); r1 += __shfl_xor(r1, o); r2 += __shfl_xor(r2, o);
    r3 += __shfl_xor(r3, o); r4 += __shfl_xor(r4, o); r5 += __shfl_xor(r5, o);
    r6 += __shfl_xor(r6, o);
  }
  if (d == 0) { pos_sc[i] = r0; neg_sc[i] = r1; nms[i] = r2; }
  float inu  = 1.f / fmaxf(sqrtf(r3), 1e-12f);
  float inum = 1.f / fmaxf(sqrtf(r4), 1e-12f);
  float inp  = 1.f / fmaxf(sqrtf(r5), 1e-12f);
  float inpm = 1.f / fmaxf(sqrtf(r6), 1e-12f);
  float a0 = uei * inu, p0 = um * inum, a1 = pei * inp, p1 = pm * inpm;
  An_u[gid] = a0;  Pn_u[gid] = p0;  An_p[gid] = a1;  Pn_p[gid] = p1;
  An_uh[gid] = bf16r(a0); Pn_uh[gid] = bf16r(p0);
  An_ph[gid] = bf16r(a1); Pn_ph[gid] = bf16r(p1);
}

// ---------------- collective-mix: parallel partial sums (64 blocks) ----------------
__global__ void k_colpart(const float* __restrict__ ue, const float* __restrict__ pe,
                          const float* __restrict__ cu, const float* __restrict__ cp,
                          float* __restrict__ S) {
  __shared__ float smu[4][64], smp[4][64];
  int t = threadIdx.x, d = t & 63, q = t >> 6;
  int r0 = blockIdx.x * 64 + q * 16;
  float su = 0.f, sp = 0.f;
#pragma unroll 4
  for (int i = r0; i < r0 + 16; ++i) {
    su = fmaf(cu[i], ue[i * DIM + d], su);
    sp = fmaf(cp[i], pe[i * DIM + d], sp);
  }
  smu[q][d] = su; smp[q][d] = sp;
  __syncthreads();
  if (t < 64) {
    atomicAdd(&S[64 + d],  smu[0][d] + smu[1][d] + smu[2][d] + smu[3][d]);
    atomicAdd(&S[128 + d], smp[0][d] + smp[1][d] + smp[2][d] + smp[3][d]);
  }
}

__global__ void k_colnorm(const float* __restrict__ S,
                          float* __restrict__ c_u, float* __restrict__ c_p) {
  int t = threadIdx.x;            // 128 threads = 2 waves
  int d = t & 63;
  float v = (t < 64) ? S[64 + d] : S[128 + d];
  float n = wred64(v * v);        // wave-local: wave0=u side, wave1=p side
  float inv = 1.f / fmaxf(sqrtf(n), 1e-12f);
  if (t < 64) c_u[d] = v * inv;
  else        c_p[d] = v * inv;
}

// ---------------- per-row sims (wave per row) ----------------
__global__ void k_sims(const float* __restrict__ An_u, const float* __restrict__ Pn_u,
                       const float* __restrict__ An_p, const float* __restrict__ Pn_p,
                       const float* __restrict__ c_u, const float* __restrict__ c_p,
                       const int* __restrict__ perm, const int* __restrict__ inv,
                       float* __restrict__ dis_u, float* __restrict__ col_u,
                       float* __restrict__ posd_u, float* __restrict__ cross_u,
                       float* __restrict__ dis_p, float* __restrict__ col_p,
                       float* __restrict__ posd_p, float* __restrict__ cross_p) {
  int gid = blockIdx.x * blockDim.x + threadIdx.x;
  int r = gid >> 6, d = gid & 63;
  int pr = perm[r], ir = inv[r];
  float au = An_u[r * DIM + d], pu = Pn_u[r * DIM + d];
  float ap = An_p[r * DIM + d], pp = Pn_p[r * DIM + d];
  float r0 = au * An_u[pr * DIM + d];
  float r1 = au * c_u[d];
  float r2 = au * pu;
  float r3 = au * Pn_u[ir * DIM + d];
  float r4 = ap * An_p[pr * DIM + d];
  float r5 = ap * c_p[d];
  float r6 = ap * pp;
  float r7 = ap * Pn_p[ir * DIM + d];
  for (int o = 32; o > 0; o >>= 1) {
    r0 += __shfl_xor(r0, o); r1 += __shfl_xor(r1, o); r2 += __shfl_xor(r2, o);
    r3 += __shfl_xor(r3, o); r4 += __shfl_xor(r4, o); r5 += __shfl_xor(r5, o);
    r6 += __shfl_xor(r6, o); r7 += __shfl_xor(r7, o);
  }
  if (d == 0) {
    dis_u[r] = r0 * INVT; col_u[r] = r1 * INVT; posd_u[r] = r2 * INVT; cross_u[r] = r3 * INVT;
    dis_p[r] = r4 * INVT; col_p[r] = r5 * INVT; posd_p[r] = r6 * INVT; cross_p[r] = r7 * INVT;
  }
}

// ---------------- MFMA fused matmul + fixed-shift sumexp over G = An @ Pn^T / T ----------
__global__ __launch_bounds__(256) void k_lse_mfma(const unsigned short* __restrict__ Anh,
                                                  const unsigned short* __restrict__ Pnh,
                                                  float* __restrict__ s_row) {
  const float C1 = INVT * 1.4426950408889634f;   // INVT*log2(e)
  int rb = blockIdx.x >> 3, cb = blockIdx.x & 7;
  int w = threadIdx.x >> 6, lane = threadIdx.x & 63;
  int r0 = rb * 64 + w * 16;
  int arow = r0 + (lane & 15);
  int koff = (lane >> 4) * 8;
  v8s a_lo = *(const v8s*)&Anh[arow * DIM + koff];
  v8s a_hi = *(const v8s*)&Anh[arow * DIM + koff + 32];
  float s0 = 0.f, s1 = 0.f, s2 = 0.f, s3 = 0.f;
  int cbase = cb * 512;
#pragma unroll 2
  for (int c0 = cbase; c0 < cbase + 512; c0 += 16) {
    int brow = c0 + (lane & 15);
    v8s b_lo = *(const v8s*)&Pnh[brow * DIM + koff];
    v8s b_hi = *(const v8s*)&Pnh[brow * DIM + koff + 32];
    f32x4 acc = {0.f, 0.f, 0.f, 0.f};
    acc = __builtin_amdgcn_mfma_f32_16x16x32_bf16(a_lo, b_lo, acc, 0, 0, 0);
    acc = __builtin_amdgcn_mfma_f32_16x16x32_bf16(a_hi, b_hi, acc, 0, 0, 0);
    s0 += exp2f(fmaf(acc[0], C1, -C1));
    s1 += exp2f(fmaf(acc[1], C1, -C1));
    s2 += exp2f(fmaf(acc[2], C1, -C1));
    s3 += exp2f(fmaf(acc[3], C1, -C1));
  }
  // sum the 16 col-slots of each row (C/D: col=lane&15, row=(lane>>4)*4+reg)
  for (int o = 1; o <= 8; o <<= 1) {
    s0 += __shfl_xor(s0, o); s1 += __shfl_xor(s1, o);
    s2 += __shfl_xor(s2, o); s3 += __shfl_xor(s3, o);
  }
  if ((lane & 15) == 0) {
    int rq = r0 + (lane >> 4) * 4;
    atomicAdd(&s_row[rq + 0], s0);
    atomicAdd(&s_row[rq + 1], s1);
    atomicAdd(&s_row[rq + 2], s2);
    atomicAdd(&s_row[rq + 3], s3);
  }
}

// ---------------- final combine (single block) — OUTPUT IS FLOAT32 ----------------
__global__ void k_final(const float* __restrict__ m_u, const float* __restrict__ s_u,
                        const float* __restrict__ dis_u, const float* __restrict__ col_u,
                        const float* __restrict__ posd_u, const float* __restrict__ cross_u,
                        const float* __restrict__ m_p, const float* __restrict__ s_p,
                        const float* __restrict__ dis_p, const float* __restrict__ col_p,
                        const float* __restrict__ posd_p, const float* __restrict__ cross_p,
                        const float* __restrict__ pos_sc, const float* __restrict__ neg_sc,
                        const float* __restrict__ nms, const int* __restrict__ inv,
                        const float* __restrict__ S, float* __restrict__ out) {
  __shared__ float red[6][256];
  int t = threadIdx.x;
  float lpu = 0.f, lnu = 0.f, lpp = 0.f, lnp = 0.f, bp = 0.f, bn = 0.f;
  for (int r = t; r < BATCH; r += 256) {
    int ir = inv[r];
    {
      float M = m_u[r], Sv = s_u[r];
      float d2 = col_u[r];
      float d1 = dis_u[r];
      float nm2 = fmaxf(M, fmaxf(d1, d2));
      float ss = Sv * __expf(M - nm2) + __expf(d1 - nm2) + __expf(d2 - nm2);
      lpu += nm2 + logf(ss) - posd_u[r];
      float d1n = dis_u[ir];
      nm2 = fmaxf(M, fmaxf(d1n, d2));
      ss = Sv * __expf(M - nm2) + __expf(d1n - nm2) + __expf(d2 - nm2);
      lnu += nm2 + logf(ss) - cross_u[r];
    }
    {
      float M = m_p[r], Sv = s_p[r];
      float d2 = col_p[r];
      float d1 = dis_p[r];
      float nm2 = fmaxf(M, fmaxf(d1, d2));
      float ss = Sv * __expf(M - nm2) + __expf(d1 - nm2) + __expf(d2 - nm2);
      lpp += nm2 + logf(ss) - posd_p[r];
      float d1n = dis_p[ir];
      nm2 = fmaxf(M, fmaxf(d1n, d2));
      ss = Sv * __expf(M - nm2) + __expf(d1n - nm2) + __expf(d2 - nm2);
      lnp += nm2 + logf(ss) - cross_p[r];
    }
    float ps = pos_sc[r];
    bp += softplusf(neg_sc[r] - ps);
    bn += softplusf(nms[r] - ps);
  }
  red[0][t] = lpu; red[1][t] = lnu; red[2][t] = lpp;
  red[3][t] = lnp; red[4][t] = bp;  red[5][t] = bn;
  __syncthreads();
  for (int off = 128; off > 0; off >>= 1) {
    if (t < off)
      for (int c = 0; c < 6; c++) red[c][t] += red[c][t + off];
    __syncthreads();
  }
  if (t == 0) {
    const float inv_b = 1.f / (float)BATCH;
    float mbu = S[1] * inv_b;            // mean(beta_u)
    float b   = S[2] * inv_b;            // mean(beta_i)
    float cl_u = mbu * (red[0][0] * inv_b) + (1.f - mbu) * (red[1][0] * inv_b);
    float cl_p = b   * (red[2][0] * inv_b) + (1.f - b)   * (red[3][0] * inv_b);
    float main_m = b * (red[4][0] * inv_b) + (1.f - b) * (red[5][0] * inv_b);
    float reg = REGC * S[0] * inv_b;
    float loss = main_m + LAMBDA * (cl_u + cl_p) + reg;
    out[0] = loss;                       // float32
  }
}

extern "C" void kernel_launch(void* const* d_in, const int* in_sizes, int n_in,
                              void* d_out, int out_size, void* d_ws, size_t ws_size,
                              hipStream_t stream) {
  const float* uemb   = (const float*)d_in[0];
  const float* iemb   = (const float*)d_in[1];
  const int*   rows   = (const int*)d_in[2];
  const int*   cols   = (const int*)d_in[3];
  const float* vals   = (const float*)d_in[4];
  const int*   user   = (const int*)d_in[5];
  const int*   pos    = (const int*)d_in[6];
  const int*   neg    = (const int*)d_in[7];
  const float* beta_u = (const float*)d_in[8];
  const float* beta_i = (const float*)d_in[9];
  const int*   perm   = (const int*)d_in[10];
  const float* cu     = (const float*)d_in[11];
  const float* cp     = (const float*)d_in[12];

  char* w = (char*)d_ws;
  size_t off = 0;
  auto alloc = [&](size_t bytes) -> char* {
    char* p = w + off;
    off += (bytes + 255) & ~(size_t)255;
    return p;
  };
  unsigned short* x0h = (unsigned short*)alloc((size_t)ND * 2);
  unsigned short* x1h = (unsigned short*)alloc((size_t)ND * 2);
  unsigned short* x2h = (unsigned short*)alloc((size_t)ND * 2);
  unsigned short* x3h = (unsigned short*)alloc((size_t)ND * 2);
  int2*  ev      = (int2*) alloc((size_t)NNZ * 8);
  int*   row_ptr = (int*)  alloc((size_t)(NN + 1) * 4);
  int*   bhist   = (int*)  alloc((size_t)NB * 4);
  int*   bbase   = (int*)  alloc((size_t)(NB + 1) * 4);
  int*   bcur    = (int*)  alloc((size_t)NB * 4);
  float* partR   = (float*)alloc((size_t)NGB * 4);
  float* ue      = (float*)alloc((size_t)BATCH * DIM * 4);
  float* pe      = (float*)alloc((size_t)BATCH * DIM * 4);
  float* ne      = (float*)alloc((size_t)BATCH * DIM * 4);
  float* An_u    = (float*)alloc((size_t)BATCH * DIM * 4);
  float* Pn_u    = (float*)alloc((size_t)BATCH * DIM * 4);
  float* An_p    = (float*)alloc((size_t)BATCH * DIM * 4);
  float* Pn_p    = (float*)alloc((size_t)BATCH * DIM * 4);
  unsigned short* An_uh = (unsigned short*)alloc((size_t)BATCH * DIM * 2);
  unsigned short* Pn_uh = (unsigned short*)alloc((size_t)BATCH * DIM * 2);
  unsigned short* An_ph = (unsigned short*)alloc((size_t)BATCH * DIM * 2);
  unsigned short* Pn_ph = (unsigned short*)alloc((size_t)BATCH * DIM * 2);
  float* pos_sc  = (float*)alloc((size_t)BATCH * 4);
  float* neg_sc  = (float*)alloc((size_t)BATCH * 4);
  float* nms     = (float*)alloc((size_t)BATCH * 4);
  float* dis_u   = (float*)alloc((size_t)BATCH * 4);
  float* col_u   = (float*)alloc((size_t)BATCH * 4);
  float* posd_u  = (float*)alloc((size_t)BATCH * 4);
  float* cross_u = (float*)alloc((size_t)BATCH * 4);
  float* m_u     = (float*)alloc((size_t)BATCH * 4);
  float* s_u     = (float*)alloc((size_t)BATCH * 4);
  float* dis_p   = (float*)alloc((size_t)BATCH * 4);
  float* col_p   = (float*)alloc((size_t)BATCH * 4);
  float* posd_p  = (float*)alloc((size_t)BATCH * 4);
  float* cross_p = (float*)alloc((size_t)BATCH * 4);
  float* m_p     = (float*)alloc((size_t)BATCH * 4);
  float* s_p     = (float*)alloc((size_t)BATCH * 4);
  int*   invp    = (int*)  alloc((size_t)BATCH * 4);
  float* c_u     = (float*)alloc(256);
  float* c_p     = (float*)alloc(256);
  float* S       = (float*)alloc(1024);

  // tmp (int2 per edge, 25.6MB) aliases x0h+x1h (38.4MB) — dead until k_inith/k_spmv_h,
  // which run AFTER the CSR build.
  int2* tmp = (int2*)x0h;

  // 1. zero bucket hist + preset LSE state (m=M0, s=0)
  k_zero<<<(NN + 255) / 256, 256, 0, stream>>>(bhist, S, m_u, s_u, m_p, s_p);
  // 2. CSR build: bucket hist -> scan -> 2-pass bucket sort (row_ptr built in pass B)
  k_bhist<<<BHB, 256, 0, stream>>>(rows, bhist);
  k_bscan<<<1, 512, 0, stream>>>(bhist, bbase, bcur, row_ptr);
  k_bucketA<<<(NNZ + ACHUNK - 1) / ACHUNK, 256, 0, stream>>>(rows, cols, vals, bcur, tmp);
  k_bucketB<<<NB, 512, 0, stream>>>(bbase, tmp, ev, row_ptr);
  // 3. init x0h = bf16(concat(user_emb, item_emb))
  k_inith<<<(ND / 4 + 255) / 256, 256, 0, stream>>>((const float4*)uemb, (const float4*)iemb,
                                                    (ushort4*)x0h);
  // 4. three GCN layers (bf16 propagation, separate layer outputs — no acc RMW)
  k_spmv_h<<<(NN + 3) / 4, 256, 0, stream>>>(row_ptr, ev, x0h, x1h);
  k_spmv_h<<<(NN + 3) / 4, 256, 0, stream>>>(row_ptr, ev, x1h, x2h);
  k_spmv_h<<<(NN + 3) / 4, 256, 0, stream>>>(row_ptr, ev, x2h, x3h);
  // 5. batch gather (sum of layer outputs for just the batch rows) + small sums
  k_gather<<<NGB, 256, 0, stream>>>((const float4*)uemb, (const float4*)iemb,
                                    (const ushort4*)x1h, (const ushort4*)x2h,
                                    (const ushort4*)x3h, user, pos, neg,
                                    (float4*)ue, (float4*)pe, (float4*)ne, partR);
  k_small<<<1, 256, 0, stream>>>(beta_u, beta_i, partR, S);
  k_invperm<<<(BATCH + 255) / 256, 256, 0, stream>>>(perm, invp);
  // 6. mixes, scores, normalization (+ bf16 copies for MFMA)
  k_mixnorm<<<(BATCH * DIM) / 256, 256, 0, stream>>>(ue, pe, ne, beta_u, beta_i, perm,
                                                     An_u, Pn_u, An_p, Pn_p,
                                                     An_uh, Pn_uh, An_ph, Pn_ph,
                                                     pos_sc, neg_sc, nms);
  k_colpart<<<BATCH / 64, 256, 0, stream>>>(ue, pe, cu, cp, S);
  k_colnorm<<<1, 128, 0, stream>>>(S, c_u, c_p);
  k_sims<<<(BATCH * DIM) / 256, 256, 0, stream>>>(An_u, Pn_u, An_p, Pn_p, c_u, c_p,
                                                  perm, invp,
                                                  dis_u, col_u, posd_u, cross_u,
                                                  dis_p, col_p, posd_p, cross_p);
  // 7. MFMA matmul + fixed-shift sumexp (user side, pos side)
  k_lse_mfma<<<512, 256, 0, stream>>>(An_uh, Pn_uh, s_u);
  k_lse_mfma<<<512, 256, 0, stream>>>(An_ph, Pn_ph, s_p);
  // 8. final combine
  k_final<<<1, 256, 0, stream>>>(m_u, s_u, dis_u, col_u, posd_u, cross_u,
                                 m_p, s_p, dis_p, col_p, posd_p, cross_p,
                                 pos_sc, neg_sc, nms, invp, S,
                                 (float*)d_out);
}

// Round 9
// 411.698 us; speedup vs baseline: 3.9077x; 1.0050x over previous
//
#include <hip/hip_runtime.h>
#include <hip/hip_bf16.h>
#include <hip/hip_fp16.h>

#define NUSERS 100000
#define NITEMS 50000
#define NN     150001          // total nodes
#define NNZ    3200000         // 2 * NNZ_INTER
#define BATCH  4096
#define DIM    64
#define ND     (NN * DIM)
#define ALPHA  0.25f           // 1/(N_LAYERS+1)
#define INVT   5.0f            // 1/TEMP
#define LAMBDA 0.1f
#define REGC   1.0e-4f
#define BKSH   9               // 512 nodes per bucket
#define NB     293             // ceil(150001/512)
#define ACHUNK 4096            // edges per bucketA block
#define M0     5.0f            // fixed LSE shift: logits = sim/T ∈ [-5,5]
#define NGB    256             // k_gather blocks (BATCH*16/256)
#define BHB    256             // k_bhist blocks
#define CMASK  0x3FFFF         // 18-bit col mask

typedef __attribute__((ext_vector_type(8))) short v8s;    // 8 bf16 (4 VGPRs)
typedef __attribute__((ext_vector_type(4))) float f32x4;  // MFMA acc

union H2U { unsigned u; __half2 h; };
__device__ __forceinline__ __half2 u2h(unsigned x) { H2U t; t.u = x; return t.h; }
__device__ __forceinline__ unsigned h2u(__half2 h) { H2U t; t.h = h; return t.u; }
__device__ __forceinline__ __half2 h2shfl(__half2 v, int m) {
  return u2h((unsigned)__shfl_xor((int)h2u(v), m));
}

__device__ __forceinline__ float wred64(float v) {
  for (int o = 32; o > 0; o >>= 1) v += __shfl_xor(v, o);
  return v;
}

__device__ __forceinline__ float softplusf(float x) {
  return (x > 20.f) ? x : log1pf(__expf(x));
}

__device__ __forceinline__ unsigned short bf16r(float v) {
  unsigned x = __float_as_uint(v);
  return (unsigned short)((x + 0x7fff + ((x >> 16) & 1)) >> 16);   // RNE
}

// fp16 quad (uint2 = 4 halves) -> float4
__device__ __forceinline__ float4 h4f(uint2 u) {
  float2 lo = __half22float2(u2h(u.x));
  float2 hi = __half22float2(u2h(u.y));
  return make_float4(lo.x, lo.y, hi.x, hi.y);
}

// ---------------- zero scratch + preset LSE state ----------------
__global__ void k_zero(int* __restrict__ bhist, float* __restrict__ S,
                       float* __restrict__ m_u, float* __restrict__ s_u,
                       float* __restrict__ m_p, float* __restrict__ s_p) {
  int i = blockIdx.x * blockDim.x + threadIdx.x;
  if (i < NB) bhist[i] = 0;
  if (i < 256) S[i] = 0.f;
  if (i < BATCH) { s_u[i] = 0.f; s_p[i] = 0.f; m_u[i] = M0; m_p[i] = M0; }
}

// ---------------- x0h = fp16(concat(user_emb, item_emb)) ----------------
__global__ void k_inith(const float4* __restrict__ uemb, const float4* __restrict__ iemb,
                        uint2* __restrict__ x0h) {
  int q = blockIdx.x * blockDim.x + threadIdx.x;   // quads: ND/4
  if (q >= ND / 4) return;
  int n = q >> 4;                                   // 16 quads per node
  float4 v = (n < NUSERS) ? uemb[q] : iemb[q - NUSERS * 16];
  x0h[q] = make_uint2(h2u(__floats2half2_rn(v.x, v.y)),
                      h2u(__floats2half2_rn(v.z, v.w)));
}

// ---------------- bucket histogram: LDS-private, 293 global atomics per block -----------
__global__ __launch_bounds__(256) void k_bhist(const int* __restrict__ rows,
                                               int* __restrict__ bhist) {
  __shared__ int lh[NB];
  int t = threadIdx.x;
  for (int i = t; i < NB; i += 256) lh[i] = 0;
  __syncthreads();
  const int per = (NNZ + BHB - 1) / BHB;
  int base = blockIdx.x * per;
  int end = min(base + per, NNZ);
  for (int e = base + t; e < end; e += 256)
    atomicAdd(&lh[rows[e] >> BKSH], 1);
  __syncthreads();
  for (int i = t; i < NB; i += 256) {
    int c = lh[i];
    if (c) atomicAdd(&bhist[i], c);
  }
}

// ---------------- bucket scan (one block, 512 threads) ----------------
__global__ __launch_bounds__(512) void k_bscan(const int* __restrict__ bhist,
                                               int* __restrict__ bbase, int* __restrict__ bcur,
                                               int* __restrict__ row_ptr) {
  __shared__ int sc[512];
  int t = threadIdx.x;
  int v = (t < NB) ? bhist[t] : 0;
  sc[t] = v;
  __syncthreads();
  for (int off = 1; off < 512; off <<= 1) {
    int u = (t >= off) ? sc[t - off] : 0;
    __syncthreads();
    sc[t] += u;
    __syncthreads();
  }
  int ex = sc[t] - v;                  // exclusive prefix
  if (t < NB) { bbase[t] = ex; bcur[t] = ex; }
  if (t == NB - 1) { bbase[NB] = ex + v; row_ptr[NN] = ex + v; }  // == NNZ
}

// ---------------- bucket pass A: LDS counting-sort, packed int2 output ----------------
// packed word: col | (row&511)<<18   (col < 2^18, row-local < 2^9)
__global__ __launch_bounds__(256) void k_bucketA(const int* __restrict__ rows,
                                                 const int* __restrict__ cols,
                                                 const float* __restrict__ vals,
                                                 int* __restrict__ bcur,
                                                 int2* __restrict__ tmp) {
  __shared__ int lhist[NB];
  __shared__ int lscan[NB];
  __shared__ int ldelta[NB];
  __shared__ int lcnt[NB];
  __shared__ int4 ent[ACHUNK];        // x=packed col/rowlocal, y=val, z=ldelta
  int t = threadIdx.x;
  int base = blockIdx.x * ACHUNK;
  for (int b = t; b < NB; b += 256) { lhist[b] = 0; lcnt[b] = 0; }
  __syncthreads();
  int pkv[16], valv[16], bkt[16];
  int nval = 0;
#pragma unroll
  for (int k = 0; k < 16; k++) {
    int e = base + t + k * 256;                 // coalesced
    if (e < NNZ) {
      int r = rows[e];
      pkv[k] = cols[e] | ((r & 511) << 18);
      valv[k] = __float_as_int(vals[e]);
      bkt[k] = r >> BKSH;
      atomicAdd(&lhist[bkt[k]], 1);
      nval = k + 1;
    }
  }
  __syncthreads();
  if (t == 0) {
    int run = 0;
    for (int b = 0; b < NB; b++) { lscan[b] = run; run += lhist[b]; }
  }
  __syncthreads();
  for (int b = t; b < NB; b += 256) {
    int c = lhist[b];
    int g = (c > 0) ? atomicAdd(&bcur[b], c) : 0;
    ldelta[b] = g - lscan[b];
  }
  __syncthreads();
#pragma unroll
  for (int k = 0; k < 16; k++) {
    if (k < nval) {
      int b = bkt[k];
      int lp = atomicAdd(&lcnt[b], 1);
      ent[lscan[b] + lp] = make_int4(pkv[k], valv[k], ldelta[b], 0);
    }
  }
  __syncthreads();
  int tot = min(ACHUNK, NNZ - base);
  for (int j = t; j < tot; j += 256) {
    int4 E = ent[j];
    tmp[E.z + j] = make_int2(E.x, E.y);        // contiguous run per bucket -> full lines
  }
}

// ---------------- bucket pass B: per-bucket row_ptr build + final scatter ----------------
__global__ __launch_bounds__(512) void k_bucketB(const int* __restrict__ bbase,
                                                 const int2* __restrict__ tmp,
                                                 int2* __restrict__ ev,
                                                 int* __restrict__ row_ptr) {
  __shared__ int h[512], sc[512], c2[512], rstart[512];
  int b = blockIdx.x, t = threadIdx.x;
  int nbase = b << BKSH;
  h[t] = 0; c2[t] = 0;
  __syncthreads();
  int beg = bbase[b], end = bbase[b + 1];
  for (int j = beg + t; j < end; j += 512)
    atomicAdd(&h[tmp[j].x >> 18], 1);
  __syncthreads();
  int v = h[t];
  sc[t] = v;
  __syncthreads();
  for (int off = 1; off < 512; off <<= 1) {
    int u = (t >= off) ? sc[t - off] : 0;
    __syncthreads();
    sc[t] += u;
    __syncthreads();
  }
  int rp = beg + sc[t] - v;            // exclusive scan -> row start
  rstart[t] = rp;
  int node = nbase + t;
  if (node < NN) row_ptr[node] = rp;
  __syncthreads();
  for (int j = beg + t; j < end; j += 512) {
    int2 E = tmp[j];
    int ln = E.x >> 18;
    int lp = atomicAdd(&c2[ln], 1);
    ev[rstart[ln] + lp] = make_int2(E.x & CMASK, E.y);
  }
}

// ---------------- gather SpMV (fp16, packed __hfma2): wave/node, 4 grp x 16 lanes x 4 dims
__global__ __launch_bounds__(256) void k_spmv_h(const int* __restrict__ row_ptr,
                                                const int2* __restrict__ ev,
                                                const unsigned short* __restrict__ cur_h,
                                                unsigned short* __restrict__ nxt_h) {
  int node = blockIdx.x * 4 + (threadIdx.x >> 6);
  if (node >= NN) return;
  node = __builtin_amdgcn_readfirstlane(node);
  int lane = threadIdx.x & 63;
  int g = lane >> 4;                 // edge group 0..3 (edges ≡ g mod 4)
  int d4 = (lane & 15) << 2;         // 4 dims per lane
  int beg = row_ptr[node], end = row_ptr[node + 1];
  __half2 a0 = __float2half2_rn(0.f);
  __half2 a1 = a0;
  int e = beg + g;
  for (; e + 12 < end; e += 16) {    // 4 edges in flight per lane
    int2 E0 = ev[e], E1 = ev[e + 4], E2 = ev[e + 8], E3 = ev[e + 12];
    uint2 H0 = *(const uint2*)&cur_h[E0.x * DIM + d4];
    uint2 H1 = *(const uint2*)&cur_h[E1.x * DIM + d4];
    uint2 H2 = *(const uint2*)&cur_h[E2.x * DIM + d4];
    uint2 H3 = *(const uint2*)&cur_h[E3.x * DIM + d4];
    __half2 v0 = __float2half2_rn(__int_as_float(E0.y));
    __half2 v1 = __float2half2_rn(__int_as_float(E1.y));
    __half2 v2 = __float2half2_rn(__int_as_float(E2.y));
    __half2 v3 = __float2half2_rn(__int_as_float(E3.y));
    a0 = __hfma2(v0, u2h(H0.x), a0); a1 = __hfma2(v0, u2h(H0.y), a1);
    a0 = __hfma2(v1, u2h(H1.x), a0); a1 = __hfma2(v1, u2h(H1.y), a1);
    a0 = __hfma2(v2, u2h(H2.x), a0); a1 = __hfma2(v2, u2h(H2.y), a1);
    a0 = __hfma2(v3, u2h(H3.x), a0); a1 = __hfma2(v3, u2h(H3.y), a1);
  }
  for (; e < end; e += 4) {
    int2 E0 = ev[e];
    uint2 H0 = *(const uint2*)&cur_h[E0.x * DIM + d4];
    __half2 v0 = __float2half2_rn(__int_as_float(E0.y));
    a0 = __hfma2(v0, u2h(H0.x), a0); a1 = __hfma2(v0, u2h(H0.y), a1);
  }
  // reduce across the 4 edge groups (packed fp16 adds)
  a0 = __hadd2(a0, h2shfl(a0, 16)); a1 = __hadd2(a1, h2shfl(a1, 16));
  a0 = __hadd2(a0, h2shfl(a0, 32)); a1 = __hadd2(a1, h2shfl(a1, 32));
  if (g == 0) {
    *(uint2*)&nxt_h[node * DIM + d4] = make_uint2(h2u(a0), h2u(a1));
  }
}

// ---------------- batch gather: ue/pe/ne = ALPHA*(x0 + x1 + x2 + x3) + reg partials ------
__global__ __launch_bounds__(256) void k_gather(const float4* __restrict__ uemb4,
                                                const float4* __restrict__ iemb4,
                                                const uint2* __restrict__ x1h,
                                                const uint2* __restrict__ x2h,
                                                const uint2* __restrict__ x3h,
                                                const int* __restrict__ user,
                                                const int* __restrict__ pos,
                                                const int* __restrict__ neg,
                                                float4* __restrict__ ue4,
                                                float4* __restrict__ pe4,
                                                float4* __restrict__ ne4,
                                                float* __restrict__ partR) {
  __shared__ float sred[256];
  int t = threadIdx.x;
  int gid = blockIdx.x * 256 + t;    // BATCH*16 exact
  int i = gid >> 4, q = gid & 15;
  int u = user[i], p = pos[i], n = neg[i];
  int qu = u * 16 + q;
  int qp = (NUSERS + p) * 16 + q;
  int qn = (NUSERS + n) * 16 + q;
  float4 eu = uemb4[qu];                       // x0 user (also reg term)
  float4 ep = iemb4[p * 16 + q];               // x0 pos  (also reg term)
  float4 en = iemb4[n * 16 + q];               // x0 neg  (also reg term)
  float4 a1 = h4f(x1h[qu]), a2 = h4f(x2h[qu]), a3 = h4f(x3h[qu]);
  float4 b1 = h4f(x1h[qp]), b2 = h4f(x2h[qp]), b3 = h4f(x3h[qp]);
  float4 c1 = h4f(x1h[qn]), c2 = h4f(x2h[qn]), c3 = h4f(x3h[qn]);
  float4 su = make_float4(ALPHA * (eu.x + a1.x + a2.x + a3.x),
                          ALPHA * (eu.y + a1.y + a2.y + a3.y),
                          ALPHA * (eu.z + a1.z + a2.z + a3.z),
                          ALPHA * (eu.w + a1.w + a2.w + a3.w));
  float4 sp = make_float4(ALPHA * (ep.x + b1.x + b2.x + b3.x),
                          ALPHA * (ep.y + b1.y + b2.y + b3.y),
                          ALPHA * (ep.z + b1.z + b2.z + b3.z),
                          ALPHA * (ep.w + b1.w + b2.w + b3.w));
  float4 sn = make_float4(ALPHA * (en.x + c1.x + c2.x + c3.x),
                          ALPHA * (en.y + c1.y + c2.y + c3.y),
                          ALPHA * (en.z + c1.z + c2.z + c3.z),
                          ALPHA * (en.w + c1.w + c2.w + c3.w));
  ue4[gid] = su;  pe4[gid] = sp;  ne4[gid] = sn;
  sred[t] = eu.x * eu.x + eu.y * eu.y + eu.z * eu.z + eu.w * eu.w
          + ep.x * ep.x + ep.y * ep.y + ep.z * ep.z + ep.w * ep.w
          + en.x * en.x + en.y * en.y + en.z * en.z + en.w * en.w;
  __syncthreads();
  for (int off = 128; off > 0; off >>= 1) {
    if (t < off) sred[t] += sred[t + off];
    __syncthreads();
  }
  if (t == 0) partR[blockIdx.x] = sred[0];
}

// ---------------- small sums: S[0]=reg partials, S[1]=sum(beta_u), S[2]=sum(beta_i) -------
__global__ void k_small(const float* __restrict__ beta_u, const float* __restrict__ beta_i,
                        const float* __restrict__ partR, float* __restrict__ S) {
  __shared__ float a[256], b[256], c[256];
  int t = threadIdx.x;
  float su = 0.f, si = 0.f, sr = 0.f;
  for (int j = t; j < BATCH; j += 256) { su += beta_u[j]; si += beta_i[j]; }
  for (int j = t; j < NGB; j += 256) sr += partR[j];
  a[t] = su; b[t] = si; c[t] = sr;
  __syncthreads();
  for (int off = 128; off > 0; off >>= 1) {
    if (t < off) { a[t] += a[t + off]; b[t] += b[t + off]; c[t] += c[t + off]; }
    __syncthreads();
  }
  if (t == 0) { S[0] = c[0]; S[1] = a[0]; S[2] = b[0]; }
}

__global__ void k_invperm(const int* __restrict__ perm, int* __restrict__ inv) {
  int i = blockIdx.x * blockDim.x + threadIdx.x;
  if (i < BATCH) inv[perm[i]] = i;
}

// ---------------- mixes, scores, row normalization (wave per row); also emit bf16 ----------
__global__ void k_mixnorm(const float* __restrict__ ue, const float* __restrict__ pe,
                          const float* __restrict__ ne, const float* __restrict__ beta_u,
                          const float* __restrict__ beta_i, const int* __restrict__ perm,
                          float* __restrict__ An_u, float* __restrict__ Pn_u,
                          float* __restrict__ An_p, float* __restrict__ Pn_p,
                          unsigned short* __restrict__ An_uh, unsigned short* __restrict__ Pn_uh,
                          unsigned short* __restrict__ An_ph, unsigned short* __restrict__ Pn_ph,
                          float* __restrict__ pos_sc, float* __restrict__ neg_sc,
                          float* __restrict__ nms) {
  int gid = blockIdx.x * blockDim.x + threadIdx.x;   // BATCH*64 exact
  int i = gid >> 6, d = gid & 63;
  int pi = perm[i];
  float uei = ue[i * DIM + d], pei = pe[i * DIM + d], nei = ne[i * DIM + d];
  float ud = ue[pi * DIM + d], pd = pe[pi * DIM + d], nd = ne[pi * DIM + d];
  float bu = beta_u[i], bi = beta_i[i];
  float um = bu * uei + (1.f - bu) * ud;
  float pm = bi * pei + (1.f - bi) * pd;
  float nm = bi * nei + (1.f - bi) * nd;
  float r0 = uei * pei, r1 = uei * nei, r2 = uei * nm;
  float r3 = uei * uei, r4 = um * um, r5 = pei * pei, r6 = pm * pm;
  for (int o = 32; o > 0; o >>= 1) {
    r0 += __shfl_xor(r0, o); r1 += __shfl_xor(r1, o); r2 += __shfl_xor(r2, o);
    r3 += __shfl_xor(r3, o); r4 += __shfl_xor(r4, o); r5 += __shfl_xor(r5, o);
    r6 += __shfl_xor(r6, o);
  }
  if (d == 0) { pos_sc[i] = r0; neg_sc[i] = r1; nms[i] = r2; }
  float inu  = 1.f / fmaxf(sqrtf(r3), 1e-12f);
  float inum = 1.f / fmaxf(sqrtf(r4), 1e-12f);
  float inp  = 1.f / fmaxf(sqrtf(r5), 1e-12f);
  float inpm = 1.f / fmaxf(sqrtf(r6), 1e-12f);
  float a0 = uei * inu, p0 = um * inum, a1 = pei * inp, p1 = pm * inpm;
  An_u[gid] = a0;  Pn_u[gid] = p0;  An_p[gid] = a1;  Pn_p[gid] = p1;
  An_uh[gid] = bf16r(a0); Pn_uh[gid] = bf16r(p0);
  An_ph[gid] = bf16r(a1); Pn_ph[gid] = bf16r(p1);
}

// ---------------- collective-mix: parallel partial sums (64 blocks) ----------------
__global__ void k_colpart(const float* __restrict__ ue, const float* __restrict__ pe,
                          const float* __restrict__ cu, const float* __restrict__ cp,
                          float* __restrict__ S) {
  __shared__ float smu[4][64], smp[4][64];
  int t = threadIdx.x, d = t & 63, q = t >> 6;
  int r0 = blockIdx.x * 64 + q * 16;
  float su = 0.f, sp = 0.f;
#pragma unroll 4
  for (int i = r0; i < r0 + 16; ++i) {
    su = fmaf(cu[i], ue[i * DIM + d], su);
    sp = fmaf(cp[i], pe[i * DIM + d], sp);
  }
  smu[q][d] = su; smp[q][d] = sp;
  __syncthreads();
  if (t < 64) {
    atomicAdd(&S[64 + d],  smu[0][d] + smu[1][d] + smu[2][d] + smu[3][d]);
    atomicAdd(&S[128 + d], smp[0][d] + smp[1][d] + smp[2][d] + smp[3][d]);
  }
}

__global__ void k_colnorm(const float* __restrict__ S,
                          float* __restrict__ c_u, float* __restrict__ c_p) {
  int t = threadIdx.x;            // 128 threads = 2 waves
  int d = t & 63;
  float v = (t < 64) ? S[64 + d] : S[128 + d];
  float n = wred64(v * v);        // wave-local: wave0=u side, wave1=p side
  float inv = 1.f / fmaxf(sqrtf(n), 1e-12f);
  if (t < 64) c_u[d] = v * inv;
  else        c_p[d] = v * inv;
}

// ---------------- per-row sims (wave per row) ----------------
__global__ void k_sims(const float* __restrict__ An_u, const float* __restrict__ Pn_u,
                       const float* __restrict__ An_p, const float* __restrict__ Pn_p,
                       const float* __restrict__ c_u, const float* __restrict__ c_p,
                       const int* __restrict__ perm, const int* __restrict__ inv,
                       float* __restrict__ dis_u, float* __restrict__ col_u,
                       float* __restrict__ posd_u, float* __restrict__ cross_u,
                       float* __restrict__ dis_p, float* __restrict__ col_p,
                       float* __restrict__ posd_p, float* __restrict__ cross_p) {
  int gid = blockIdx.x * blockDim.x + threadIdx.x;
  int r = gid >> 6, d = gid & 63;
  int pr = perm[r], ir = inv[r];
  float au = An_u[r * DIM + d], pu = Pn_u[r * DIM + d];
  float ap = An_p[r * DIM + d], pp = Pn_p[r * DIM + d];
  float r0 = au * An_u[pr * DIM + d];
  float r1 = au * c_u[d];
  float r2 = au * pu;
  float r3 = au * Pn_u[ir * DIM + d];
  float r4 = ap * An_p[pr * DIM + d];
  float r5 = ap * c_p[d];
  float r6 = ap * pp;
  float r7 = ap * Pn_p[ir * DIM + d];
  for (int o = 32; o > 0; o >>= 1) {
    r0 += __shfl_xor(r0, o); r1 += __shfl_xor(r1, o); r2 += __shfl_xor(r2, o);
    r3 += __shfl_xor(r3, o); r4 += __shfl_xor(r4, o); r5 += __shfl_xor(r5, o);
    r6 += __shfl_xor(r6, o); r7 += __shfl_xor(r7, o);
  }
  if (d == 0) {
    dis_u[r] = r0 * INVT; col_u[r] = r1 * INVT; posd_u[r] = r2 * INVT; cross_u[r] = r3 * INVT;
    dis_p[r] = r4 * INVT; col_p[r] = r5 * INVT; posd_p[r] = r6 * INVT; cross_p[r] = r7 * INVT;
  }
}

// ---------------- MFMA fused matmul + fixed-shift sumexp over G = An @ Pn^T / T ----------
__global__ __launch_bounds__(256) void k_lse_mfma(const unsigned short* __restrict__ Anh,
                                                  const unsigned short* __restrict__ Pnh,
                                                  float* __restrict__ s_row) {
  const float C1 = INVT * 1.4426950408889634f;   // INVT*log2(e)
  int rb = blockIdx.x >> 3, cb = blockIdx.x & 7;
  int w = threadIdx.x >> 6, lane = threadIdx.x & 63;
  int r0 = rb * 64 + w * 16;
  int arow = r0 + (lane & 15);
  int koff = (lane >> 4) * 8;
  v8s a_lo = *(const v8s*)&Anh[arow * DIM + koff];
  v8s a_hi = *(const v8s*)&Anh[arow * DIM + koff + 32];
  float s0 = 0.f, s1 = 0.f, s2 = 0.f, s3 = 0.f;
  int cbase = cb * 512;
#pragma unroll 2
  for (int c0 = cbase; c0 < cbase + 512; c0 += 16) {
    int brow = c0 + (lane & 15);
    v8s b_lo = *(const v8s*)&Pnh[brow * DIM + koff];
    v8s b_hi = *(const v8s*)&Pnh[brow * DIM + koff + 32];
    f32x4 acc = {0.f, 0.f, 0.f, 0.f};
    acc = __builtin_amdgcn_mfma_f32_16x16x32_bf16(a_lo, b_lo, acc, 0, 0, 0);
    acc = __builtin_amdgcn_mfma_f32_16x16x32_bf16(a_hi, b_hi, acc, 0, 0, 0);
    s0 += exp2f(fmaf(acc[0], C1, -C1));
    s1 += exp2f(fmaf(acc[1], C1, -C1));
    s2 += exp2f(fmaf(acc[2], C1, -C1));
    s3 += exp2f(fmaf(acc[3], C1, -C1));
  }
  // sum the 16 col-slots of each row (C/D: col=lane&15, row=(lane>>4)*4+reg)
  for (int o = 1; o <= 8; o <<= 1) {
    s0 += __shfl_xor(s0, o); s1 += __shfl_xor(s1, o);
    s2 += __shfl_xor(s2, o); s3 += __shfl_xor(s3, o);
  }
  if ((lane & 15) == 0) {
    int rq = r0 + (lane >> 4) * 4;
    atomicAdd(&s_row[rq + 0], s0);
    atomicAdd(&s_row[rq + 1], s1);
    atomicAdd(&s_row[rq + 2], s2);
    atomicAdd(&s_row[rq + 3], s3);
  }
}

// ---------------- final combine (single block) — OUTPUT IS FLOAT32 ----------------
__global__ void k_final(const float* __restrict__ m_u, const float* __restrict__ s_u,
                        const float* __restrict__ dis_u, const float* __restrict__ col_u,
                        const float* __restrict__ posd_u, const float* __restrict__ cross_u,
                        const float* __restrict__ m_p, const float* __restrict__ s_p,
                        const float* __restrict__ dis_p, const float* __restrict__ col_p,
                        const float* __restrict__ posd_p, const float* __restrict__ cross_p,
                        const float* __restrict__ pos_sc, const float* __restrict__ neg_sc,
                        const float* __restrict__ nms, const int* __restrict__ inv,
                        const float* __restrict__ S, float* __restrict__ out) {
  __shared__ float red[6][256];
  int t = threadIdx.x;
  float lpu = 0.f, lnu = 0.f, lpp = 0.f, lnp = 0.f, bp = 0.f, bn = 0.f;
  for (int r = t; r < BATCH; r += 256) {
    int ir = inv[r];
    {
      float M = m_u[r], Sv = s_u[r];
      float d2 = col_u[r];
      float d1 = dis_u[r];
      float nm2 = fmaxf(M, fmaxf(d1, d2));
      float ss = Sv * __expf(M - nm2) + __expf(d1 - nm2) + __expf(d2 - nm2);
      lpu += nm2 + logf(ss) - posd_u[r];
      float d1n = dis_u[ir];
      nm2 = fmaxf(M, fmaxf(d1n, d2));
      ss = Sv * __expf(M - nm2) + __expf(d1n - nm2) + __expf(d2 - nm2);
      lnu += nm2 + logf(ss) - cross_u[r];
    }
    {
      float M = m_p[r], Sv = s_p[r];
      float d2 = col_p[r];
      float d1 = dis_p[r];
      float nm2 = fmaxf(M, fmaxf(d1, d2));
      float ss = Sv * __expf(M - nm2) + __expf(d1 - nm2) + __expf(d2 - nm2);
      lpp += nm2 + logf(ss) - posd_p[r];
      float d1n = dis_p[ir];
      nm2 = fmaxf(M, fmaxf(d1n, d2));
      ss = Sv * __expf(M - nm2) + __expf(d1n - nm2) + __expf(d2 - nm2);
      lnp += nm2 + logf(ss) - cross_p[r];
    }
    float ps = pos_sc[r];
    bp += softplusf(neg_sc[r] - ps);
    bn += softplusf(nms[r] - ps);
  }
  red[0][t] = lpu; red[1][t] = lnu; red[2][t] = lpp;
  red[3][t] = lnp; red[4][t] = bp;  red[5][t] = bn;
  __syncthreads();
  for (int off = 128; off > 0; off >>= 1) {
    if (t < off)
      for (int c = 0; c < 6; c++) red[c][t] += red[c][t + off];
    __syncthreads();
  }
  if (t == 0) {
    const float inv_b = 1.f / (float)BATCH;
    float mbu = S[1] * inv_b;            // mean(beta_u)
    float b   = S[2] * inv_b;            // mean(beta_i)
    float cl_u = mbu * (red[0][0] * inv_b) + (1.f - mbu) * (red[1][0] * inv_b);
    float cl_p = b   * (red[2][0] * inv_b) + (1.f - b)   * (red[3][0] * inv_b);
    float main_m = b * (red[4][0] * inv_b) + (1.f - b) * (red[5][0] * inv_b);
    float reg = REGC * S[0] * inv_b;
    float loss = main_m + LAMBDA * (cl_u + cl_p) + reg;
    out[0] = loss;                       // float32
  }
}

extern "C" void kernel_launch(void* const* d_in, const int* in_sizes, int n_in,
                              void* d_out, int out_size, void* d_ws, size_t ws_size,
                              hipStream_t stream) {
  const float* uemb   = (const float*)d_in[0];
  const float* iemb   = (const float*)d_in[1];
  const int*   rows   = (const int*)d_in[2];
  const int*   cols   = (const int*)d_in[3];
  const float* vals   = (const float*)d_in[4];
  const int*   user   = (const int*)d_in[5];
  const int*   pos    = (const int*)d_in[6];
  const int*   neg    = (const int*)d_in[7];
  const float* beta_u = (const float*)d_in[8];
  const float* beta_i = (const float*)d_in[9];
  const int*   perm   = (const int*)d_in[10];
  const float* cu     = (const float*)d_in[11];
  const float* cp     = (const float*)d_in[12];

  char* w = (char*)d_ws;
  size_t off = 0;
  auto alloc = [&](size_t bytes) -> char* {
    char* p = w + off;
    off += (bytes + 255) & ~(size_t)255;
    return p;
  };
  unsigned short* x0h = (unsigned short*)alloc((size_t)ND * 2);
  unsigned short* x1h = (unsigned short*)alloc((size_t)ND * 2);
  unsigned short* x2h = (unsigned short*)alloc((size_t)ND * 2);
  unsigned short* x3h = (unsigned short*)alloc((size_t)ND * 2);
  int2*  ev      = (int2*) alloc((size_t)NNZ * 8);
  int*   row_ptr = (int*)  alloc((size_t)(NN + 1) * 4);
  int*   bhist   = (int*)  alloc((size_t)NB * 4);
  int*   bbase   = (int*)  alloc((size_t)(NB + 1) * 4);
  int*   bcur    = (int*)  alloc((size_t)NB * 4);
  float* partR   = (float*)alloc((size_t)NGB * 4);
  float* ue      = (float*)alloc((size_t)BATCH * DIM * 4);
  float* pe      = (float*)alloc((size_t)BATCH * DIM * 4);
  float* ne      = (float*)alloc((size_t)BATCH * DIM * 4);
  float* An_u    = (float*)alloc((size_t)BATCH * DIM * 4);
  float* Pn_u    = (float*)alloc((size_t)BATCH * DIM * 4);
  float* An_p    = (float*)alloc((size_t)BATCH * DIM * 4);
  float* Pn_p    = (float*)alloc((size_t)BATCH * DIM * 4);
  unsigned short* An_uh = (unsigned short*)alloc((size_t)BATCH * DIM * 2);
  unsigned short* Pn_uh = (unsigned short*)alloc((size_t)BATCH * DIM * 2);
  unsigned short* An_ph = (unsigned short*)alloc((size_t)BATCH * DIM * 2);
  unsigned short* Pn_ph = (unsigned short*)alloc((size_t)BATCH * DIM * 2);
  float* pos_sc  = (float*)alloc((size_t)BATCH * 4);
  float* neg_sc  = (float*)alloc((size_t)BATCH * 4);
  float* nms     = (float*)alloc((size_t)BATCH * 4);
  float* dis_u   = (float*)alloc((size_t)BATCH * 4);
  float* col_u   = (float*)alloc((size_t)BATCH * 4);
  float* posd_u  = (float*)alloc((size_t)BATCH * 4);
  float* cross_u = (float*)alloc((size_t)BATCH * 4);
  float* m_u     = (float*)alloc((size_t)BATCH * 4);
  float* s_u     = (float*)alloc((size_t)BATCH * 4);
  float* dis_p   = (float*)alloc((size_t)BATCH * 4);
  float* col_p   = (float*)alloc((size_t)BATCH * 4);
  float* posd_p  = (float*)alloc((size_t)BATCH * 4);
  float* cross_p = (float*)alloc((size_t)BATCH * 4);
  float* m_p     = (float*)alloc((size_t)BATCH * 4);
  float* s_p     = (float*)alloc((size_t)BATCH * 4);
  int*   invp    = (int*)  alloc((size_t)BATCH * 4);
  float* c_u     = (float*)alloc(256);
  float* c_p     = (float*)alloc(256);
  float* S       = (float*)alloc(1024);

  // tmp (int2 per edge, 25.6MB) aliases x0h+x1h (38.4MB) — dead until k_inith/k_spmv_h,
  // which run AFTER the CSR build.
  int2* tmp = (int2*)x0h;

  // 1. zero bucket hist + preset LSE state (m=M0, s=0)
  k_zero<<<(NN + 255) / 256, 256, 0, stream>>>(bhist, S, m_u, s_u, m_p, s_p);
  // 2. CSR build: bucket hist -> scan -> 2-pass bucket sort (row_ptr built in pass B)
  k_bhist<<<BHB, 256, 0, stream>>>(rows, bhist);
  k_bscan<<<1, 512, 0, stream>>>(bhist, bbase, bcur, row_ptr);
  k_bucketA<<<(NNZ + ACHUNK - 1) / ACHUNK, 256, 0, stream>>>(rows, cols, vals, bcur, tmp);
  k_bucketB<<<NB, 512, 0, stream>>>(bbase, tmp, ev, row_ptr);
  // 3. init x0h = fp16(concat(user_emb, item_emb))
  k_inith<<<(ND / 4 + 255) / 256, 256, 0, stream>>>((const float4*)uemb, (const float4*)iemb,
                                                    (uint2*)x0h);
  // 4. three GCN layers (fp16 packed-FMA propagation, separate layer outputs)
  k_spmv_h<<<(NN + 3) / 4, 256, 0, stream>>>(row_ptr, ev, x0h, x1h);
  k_spmv_h<<<(NN + 3) / 4, 256, 0, stream>>>(row_ptr, ev, x1h, x2h);
  k_spmv_h<<<(NN + 3) / 4, 256, 0, stream>>>(row_ptr, ev, x2h, x3h);
  // 5. batch gather (sum of layer outputs for just the batch rows) + small sums
  k_gather<<<NGB, 256, 0, stream>>>((const float4*)uemb, (const float4*)iemb,
                                    (const uint2*)x1h, (const uint2*)x2h,
                                    (const uint2*)x3h, user, pos, neg,
                                    (float4*)ue, (float4*)pe, (float4*)ne, partR);
  k_small<<<1, 256, 0, stream>>>(beta_u, beta_i, partR, S);
  k_invperm<<<(BATCH + 255) / 256, 256, 0, stream>>>(perm, invp);
  // 6. mixes, scores, normalization (+ bf16 copies for MFMA)
  k_mixnorm<<<(BATCH * DIM) / 256, 256, 0, stream>>>(ue, pe, ne, beta_u, beta_i, perm,
                                                     An_u, Pn_u, An_p, Pn_p,
                                                     An_uh, Pn_uh, An_ph, Pn_ph,
                                                     pos_sc, neg_sc, nms);
  k_colpart<<<BATCH / 64, 256, 0, stream>>>(ue, pe, cu, cp, S);
  k_colnorm<<<1, 128, 0, stream>>>(S, c_u, c_p);
  k_sims<<<(BATCH * DIM) / 256, 256, 0, stream>>>(An_u, Pn_u, An_p, Pn_p, c_u, c_p,
                                                  perm, invp,
                                                  dis_u, col_u, posd_u, cross_u,
                                                  dis_p, col_p, posd_p, cross_p);
  // 7. MFMA matmul + fixed-shift sumexp (user side, pos side)
  k_lse_mfma<<<512, 256, 0, stream>>>(An_uh, Pn_uh, s_u);
  k_lse_mfma<<<512, 256, 0, stream>>>(An_ph, Pn_ph, s_p);
  // 8. final combine
  k_final<<<1, 256, 0, stream>>>(m_u, s_u, dis_u, col_u, posd_u, cross_u,
                                 m_p, s_p, dis_p, col_p, posd_p, cross_p,
                                 pos_sc, neg_sc, nms, invp, S,
                                 (float*)d_out);
}

// Round 10
// 361.384 us; speedup vs baseline: 4.4518x; 1.1392x over previous
//
#include <hip/hip_runtime.h>
#include <hip/hip_bf16.h>
#include <hip/hip_fp16.h>

#define NUSERS 100000
#define NITEMS 50000
#define NN     150001          // total nodes
#define NNZ    3200000         // 2 * NNZ_INTER
#define BATCH  4096
#define DIM    64
#define ND     (NN * DIM)
#define ALPHA  0.25f           // 1/(N_LAYERS+1)
#define INVT   5.0f            // 1/TEMP
#define LAMBDA 0.1f
#define REGC   1.0e-4f
#define BKSH   9               // 512 nodes per bucket
#define NB     293             // ceil(150001/512)
#define ACHUNK 4096            // edges per bucketA block
#define M0     5.0f            // fixed LSE shift: logits = sim/T ∈ [-5,5]
#define NGB    256             // k_gather blocks (BATCH*16/256)
#define BHB    256             // k_bhist blocks
#define CMASK  0x3FFFF         // 18-bit col mask
#define SPMVB  2048            // k_spmv_h grid (8 blocks/CU -> 32 waves/CU)

typedef __attribute__((ext_vector_type(8))) short v8s;    // 8 bf16 (4 VGPRs)
typedef __attribute__((ext_vector_type(4))) float f32x4;  // MFMA acc

union H2U { unsigned u; __half2 h; };
__device__ __forceinline__ __half2 u2h(unsigned x) { H2U t; t.u = x; return t.h; }
__device__ __forceinline__ unsigned h2u(__half2 h) { H2U t; t.h = h; return t.u; }
__device__ __forceinline__ __half2 h2shfl(__half2 v, int m) {
  return u2h((unsigned)__shfl_xor((int)h2u(v), m));
}

__device__ __forceinline__ float wred64(float v) {
  for (int o = 32; o > 0; o >>= 1) v += __shfl_xor(v, o);
  return v;
}

__device__ __forceinline__ float softplusf(float x) {
  return (x > 20.f) ? x : log1pf(__expf(x));
}

__device__ __forceinline__ unsigned short bf16r(float v) {
  unsigned x = __float_as_uint(v);
  return (unsigned short)((x + 0x7fff + ((x >> 16) & 1)) >> 16);   // RNE
}

// fp16 quad (uint2 = 4 halves) -> float4
__device__ __forceinline__ float4 h4f(uint2 u) {
  float2 lo = __half22float2(u2h(u.x));
  float2 hi = __half22float2(u2h(u.y));
  return make_float4(lo.x, lo.y, hi.x, hi.y);
}

// ---------------- zero scratch + preset LSE state ----------------
__global__ void k_zero(int* __restrict__ bhist, float* __restrict__ S,
                       float* __restrict__ m_u, float* __restrict__ s_u,
                       float* __restrict__ m_p, float* __restrict__ s_p) {
  int i = blockIdx.x * blockDim.x + threadIdx.x;
  if (i < NB) bhist[i] = 0;
  if (i < 256) S[i] = 0.f;
  if (i < BATCH) { s_u[i] = 0.f; s_p[i] = 0.f; m_u[i] = M0; m_p[i] = M0; }
}

// ---------------- x0h = fp16(concat(user_emb, item_emb)) ----------------
__global__ void k_inith(const float4* __restrict__ uemb, const float4* __restrict__ iemb,
                        uint2* __restrict__ x0h) {
  int q = blockIdx.x * blockDim.x + threadIdx.x;   // quads: ND/4
  if (q >= ND / 4) return;
  int n = q >> 4;                                   // 16 quads per node
  float4 v = (n < NUSERS) ? uemb[q] : iemb[q - NUSERS * 16];
  x0h[q] = make_uint2(h2u(__floats2half2_rn(v.x, v.y)),
                      h2u(__floats2half2_rn(v.z, v.w)));
}

// ---------------- dis[n] = rsqrt(deg(n)) from row_ptr ----------------
__global__ void k_dis(const int* __restrict__ row_ptr, float* __restrict__ dis) {
  int n = blockIdx.x * blockDim.x + threadIdx.x;
  if (n < NN) {
    int d = row_ptr[n + 1] - row_ptr[n];
    dis[n] = (d > 0) ? rsqrtf((float)d) : 0.f;
  }
}

// ---------------- bucket histogram: LDS-private, 293 global atomics per block -----------
__global__ __launch_bounds__(256) void k_bhist(const int* __restrict__ rows,
                                               int* __restrict__ bhist) {
  __shared__ int lh[NB];
  int t = threadIdx.x;
  for (int i = t; i < NB; i += 256) lh[i] = 0;
  __syncthreads();
  const int per = (NNZ + BHB - 1) / BHB;
  int base = blockIdx.x * per;
  int end = min(base + per, NNZ);
  for (int e = base + t; e < end; e += 256)
    atomicAdd(&lh[rows[e] >> BKSH], 1);
  __syncthreads();
  for (int i = t; i < NB; i += 256) {
    int c = lh[i];
    if (c) atomicAdd(&bhist[i], c);
  }
}

// ---------------- bucket scan (one block, 512 threads) ----------------
__global__ __launch_bounds__(512) void k_bscan(const int* __restrict__ bhist,
                                               int* __restrict__ bbase, int* __restrict__ bcur,
                                               int* __restrict__ row_ptr) {
  __shared__ int sc[512];
  int t = threadIdx.x;
  int v = (t < NB) ? bhist[t] : 0;
  sc[t] = v;
  __syncthreads();
  for (int off = 1; off < 512; off <<= 1) {
    int u = (t >= off) ? sc[t - off] : 0;
    __syncthreads();
    sc[t] += u;
    __syncthreads();
  }
  int ex = sc[t] - v;                  // exclusive prefix
  if (t < NB) { bbase[t] = ex; bcur[t] = ex; }
  if (t == NB - 1) { bbase[NB] = ex + v; row_ptr[NN] = ex + v; }  // == NNZ
}

// ---------------- bucket pass A: LDS counting-sort, packed 4-byte output ----------------
// packed word: col | (row&511)<<18   (col < 2^18, row-local < 2^9); vals recomputed later
__global__ __launch_bounds__(256) void k_bucketA(const int* __restrict__ rows,
                                                 const int* __restrict__ cols,
                                                 int* __restrict__ bcur,
                                                 int* __restrict__ tmp) {
  __shared__ int lhist[NB];
  __shared__ int lscan[NB];
  __shared__ int ldelta[NB];
  __shared__ int lcnt[NB];
  __shared__ int2 ent[ACHUNK];        // x=packed col/rowlocal, y=ldelta
  int t = threadIdx.x;
  int base = blockIdx.x * ACHUNK;
  for (int b = t; b < NB; b += 256) { lhist[b] = 0; lcnt[b] = 0; }
  __syncthreads();
  int pkv[16], bkt[16];
  int nval = 0;
#pragma unroll
  for (int k = 0; k < 16; k++) {
    int e = base + t + k * 256;                 // coalesced
    if (e < NNZ) {
      int r = rows[e];
      pkv[k] = cols[e] | ((r & 511) << 18);
      bkt[k] = r >> BKSH;
      atomicAdd(&lhist[bkt[k]], 1);
      nval = k + 1;
    }
  }
  __syncthreads();
  if (t == 0) {
    int run = 0;
    for (int b = 0; b < NB; b++) { lscan[b] = run; run += lhist[b]; }
  }
  __syncthreads();
  for (int b = t; b < NB; b += 256) {
    int c = lhist[b];
    int g = (c > 0) ? atomicAdd(&bcur[b], c) : 0;
    ldelta[b] = g - lscan[b];
  }
  __syncthreads();
#pragma unroll
  for (int k = 0; k < 16; k++) {
    if (k < nval) {
      int b = bkt[k];
      int lp = atomicAdd(&lcnt[b], 1);
      ent[lscan[b] + lp] = make_int2(pkv[k], ldelta[b]);
    }
  }
  __syncthreads();
  int tot = min(ACHUNK, NNZ - base);
  for (int j = t; j < tot; j += 256) {
    int2 E = ent[j];
    tmp[E.y + j] = E.x;                        // contiguous run per bucket -> full lines
  }
}

// ---------------- bucket pass B: per-bucket row_ptr build + final scatter ----------------
__global__ __launch_bounds__(512) void k_bucketB(const int* __restrict__ bbase,
                                                 const int* __restrict__ tmp,
                                                 int* __restrict__ ev,
                                                 int* __restrict__ row_ptr) {
  __shared__ int h[512], sc[512], c2[512], rstart[512];
  int b = blockIdx.x, t = threadIdx.x;
  int nbase = b << BKSH;
  h[t] = 0; c2[t] = 0;
  __syncthreads();
  int beg = bbase[b], end = bbase[b + 1];
  for (int j = beg + t; j < end; j += 512)
    atomicAdd(&h[tmp[j] >> 18], 1);
  __syncthreads();
  int v = h[t];
  sc[t] = v;
  __syncthreads();
  for (int off = 1; off < 512; off <<= 1) {
    int u = (t >= off) ? sc[t - off] : 0;
    __syncthreads();
    sc[t] += u;
    __syncthreads();
  }
  int rp = beg + sc[t] - v;            // exclusive scan -> row start
  rstart[t] = rp;
  int node = nbase + t;
  if (node < NN) row_ptr[node] = rp;
  __syncthreads();
  for (int j = beg + t; j < end; j += 512) {
    int w = tmp[j];
    int ln = w >> 18;
    int lp = atomicAdd(&c2[ln], 1);
    ev[rstart[ln] + lp] = w & CMASK;
  }
}

// ---------------- gather SpMV (fp16, 4B edges, dis-recomputed vals) ----------------
// wave/node, 4 grp x 16 lanes x 4 dims; grid-stride; predicated batch tail.
__global__ __launch_bounds__(256) void k_spmv_h(const int* __restrict__ row_ptr,
                                                const int* __restrict__ ev,
                                                const float* __restrict__ dis,
                                                const unsigned short* __restrict__ cur_h,
                                                unsigned short* __restrict__ nxt_h) {
  int lane = threadIdx.x & 63;
  int g = lane >> 4;                 // edge group 0..3 (edges ≡ g mod 4)
  int d4 = (lane & 15) << 2;         // 4 dims per lane
  for (int node0 = blockIdx.x * 4 + (threadIdx.x >> 6); node0 < NN;
       node0 += SPMVB * 4) {
    int node = __builtin_amdgcn_readfirstlane(node0);
    int beg = row_ptr[node], end = row_ptr[node + 1];
    float dr = dis[node];            // wave-uniform
    __half2 a0 = __float2half2_rn(0.f);
    __half2 a1 = a0;
    int e = beg + g;
    for (; e + 12 < end; e += 16) {  // 4 edges in flight per lane
      int c0 = ev[e], c1 = ev[e + 4], c2 = ev[e + 8], c3 = ev[e + 12];
      uint2 H0 = *(const uint2*)&cur_h[c0 * DIM + d4];
      uint2 H1 = *(const uint2*)&cur_h[c1 * DIM + d4];
      uint2 H2 = *(const uint2*)&cur_h[c2 * DIM + d4];
      uint2 H3 = *(const uint2*)&cur_h[c3 * DIM + d4];
      float f0 = dis[c0], f1 = dis[c1], f2 = dis[c2], f3 = dis[c3];
      __half2 v0 = __float2half2_rn(dr * f0);
      __half2 v1 = __float2half2_rn(dr * f1);
      __half2 v2 = __float2half2_rn(dr * f2);
      __half2 v3 = __float2half2_rn(dr * f3);
      a0 = __hfma2(v0, u2h(H0.x), a0); a1 = __hfma2(v0, u2h(H0.y), a1);
      a0 = __hfma2(v1, u2h(H1.x), a0); a1 = __hfma2(v1, u2h(H1.y), a1);
      a0 = __hfma2(v2, u2h(H2.x), a0); a1 = __hfma2(v2, u2h(H2.y), a1);
      a0 = __hfma2(v3, u2h(H3.x), a0); a1 = __hfma2(v3, u2h(H3.y), a1);
    }
    // predicated batch tail (<=3 edges) — all loads issue concurrently
    {
      bool p0 = e < end, p1 = e + 4 < end, p2 = e + 8 < end;
      int c0 = 0, c1 = 0, c2 = 0;
      if (p0) c0 = ev[e];
      if (p1) c1 = ev[e + 4];
      if (p2) c2 = ev[e + 8];
      uint2 H0 = make_uint2(0u, 0u), H1 = H0, H2 = H0;
      float f0 = 0.f, f1 = 0.f, f2 = 0.f;
      if (p0) { H0 = *(const uint2*)&cur_h[c0 * DIM + d4]; f0 = dis[c0]; }
      if (p1) { H1 = *(const uint2*)&cur_h[c1 * DIM + d4]; f1 = dis[c1]; }
      if (p2) { H2 = *(const uint2*)&cur_h[c2 * DIM + d4]; f2 = dis[c2]; }
      __half2 v0 = __float2half2_rn(dr * f0);
      __half2 v1 = __float2half2_rn(dr * f1);
      __half2 v2 = __float2half2_rn(dr * f2);
      a0 = __hfma2(v0, u2h(H0.x), a0); a1 = __hfma2(v0, u2h(H0.y), a1);
      a0 = __hfma2(v1, u2h(H1.x), a0); a1 = __hfma2(v1, u2h(H1.y), a1);
      a0 = __hfma2(v2, u2h(H2.x), a0); a1 = __hfma2(v2, u2h(H2.y), a1);
    }
    // reduce across the 4 edge groups (packed fp16 adds)
    a0 = __hadd2(a0, h2shfl(a0, 16)); a1 = __hadd2(a1, h2shfl(a1, 16));
    a0 = __hadd2(a0, h2shfl(a0, 32)); a1 = __hadd2(a1, h2shfl(a1, 32));
    if (g == 0) {
      *(uint2*)&nxt_h[node * DIM + d4] = make_uint2(h2u(a0), h2u(a1));
    }
  }
}

// ---------------- batch gather: ue/pe/ne = ALPHA*(x0 + x1 + x2 + x3) + reg partials ------
__global__ __launch_bounds__(256) void k_gather(const float4* __restrict__ uemb4,
                                                const float4* __restrict__ iemb4,
                                                const uint2* __restrict__ x1h,
                                                const uint2* __restrict__ x2h,
                                                const uint2* __restrict__ x3h,
                                                const int* __restrict__ user,
                                                const int* __restrict__ pos,
                                                const int* __restrict__ neg,
                                                float4* __restrict__ ue4,
                                                float4* __restrict__ pe4,
                                                float4* __restrict__ ne4,
                                                float* __restrict__ partR) {
  __shared__ float sred[256];
  int t = threadIdx.x;
  int gid = blockIdx.x * 256 + t;    // BATCH*16 exact
  int i = gid >> 4, q = gid & 15;
  int u = user[i], p = pos[i], n = neg[i];
  int qu = u * 16 + q;
  int qp = (NUSERS + p) * 16 + q;
  int qn = (NUSERS + n) * 16 + q;
  float4 eu = uemb4[qu];                       // x0 user (also reg term)
  float4 ep = iemb4[p * 16 + q];               // x0 pos  (also reg term)
  float4 en = iemb4[n * 16 + q];               // x0 neg  (also reg term)
  float4 a1 = h4f(x1h[qu]), a2 = h4f(x2h[qu]), a3 = h4f(x3h[qu]);
  float4 b1 = h4f(x1h[qp]), b2 = h4f(x2h[qp]), b3 = h4f(x3h[qp]);
  float4 c1 = h4f(x1h[qn]), c2 = h4f(x2h[qn]), c3 = h4f(x3h[qn]);
  float4 su = make_float4(ALPHA * (eu.x + a1.x + a2.x + a3.x),
                          ALPHA * (eu.y + a1.y + a2.y + a3.y),
                          ALPHA * (eu.z + a1.z + a2.z + a3.z),
                          ALPHA * (eu.w + a1.w + a2.w + a3.w));
  float4 sp = make_float4(ALPHA * (ep.x + b1.x + b2.x + b3.x),
                          ALPHA * (ep.y + b1.y + b2.y + b3.y),
                          ALPHA * (ep.z + b1.z + b2.z + b3.z),
                          ALPHA * (ep.w + b1.w + b2.w + b3.w));
  float4 sn = make_float4(ALPHA * (en.x + c1.x + c2.x + c3.x),
                          ALPHA * (en.y + c1.y + c2.y + c3.y),
                          ALPHA * (en.z + c1.z + c2.z + c3.z),
                          ALPHA * (en.w + c1.w + c2.w + c3.w));
  ue4[gid] = su;  pe4[gid] = sp;  ne4[gid] = sn;
  sred[t] = eu.x * eu.x + eu.y * eu.y + eu.z * eu.z + eu.w * eu.w
          + ep.x * ep.x + ep.y * ep.y + ep.z * ep.z + ep.w * ep.w
          + en.x * en.x + en.y * en.y + en.z * en.z + en.w * en.w;
  __syncthreads();
  for (int off = 128; off > 0; off >>= 1) {
    if (t < off) sred[t] += sred[t + off];
    __syncthreads();
  }
  if (t == 0) partR[blockIdx.x] = sred[0];
}

// ---------------- small sums: S[0]=reg partials, S[1]=sum(beta_u), S[2]=sum(beta_i) -------
__global__ void k_small(const float* __restrict__ beta_u, const float* __restrict__ beta_i,
                        const float* __restrict__ partR, float* __restrict__ S) {
  __shared__ float a[256], b[256], c[256];
  int t = threadIdx.x;
  float su = 0.f, si = 0.f, sr = 0.f;
  for (int j = t; j < BATCH; j += 256) { su += beta_u[j]; si += beta_i[j]; }
  for (int j = t; j < NGB; j += 256) sr += partR[j];
  a[t] = su; b[t] = si; c[t] = sr;
  __syncthreads();
  for (int off = 128; off > 0; off >>= 1) {
    if (t < off) { a[t] += a[t + off]; b[t] += b[t + off]; c[t] += c[t + off]; }
    __syncthreads();
  }
  if (t == 0) { S[0] = c[0]; S[1] = a[0]; S[2] = b[0]; }
}

__global__ void k_invperm(const int* __restrict__ perm, int* __restrict__ inv) {
  int i = blockIdx.x * blockDim.x + threadIdx.x;
  if (i < BATCH) inv[perm[i]] = i;
}

// ---------------- mixes, scores, row normalization (wave per row); also emit bf16 ----------
__global__ void k_mixnorm(const float* __restrict__ ue, const float* __restrict__ pe,
                          const float* __restrict__ ne, const float* __restrict__ beta_u,
                          const float* __restrict__ beta_i, const int* __restrict__ perm,
                          float* __restrict__ An_u, float* __restrict__ Pn_u,
                          float* __restrict__ An_p, float* __restrict__ Pn_p,
                          unsigned short* __restrict__ An_uh, unsigned short* __restrict__ Pn_uh,
                          unsigned short* __restrict__ An_ph, unsigned short* __restrict__ Pn_ph,
                          float* __restrict__ pos_sc, float* __restrict__ neg_sc,
                          float* __restrict__ nms) {
  int gid = blockIdx.x * blockDim.x + threadIdx.x;   // BATCH*64 exact
  int i = gid >> 6, d = gid & 63;
  int pi = perm[i];
  float uei = ue[i * DIM + d], pei = pe[i * DIM + d], nei = ne[i * DIM + d];
  float ud = ue[pi * DIM + d], pd = pe[pi * DIM + d], nd = ne[pi * DIM + d];
  float bu = beta_u[i], bi = beta_i[i];
  float um = bu * uei + (1.f - bu) * ud;
  float pm = bi * pei + (1.f - bi) * pd;
  float nm = bi * nei + (1.f - bi) * nd;
  float r0 = uei * pei, r1 = uei * nei, r2 = uei * nm;
  float r3 = uei * uei, r4 = um * um, r5 = pei * pei, r6 = pm * pm;
  for (int o = 32; o > 0; o >>= 1) {
    r0 += __shfl_xor(r0, o); r1 += __shfl_xor(r1, o); r2 += __shfl_xor(r2, o);
    r3 += __shfl_xor(r3, o); r4 += __shfl_xor(r4, o); r5 += __shfl_xor(r5, o);
    r6 += __shfl_xor(r6, o);
  }
  if (d == 0) { pos_sc[i] = r0; neg_sc[i] = r1; nms[i] = r2; }
  float inu  = 1.f / fmaxf(sqrtf(r3), 1e-12f);
  float inum = 1.f / fmaxf(sqrtf(r4), 1e-12f);
  float inp  = 1.f / fmaxf(sqrtf(r5), 1e-12f);
  float inpm = 1.f / fmaxf(sqrtf(r6), 1e-12f);
  float a0 = uei * inu, p0 = um * inum, a1 = pei * inp, p1 = pm * inpm;
  An_u[gid] = a0;  Pn_u[gid] = p0;  An_p[gid] = a1;  Pn_p[gid] = p1;
  An_uh[gid] = bf16r(a0); Pn_uh[gid] = bf16r(p0);
  An_ph[gid] = bf16r(a1); Pn_ph[gid] = bf16r(p1);
}

// ---------------- collective-mix: parallel partial sums (64 blocks) ----------------
__global__ void k_colpart(const float* __restrict__ ue, const float* __restrict__ pe,
                          const float* __restrict__ cu, const float* __restrict__ cp,
                          float* __restrict__ S) {
  __shared__ float smu[4][64], smp[4][64];
  int t = threadIdx.x, d = t & 63, q = t >> 6;
  int r0 = blockIdx.x * 64 + q * 16;
  float su = 0.f, sp = 0.f;
#pragma unroll 4
  for (int i = r0; i < r0 + 16; ++i) {
    su = fmaf(cu[i], ue[i * DIM + d], su);
    sp = fmaf(cp[i], pe[i * DIM + d], sp);
  }
  smu[q][d] = su; smp[q][d] = sp;
  __syncthreads();
  if (t < 64) {
    atomicAdd(&S[64 + d],  smu[0][d] + smu[1][d] + smu[2][d] + smu[3][d]);
    atomicAdd(&S[128 + d], smp[0][d] + smp[1][d] + smp[2][d] + smp[3][d]);
  }
}

__global__ void k_colnorm(const float* __restrict__ S,
                          float* __restrict__ c_u, float* __restrict__ c_p) {
  int t = threadIdx.x;            // 128 threads = 2 waves
  int d = t & 63;
  float v = (t < 64) ? S[64 + d] : S[128 + d];
  float n = wred64(v * v);        // wave-local: wave0=u side, wave1=p side
  float inv = 1.f / fmaxf(sqrtf(n), 1e-12f);
  if (t < 64) c_u[d] = v * inv;
  else        c_p[d] = v * inv;
}

// ---------------- per-row sims (wave per row) ----------------
__global__ void k_sims(const float* __restrict__ An_u, const float* __restrict__ Pn_u,
                       const float* __restrict__ An_p, const float* __restrict__ Pn_p,
                       const float* __restrict__ c_u, const float* __restrict__ c_p,
                       const int* __restrict__ perm, const int* __restrict__ inv,
                       float* __restrict__ dis_u, float* __restrict__ col_u,
                       float* __restrict__ posd_u, float* __restrict__ cross_u,
                       float* __restrict__ dis_p, float* __restrict__ col_p,
                       float* __restrict__ posd_p, float* __restrict__ cross_p) {
  int gid = blockIdx.x * blockDim.x + threadIdx.x;
  int r = gid >> 6, d = gid & 63;
  int pr = perm[r], ir = inv[r];
  float au = An_u[r * DIM + d], pu = Pn_u[r * DIM + d];
  float ap = An_p[r * DIM + d], pp = Pn_p[r * DIM + d];
  float r0 = au * An_u[pr * DIM + d];
  float r1 = au * c_u[d];
  float r2 = au * pu;
  float r3 = au * Pn_u[ir * DIM + d];
  float r4 = ap * An_p[pr * DIM + d];
  float r5 = ap * c_p[d];
  float r6 = ap * pp;
  float r7 = ap * Pn_p[ir * DIM + d];
  for (int o = 32; o > 0; o >>= 1) {
    r0 += __shfl_xor(r0, o); r1 += __shfl_xor(r1, o); r2 += __shfl_xor(r2, o);
    r3 += __shfl_xor(r3, o); r4 += __shfl_xor(r4, o); r5 += __shfl_xor(r5, o);
    r6 += __shfl_xor(r6, o); r7 += __shfl_xor(r7, o);
  }
  if (d == 0) {
    dis_u[r] = r0 * INVT; col_u[r] = r1 * INVT; posd_u[r] = r2 * INVT; cross_u[r] = r3 * INVT;
    dis_p[r] = r4 * INVT; col_p[r] = r5 * INVT; posd_p[r] = r6 * INVT; cross_p[r] = r7 * INVT;
  }
}

// ---------------- MFMA fused matmul + fixed-shift sumexp over G = An @ Pn^T / T ----------
__global__ __launch_bounds__(256) void k_lse_mfma(const unsigned short* __restrict__ Anh,
                                                  const unsigned short* __restrict__ Pnh,
                                                  float* __restrict__ s_row) {
  const float C1 = INVT * 1.4426950408889634f;   // INVT*log2(e)
  int rb = blockIdx.x >> 3, cb = blockIdx.x & 7;
  int w = threadIdx.x >> 6, lane = threadIdx.x & 63;
  int r0 = rb * 64 + w * 16;
  int arow = r0 + (lane & 15);
  int koff = (lane >> 4) * 8;
  v8s a_lo = *(const v8s*)&Anh[arow * DIM + koff];
  v8s a_hi = *(const v8s*)&Anh[arow * DIM + koff + 32];
  float s0 = 0.f, s1 = 0.f, s2 = 0.f, s3 = 0.f;
  int cbase = cb * 512;
#pragma unroll 2
  for (int c0 = cbase; c0 < cbase + 512; c0 += 16) {
    int brow = c0 + (lane & 15);
    v8s b_lo = *(const v8s*)&Pnh[brow * DIM + koff];
    v8s b_hi = *(const v8s*)&Pnh[brow * DIM + koff + 32];
    f32x4 acc = {0.f, 0.f, 0.f, 0.f};
    acc = __builtin_amdgcn_mfma_f32_16x16x32_bf16(a_lo, b_lo, acc, 0, 0, 0);
    acc = __builtin_amdgcn_mfma_f32_16x16x32_bf16(a_hi, b_hi, acc, 0, 0, 0);
    s0 += exp2f(fmaf(acc[0], C1, -C1));
    s1 += exp2f(fmaf(acc[1], C1, -C1));
    s2 += exp2f(fmaf(acc[2], C1, -C1));
    s3 += exp2f(fmaf(acc[3], C1, -C1));
  }
  // sum the 16 col-slots of each row (C/D: col=lane&15, row=(lane>>4)*4+reg)
  for (int o = 1; o <= 8; o <<= 1) {
    s0 += __shfl_xor(s0, o); s1 += __shfl_xor(s1, o);
    s2 += __shfl_xor(s2, o); s3 += __shfl_xor(s3, o);
  }
  if ((lane & 15) == 0) {
    int rq = r0 + (lane >> 4) * 4;
    atomicAdd(&s_row[rq + 0], s0);
    atomicAdd(&s_row[rq + 1], s1);
    atomicAdd(&s_row[rq + 2], s2);
    atomicAdd(&s_row[rq + 3], s3);
  }
}

// ---------------- final combine (single block) — OUTPUT IS FLOAT32 ----------------
__global__ void k_final(const float* __restrict__ m_u, const float* __restrict__ s_u,
                        const float* __restrict__ dis_u, const float* __restrict__ col_u,
                        const float* __restrict__ posd_u, const float* __restrict__ cross_u,
                        const float* __restrict__ m_p, const float* __restrict__ s_p,
                        const float* __restrict__ dis_p, const float* __restrict__ col_p,
                        const float* __restrict__ posd_p, const float* __restrict__ cross_p,
                        const float* __restrict__ pos_sc, const float* __restrict__ neg_sc,
                        const float* __restrict__ nms, const int* __restrict__ inv,
                        const float* __restrict__ S, float* __restrict__ out) {
  __shared__ float red[6][256];
  int t = threadIdx.x;
  float lpu = 0.f, lnu = 0.f, lpp = 0.f, lnp = 0.f, bp = 0.f, bn = 0.f;
  for (int r = t; r < BATCH; r += 256) {
    int ir = inv[r];
    {
      float M = m_u[r], Sv = s_u[r];
      float d2 = col_u[r];
      float d1 = dis_u[r];
      float nm2 = fmaxf(M, fmaxf(d1, d2));
      float ss = Sv * __expf(M - nm2) + __expf(d1 - nm2) + __expf(d2 - nm2);
      lpu += nm2 + logf(ss) - posd_u[r];
      float d1n = dis_u[ir];
      nm2 = fmaxf(M, fmaxf(d1n, d2));
      ss = Sv * __expf(M - nm2) + __expf(d1n - nm2) + __expf(d2 - nm2);
      lnu += nm2 + logf(ss) - cross_u[r];
    }
    {
      float M = m_p[r], Sv = s_p[r];
      float d2 = col_p[r];
      float d1 = dis_p[r];
      float nm2 = fmaxf(M, fmaxf(d1, d2));
      float ss = Sv * __expf(M - nm2) + __expf(d1 - nm2) + __expf(d2 - nm2);
      lpp += nm2 + logf(ss) - posd_p[r];
      float d1n = dis_p[ir];
      nm2 = fmaxf(M, fmaxf(d1n, d2));
      ss = Sv * __expf(M - nm2) + __expf(d1n - nm2) + __expf(d2 - nm2);
      lnp += nm2 + logf(ss) - cross_p[r];
    }
    float ps = pos_sc[r];
    bp += softplusf(neg_sc[r] - ps);
    bn += softplusf(nms[r] - ps);
  }
  red[0][t] = lpu; red[1][t] = lnu; red[2][t] = lpp;
  red[3][t] = lnp; red[4][t] = bp;  red[5][t] = bn;
  __syncthreads();
  for (int off = 128; off > 0; off >>= 1) {
    if (t < off)
      for (int c = 0; c < 6; c++) red[c][t] += red[c][t + off];
    __syncthreads();
  }
  if (t == 0) {
    const float inv_b = 1.f / (float)BATCH;
    float mbu = S[1] * inv_b;            // mean(beta_u)
    float b   = S[2] * inv_b;            // mean(beta_i)
    float cl_u = mbu * (red[0][0] * inv_b) + (1.f - mbu) * (red[1][0] * inv_b);
    float cl_p = b   * (red[2][0] * inv_b) + (1.f - b)   * (red[3][0] * inv_b);
    float main_m = b * (red[4][0] * inv_b) + (1.f - b) * (red[5][0] * inv_b);
    float reg = REGC * S[0] * inv_b;
    float loss = main_m + LAMBDA * (cl_u + cl_p) + reg;
    out[0] = loss;                       // float32
  }
}

extern "C" void kernel_launch(void* const* d_in, const int* in_sizes, int n_in,
                              void* d_out, int out_size, void* d_ws, size_t ws_size,
                              hipStream_t stream) {
  const float* uemb   = (const float*)d_in[0];
  const float* iemb   = (const float*)d_in[1];
  const int*   rows   = (const int*)d_in[2];
  const int*   cols   = (const int*)d_in[3];
  const int*   user   = (const int*)d_in[5];
  const int*   pos    = (const int*)d_in[6];
  const int*   neg    = (const int*)d_in[7];
  const float* beta_u = (const float*)d_in[8];
  const float* beta_i = (const float*)d_in[9];
  const int*   perm   = (const int*)d_in[10];
  const float* cu     = (const float*)d_in[11];
  const float* cp     = (const float*)d_in[12];

  char* w = (char*)d_ws;
  size_t off = 0;
  auto alloc = [&](size_t bytes) -> char* {
    char* p = w + off;
    off += (bytes + 255) & ~(size_t)255;
    return p;
  };
  unsigned short* x0h = (unsigned short*)alloc((size_t)ND * 2);
  unsigned short* x1h = (unsigned short*)alloc((size_t)ND * 2);
  unsigned short* x2h = (unsigned short*)alloc((size_t)ND * 2);
  unsigned short* x3h = (unsigned short*)alloc((size_t)ND * 2);
  int*   ev      = (int*)  alloc((size_t)NNZ * 4);
  int*   row_ptr = (int*)  alloc((size_t)(NN + 1) * 4);
  float* dis     = (float*)alloc((size_t)NN * 4);
  int*   bhist   = (int*)  alloc((size_t)NB * 4);
  int*   bbase   = (int*)  alloc((size_t)(NB + 1) * 4);
  int*   bcur    = (int*)  alloc((size_t)NB * 4);
  float* partR   = (float*)alloc((size_t)NGB * 4);
  float* ue      = (float*)alloc((size_t)BATCH * DIM * 4);
  float* pe      = (float*)alloc((size_t)BATCH * DIM * 4);
  float* ne      = (float*)alloc((size_t)BATCH * DIM * 4);
  float* An_u    = (float*)alloc((size_t)BATCH * DIM * 4);
  float* Pn_u    = (float*)alloc((size_t)BATCH * DIM * 4);
  float* An_p    = (float*)alloc((size_t)BATCH * DIM * 4);
  float* Pn_p    = (float*)alloc((size_t)BATCH * DIM * 4);
  unsigned short* An_uh = (unsigned short*)alloc((size_t)BATCH * DIM * 2);
  unsigned short* Pn_uh = (unsigned short*)alloc((size_t)BATCH * DIM * 2);
  unsigned short* An_ph = (unsigned short*)alloc((size_t)BATCH * DIM * 2);
  unsigned short* Pn_ph = (unsigned short*)alloc((size_t)BATCH * DIM * 2);
  float* pos_sc  = (float*)alloc((size_t)BATCH * 4);
  float* neg_sc  = (float*)alloc((size_t)BATCH * 4);
  float* nms     = (float*)alloc((size_t)BATCH * 4);
  float* dis_u   = (float*)alloc((size_t)BATCH * 4);
  float* col_u   = (float*)alloc((size_t)BATCH * 4);
  float* posd_u  = (float*)alloc((size_t)BATCH * 4);
  float* cross_u = (float*)alloc((size_t)BATCH * 4);
  float* m_u     = (float*)alloc((size_t)BATCH * 4);
  float* s_u     = (float*)alloc((size_t)BATCH * 4);
  float* dis_p   = (float*)alloc((size_t)BATCH * 4);
  float* col_p   = (float*)alloc((size_t)BATCH * 4);
  float* posd_p  = (float*)alloc((size_t)BATCH * 4);
  float* cross_p = (float*)alloc((size_t)BATCH * 4);
  float* m_p     = (float*)alloc((size_t)BATCH * 4);
  float* s_p     = (float*)alloc((size_t)BATCH * 4);
  int*   invp    = (int*)  alloc((size_t)BATCH * 4);
  float* c_u     = (float*)alloc(256);
  float* c_p     = (float*)alloc(256);
  float* S       = (float*)alloc(1024);

  // tmp (int per edge, 12.8MB) aliases x0h (19.2MB) — dead until k_inith,
  // which runs AFTER the CSR build.
  int* tmp = (int*)x0h;

  // 1. zero bucket hist + preset LSE state (m=M0, s=0)
  k_zero<<<(NN + 255) / 256, 256, 0, stream>>>(bhist, S, m_u, s_u, m_p, s_p);
  // 2. CSR build: bucket hist -> scan -> 2-pass bucket sort (row_ptr built in pass B)
  k_bhist<<<BHB, 256, 0, stream>>>(rows, bhist);
  k_bscan<<<1, 512, 0, stream>>>(bhist, bbase, bcur, row_ptr);
  k_bucketA<<<(NNZ + ACHUNK - 1) / ACHUNK, 256, 0, stream>>>(rows, cols, bcur, tmp);
  k_bucketB<<<NB, 512, 0, stream>>>(bbase, tmp, ev, row_ptr);
  k_dis<<<(NN + 255) / 256, 256, 0, stream>>>(row_ptr, dis);
  // 3. init x0h = fp16(concat(user_emb, item_emb))
  k_inith<<<(ND / 4 + 255) / 256, 256, 0, stream>>>((const float4*)uemb, (const float4*)iemb,
                                                    (uint2*)x0h);
  // 4. three GCN layers (fp16 packed-FMA, 4B edges, dis-recomputed vals)
  k_spmv_h<<<SPMVB, 256, 0, stream>>>(row_ptr, ev, dis, x0h, x1h);
  k_spmv_h<<<SPMVB, 256, 0, stream>>>(row_ptr, ev, dis, x1h, x2h);
  k_spmv_h<<<SPMVB, 256, 0, stream>>>(row_ptr, ev, dis, x2h, x3h);
  // 5. batch gather (sum of layer outputs for just the batch rows) + small sums
  k_gather<<<NGB, 256, 0, stream>>>((const float4*)uemb, (const float4*)iemb,
                                    (const uint2*)x1h, (const uint2*)x2h,
                                    (const uint2*)x3h, user, pos, neg,
                                    (float4*)ue, (float4*)pe, (float4*)ne, partR);
  k_small<<<1, 256, 0, stream>>>(beta_u, beta_i, partR, S);
  k_invperm<<<(BATCH + 255) / 256, 256, 0, stream>>>(perm, invp);
  // 6. mixes, scores, normalization (+ bf16 copies for MFMA)
  k_mixnorm<<<(BATCH * DIM) / 256, 256, 0, stream>>>(ue, pe, ne, beta_u, beta_i, perm,
                                                     An_u, Pn_u, An_p, Pn_p,
                                                     An_uh, Pn_uh, An_ph, Pn_ph,
                                                     pos_sc, neg_sc, nms);
  k_colpart<<<BATCH / 64, 256, 0, stream>>>(ue, pe, cu, cp, S);
  k_colnorm<<<1, 128, 0, stream>>>(S, c_u, c_p);
  k_sims<<<(BATCH * DIM) / 256, 256, 0, stream>>>(An_u, Pn_u, An_p, Pn_p, c_u, c_p,
                                                  perm, invp,
                                                  dis_u, col_u, posd_u, cross_u,
                                                  dis_p, col_p, posd_p, cross_p);
  // 7. MFMA matmul + fixed-shift sumexp (user side, pos side)
  k_lse_mfma<<<512, 256, 0, stream>>>(An_uh, Pn_uh, s_u);
  k_lse_mfma<<<512, 256, 0, stream>>>(An_ph, Pn_ph, s_p);
  // 8. final combine
  k_final<<<1, 256, 0, stream>>>(m_u, s_u, dis_u, col_u, posd_u, cross_u,
                                 m_p, s_p, dis_p, col_p, posd_p, cross_p,
                                 pos_sc, neg_sc, nms, invp, S,
                                 (float*)d_out);
}

// Round 11
// 336.267 us; speedup vs baseline: 4.7843x; 1.0747x over previous
//
#include <hip/hip_runtime.h>
#include <hip/hip_bf16.h>
#include <hip/hip_fp16.h>

#define NUSERS 100000
#define NITEMS 50000
#define NN     150001          // total nodes
#define NNZ    3200000         // 2 * NNZ_INTER
#define BATCH  4096
#define DIM    64
#define ND     (NN * DIM)
#define ALPHA  0.25f           // 1/(N_LAYERS+1)
#define INVT   5.0f            // 1/TEMP
#define LAMBDA 0.1f
#define REGC   1.0e-4f
#define BKSH   9               // 512 nodes per bucket
#define NB     293             // ceil(150001/512)
#define ACHUNK 4096            // edges per bucketA block
#define M0     5.0f            // fixed LSE shift: logits = sim/T ∈ [-5,5]
#define NGB    256             // k_gather blocks (BATCH*16/256)
#define BHB    256             // k_bhist blocks
#define CMASK  0x3FFFF         // 18-bit col mask
#define SPMVB  2048            // k_spmv grid (8 blocks/CU -> 32 waves/CU)

typedef __attribute__((ext_vector_type(8))) short v8s;    // 8 bf16 (4 VGPRs)
typedef __attribute__((ext_vector_type(4))) float f32x4;  // MFMA acc

union H2U { unsigned u; __half2 h; };
__device__ __forceinline__ __half2 u2h(unsigned x) { H2U t; t.u = x; return t.h; }
__device__ __forceinline__ unsigned h2u(__half2 h) { H2U t; t.h = h; return t.u; }
__device__ __forceinline__ __half2 h2shfl(__half2 v, int m) {
  return u2h((unsigned)__shfl_xor((int)h2u(v), m));
}

__device__ __forceinline__ float wred64(float v) {
  for (int o = 32; o > 0; o >>= 1) v += __shfl_xor(v, o);
  return v;
}

__device__ __forceinline__ float softplusf(float x) {
  return (x > 20.f) ? x : log1pf(__expf(x));
}

__device__ __forceinline__ unsigned short bf16r(float v) {
  unsigned x = __float_as_uint(v);
  return (unsigned short)((x + 0x7fff + ((x >> 16) & 1)) >> 16);   // RNE
}

// fp16 quad (uint2 = 4 halves) -> float4
__device__ __forceinline__ float4 h4f(uint2 u) {
  float2 lo = __half22float2(u2h(u.x));
  float2 hi = __half22float2(u2h(u.y));
  return make_float4(lo.x, lo.y, hi.x, hi.y);
}

// ---------------- zero scratch + preset LSE state + invperm ----------------
__global__ void k_zero(int* __restrict__ bhist, float* __restrict__ S,
                       float* __restrict__ m_u, float* __restrict__ s_u,
                       float* __restrict__ m_p, float* __restrict__ s_p,
                       const int* __restrict__ perm, int* __restrict__ inv) {
  int i = blockIdx.x * blockDim.x + threadIdx.x;
  if (i < NB) bhist[i] = 0;
  if (i < 256) S[i] = 0.f;
  if (i < BATCH) {
    s_u[i] = 0.f; s_p[i] = 0.f; m_u[i] = M0; m_p[i] = M0;
    inv[perm[i]] = i;
  }
}

// ---------------- w0 = rsqrt(deg) * concat(user_emb, item_emb), fp16 ----------------
__global__ void k_inith(const float4* __restrict__ uemb, const float4* __restrict__ iemb,
                        const float* __restrict__ rsq, uint2* __restrict__ x0h) {
  int q = blockIdx.x * blockDim.x + threadIdx.x;   // quads: ND/4
  if (q >= ND / 4) return;
  int n = q >> 4;                                   // 16 quads per node
  float4 v = (n < NUSERS) ? uemb[q] : iemb[q - NUSERS * 16];
  float r = rsq[n];
  x0h[q] = make_uint2(h2u(__floats2half2_rn(v.x * r, v.y * r)),
                      h2u(__floats2half2_rn(v.z * r, v.w * r)));
}

// ---------------- bucket histogram: LDS-private, 293 global atomics per block -----------
__global__ __launch_bounds__(256) void k_bhist(const int* __restrict__ rows,
                                               int* __restrict__ bhist) {
  __shared__ int lh[NB];
  int t = threadIdx.x;
  for (int i = t; i < NB; i += 256) lh[i] = 0;
  __syncthreads();
  const int per = (NNZ + BHB - 1) / BHB;
  int base = blockIdx.x * per;
  int end = min(base + per, NNZ);
  for (int e = base + t; e < end; e += 256)
    atomicAdd(&lh[rows[e] >> BKSH], 1);
  __syncthreads();
  for (int i = t; i < NB; i += 256) {
    int c = lh[i];
    if (c) atomicAdd(&bhist[i], c);
  }
}

// ---------------- bucket scan (one block, 512 threads) ----------------
__global__ __launch_bounds__(512) void k_bscan(const int* __restrict__ bhist,
                                               int* __restrict__ bbase, int* __restrict__ bcur,
                                               int* __restrict__ row_ptr) {
  __shared__ int sc[512];
  int t = threadIdx.x;
  int v = (t < NB) ? bhist[t] : 0;
  sc[t] = v;
  __syncthreads();
  for (int off = 1; off < 512; off <<= 1) {
    int u = (t >= off) ? sc[t - off] : 0;
    __syncthreads();
    sc[t] += u;
    __syncthreads();
  }
  int ex = sc[t] - v;                  // exclusive prefix
  if (t < NB) { bbase[t] = ex; bcur[t] = ex; }
  if (t == NB - 1) { bbase[NB] = ex + v; row_ptr[NN] = ex + v; }  // == NNZ
}

// ---------------- bucket pass A: LDS counting-sort, packed 4-byte output ----------------
// packed word: col | (row&511)<<18   (col < 2^18, row-local < 2^9)
__global__ __launch_bounds__(256) void k_bucketA(const int* __restrict__ rows,
                                                 const int* __restrict__ cols,
                                                 int* __restrict__ bcur,
                                                 int* __restrict__ tmp) {
  __shared__ int lhist[NB];
  __shared__ int lscan[NB];
  __shared__ int ldelta[NB];
  __shared__ int lcnt[NB];
  __shared__ int2 ent[ACHUNK];        // x=packed col/rowlocal, y=ldelta
  int t = threadIdx.x;
  int base = blockIdx.x * ACHUNK;
  for (int b = t; b < NB; b += 256) { lhist[b] = 0; lcnt[b] = 0; }
  __syncthreads();
  int pkv[16], bkt[16];
  int nval = 0;
#pragma unroll
  for (int k = 0; k < 16; k++) {
    int e = base + t + k * 256;                 // coalesced
    if (e < NNZ) {
      int r = rows[e];
      pkv[k] = cols[e] | ((r & 511) << 18);
      bkt[k] = r >> BKSH;
      atomicAdd(&lhist[bkt[k]], 1);
      nval = k + 1;
    }
  }
  __syncthreads();
  if (t == 0) {
    int run = 0;
    for (int b = 0; b < NB; b++) { lscan[b] = run; run += lhist[b]; }
  }
  __syncthreads();
  for (int b = t; b < NB; b += 256) {
    int c = lhist[b];
    int g = (c > 0) ? atomicAdd(&bcur[b], c) : 0;
    ldelta[b] = g - lscan[b];
  }
  __syncthreads();
#pragma unroll
  for (int k = 0; k < 16; k++) {
    if (k < nval) {
      int b = bkt[k];
      int lp = atomicAdd(&lcnt[b], 1);
      ent[lscan[b] + lp] = make_int2(pkv[k], ldelta[b]);
    }
  }
  __syncthreads();
  int tot = min(ACHUNK, NNZ - base);
  for (int j = t; j < tot; j += 256) {
    int2 E = ent[j];
    tmp[E.y + j] = E.x;                        // contiguous run per bucket -> full lines
  }
}

// ---------------- bucket pass B: row_ptr + deg tables + final scatter ----------------
__global__ __launch_bounds__(512) void k_bucketB(const int* __restrict__ bbase,
                                                 const int* __restrict__ tmp,
                                                 int* __restrict__ ev,
                                                 int* __restrict__ row_ptr,
                                                 float* __restrict__ rsq,
                                                 float* __restrict__ sqd) {
  __shared__ int h[512], sc[512], c2[512], rstart[512];
  int b = blockIdx.x, t = threadIdx.x;
  int nbase = b << BKSH;
  h[t] = 0; c2[t] = 0;
  __syncthreads();
  int beg = bbase[b], end = bbase[b + 1];
  for (int j = beg + t; j < end; j += 512)
    atomicAdd(&h[tmp[j] >> 18], 1);
  __syncthreads();
  int v = h[t];
  sc[t] = v;
  __syncthreads();
  for (int off = 1; off < 512; off <<= 1) {
    int u = (t >= off) ? sc[t - off] : 0;
    __syncthreads();
    sc[t] += u;
    __syncthreads();
  }
  int rp = beg + sc[t] - v;            // exclusive scan -> row start
  rstart[t] = rp;
  int node = nbase + t;
  if (node < NN) {
    row_ptr[node] = rp;
    float fd = (float)v;
    rsq[node] = (v > 0) ? rsqrtf(fd) : 0.f;
    sqd[node] = sqrtf(fd);
  }
  __syncthreads();
  for (int j = beg + t; j < end; j += 512) {
    int w = tmp[j];
    int ln = w >> 18;
    int lp = atomicAdd(&c2[ln], 1);
    ev[rstart[ln] + lp] = w & CMASK;
  }
}

// ---------------- gather SpMV in w-space: w_out = (1/deg) * sum_neighbors(w_in) ---------
// NO per-edge weights. wave/node, 4 grp x 16 lanes x 4 dims; grid-stride; predicated tail.
__global__ __launch_bounds__(256) void k_spmv(const int* __restrict__ row_ptr,
                                              const int* __restrict__ ev,
                                              const unsigned short* __restrict__ cur,
                                              unsigned short* __restrict__ nxt) {
  int lane = threadIdx.x & 63;
  int g = lane >> 4;                 // edge group 0..3 (edges ≡ g mod 4)
  int d4 = (lane & 15) << 2;         // 4 dims per lane
  for (int node0 = blockIdx.x * 4 + (threadIdx.x >> 6); node0 < NN;
       node0 += SPMVB * 4) {
    int node = __builtin_amdgcn_readfirstlane(node0);
    int beg = row_ptr[node], end = row_ptr[node + 1];
    __half2 a0 = __float2half2_rn(0.f);
    __half2 a1 = a0;
    int e = beg + g;
    for (; e + 12 < end; e += 16) {  // 4 edges in flight per lane
      int c0 = ev[e], c1 = ev[e + 4], c2 = ev[e + 8], c3 = ev[e + 12];
      uint2 H0 = *(const uint2*)&cur[c0 * DIM + d4];
      uint2 H1 = *(const uint2*)&cur[c1 * DIM + d4];
      uint2 H2 = *(const uint2*)&cur[c2 * DIM + d4];
      uint2 H3 = *(const uint2*)&cur[c3 * DIM + d4];
      a0 = __hadd2(a0, u2h(H0.x)); a1 = __hadd2(a1, u2h(H0.y));
      a0 = __hadd2(a0, u2h(H1.x)); a1 = __hadd2(a1, u2h(H1.y));
      a0 = __hadd2(a0, u2h(H2.x)); a1 = __hadd2(a1, u2h(H2.y));
      a0 = __hadd2(a0, u2h(H3.x)); a1 = __hadd2(a1, u2h(H3.y));
    }
    // predicated batch tail (<=3 edges per group) — all loads issue concurrently
    {
      bool p0 = e < end, p1 = e + 4 < end, p2 = e + 8 < end;
      int c0 = 0, c1 = 0, c2 = 0;
      if (p0) c0 = ev[e];
      if (p1) c1 = ev[e + 4];
      if (p2) c2 = ev[e + 8];
      uint2 H0 = make_uint2(0u, 0u), H1 = H0, H2 = H0;
      if (p0) H0 = *(const uint2*)&cur[c0 * DIM + d4];
      if (p1) H1 = *(const uint2*)&cur[c1 * DIM + d4];
      if (p2) H2 = *(const uint2*)&cur[c2 * DIM + d4];
      a0 = __hadd2(a0, u2h(H0.x)); a1 = __hadd2(a1, u2h(H0.y));
      a0 = __hadd2(a0, u2h(H1.x)); a1 = __hadd2(a1, u2h(H1.y));
      a0 = __hadd2(a0, u2h(H2.x)); a1 = __hadd2(a1, u2h(H2.y));
    }
    // reduce across the 4 edge groups (packed fp16 adds)
    a0 = __hadd2(a0, h2shfl(a0, 16)); a1 = __hadd2(a1, h2shfl(a1, 16));
    a0 = __hadd2(a0, h2shfl(a0, 32)); a1 = __hadd2(a1, h2shfl(a1, 32));
    if (g == 0) {
      float invd = (end > beg) ? 1.f / (float)(end - beg) : 0.f;
      __half2 iv = __float2half2_rn(invd);
      *(uint2*)&nxt[node * DIM + d4] =
          make_uint2(h2u(__hmul2(a0, iv)), h2u(__hmul2(a1, iv)));
    }
  }
}

// ---------------- batch gather: ue/pe/ne = ALPHA*(x0 + sqrt(deg)*(w1+w2+w3)) ------------
__global__ __launch_bounds__(256) void k_gather(const float4* __restrict__ uemb4,
                                                const float4* __restrict__ iemb4,
                                                const uint2* __restrict__ x1h,
                                                const uint2* __restrict__ x2h,
                                                const uint2* __restrict__ x3h,
                                                const float* __restrict__ sqd,
                                                const int* __restrict__ user,
                                                const int* __restrict__ pos,
                                                const int* __restrict__ neg,
                                                float4* __restrict__ ue4,
                                                float4* __restrict__ pe4,
                                                float4* __restrict__ ne4,
                                                float* __restrict__ partR) {
  __shared__ float sred[256];
  int t = threadIdx.x;
  int gid = blockIdx.x * 256 + t;    // BATCH*16 exact
  int i = gid >> 4, q = gid & 15;
  int u = user[i], p = pos[i], n = neg[i];
  int nu = u, np = NUSERS + p, nn = NUSERS + n;
  int qu = nu * 16 + q, qp = np * 16 + q, qn = nn * 16 + q;
  float4 eu = uemb4[qu];                       // x0 user (also reg term)
  float4 ep = iemb4[p * 16 + q];               // x0 pos  (also reg term)
  float4 en = iemb4[n * 16 + q];               // x0 neg  (also reg term)
  float su_ = sqd[nu], sp_ = sqd[np], sn_ = sqd[nn];
  float4 a1 = h4f(x1h[qu]), a2 = h4f(x2h[qu]), a3 = h4f(x3h[qu]);
  float4 b1 = h4f(x1h[qp]), b2 = h4f(x2h[qp]), b3 = h4f(x3h[qp]);
  float4 c1 = h4f(x1h[qn]), c2 = h4f(x2h[qn]), c3 = h4f(x3h[qn]);
  float4 su = make_float4(ALPHA * (eu.x + su_ * (a1.x + a2.x + a3.x)),
                          ALPHA * (eu.y + su_ * (a1.y + a2.y + a3.y)),
                          ALPHA * (eu.z + su_ * (a1.z + a2.z + a3.z)),
                          ALPHA * (eu.w + su_ * (a1.w + a2.w + a3.w)));
  float4 sp = make_float4(ALPHA * (ep.x + sp_ * (b1.x + b2.x + b3.x)),
                          ALPHA * (ep.y + sp_ * (b1.y + b2.y + b3.y)),
                          ALPHA * (ep.z + sp_ * (b1.z + b2.z + b3.z)),
                          ALPHA * (ep.w + sp_ * (b1.w + b2.w + b3.w)));
  float4 sn = make_float4(ALPHA * (en.x + sn_ * (c1.x + c2.x + c3.x)),
                          ALPHA * (en.y + sn_ * (c1.y + c2.y + c3.y)),
                          ALPHA * (en.z + sn_ * (c1.z + c2.z + c3.z)),
                          ALPHA * (en.w + sn_ * (c1.w + c2.w + c3.w)));
  ue4[gid] = su;  pe4[gid] = sp;  ne4[gid] = sn;
  sred[t] = eu.x * eu.x + eu.y * eu.y + eu.z * eu.z + eu.w * eu.w
          + ep.x * ep.x + ep.y * ep.y + ep.z * ep.z + ep.w * ep.w
          + en.x * en.x + en.y * en.y + en.z * en.z + en.w * en.w;
  __syncthreads();
  for (int off = 128; off > 0; off >>= 1) {
    if (t < off) sred[t] += sred[t + off];
    __syncthreads();
  }
  if (t == 0) partR[blockIdx.x] = sred[0];
}

// ---------------- mixes, scores, row normalization (wave per row); also emit bf16 ----------
__global__ void k_mixnorm(const float* __restrict__ ue, const float* __restrict__ pe,
                          const float* __restrict__ ne, const float* __restrict__ beta_u,
                          const float* __restrict__ beta_i, const int* __restrict__ perm,
                          float* __restrict__ An_u, float* __restrict__ Pn_u,
                          float* __restrict__ An_p, float* __restrict__ Pn_p,
                          unsigned short* __restrict__ An_uh, unsigned short* __restrict__ Pn_uh,
                          unsigned short* __restrict__ An_ph, unsigned short* __restrict__ Pn_ph,
                          float* __restrict__ pos_sc, float* __restrict__ neg_sc,
                          float* __restrict__ nms) {
  int gid = blockIdx.x * blockDim.x + threadIdx.x;   // BATCH*64 exact
  int i = gid >> 6, d = gid & 63;
  int pi = perm[i];
  float uei = ue[i * DIM + d], pei = pe[i * DIM + d], nei = ne[i * DIM + d];
  float ud = ue[pi * DIM + d], pd = pe[pi * DIM + d], nd = ne[pi * DIM + d];
  float bu = beta_u[i], bi = beta_i[i];
  float um = bu * uei + (1.f - bu) * ud;
  float pm = bi * pei + (1.f - bi) * pd;
  float nm = bi * nei + (1.f - bi) * nd;
  float r0 = uei * pei, r1 = uei * nei, r2 = uei * nm;
  float r3 = uei * uei, r4 = um * um, r5 = pei * pei, r6 = pm * pm;
  for (int o = 32; o > 0; o >>= 1) {
    r0 += __shfl_xor(r0, o); r1 += __shfl_xor(r1, o); r2 += __shfl_xor(r2, o);
    r3 += __shfl_xor(r3, o); r4 += __shfl_xor(r4, o); r5 += __shfl_xor(r5, o);
    r6 += __shfl_xor(r6, o);
  }
  if (d == 0) { pos_sc[i] = r0; neg_sc[i] = r1; nms[i] = r2; }
  float inu  = 1.f / fmaxf(sqrtf(r3), 1e-12f);
  float inum = 1.f / fmaxf(sqrtf(r4), 1e-12f);
  float inp  = 1.f / fmaxf(sqrtf(r5), 1e-12f);
  float inpm = 1.f / fmaxf(sqrtf(r6), 1e-12f);
  float a0 = uei * inu, p0 = um * inum, a1 = pei * inp, p1 = pm * inpm;
  An_u[gid] = a0;  Pn_u[gid] = p0;  An_p[gid] = a1;  Pn_p[gid] = p1;
  An_uh[gid] = bf16r(a0); Pn_uh[gid] = bf16r(p0);
  An_ph[gid] = bf16r(a1); Pn_ph[gid] = bf16r(p1);
}

// ---------------- collective-mix: parallel partial sums (64 blocks) ----------------
__global__ void k_colpart(const float* __restrict__ ue, const float* __restrict__ pe,
                          const float* __restrict__ cu, const float* __restrict__ cp,
                          float* __restrict__ S) {
  __shared__ float smu[4][64], smp[4][64];
  int t = threadIdx.x, d = t & 63, q = t >> 6;
  int r0 = blockIdx.x * 64 + q * 16;
  float su = 0.f, sp = 0.f;
#pragma unroll 4
  for (int i = r0; i < r0 + 16; ++i) {
    su = fmaf(cu[i], ue[i * DIM + d], su);
    sp = fmaf(cp[i], pe[i * DIM + d], sp);
  }
  smu[q][d] = su; smp[q][d] = sp;
  __syncthreads();
  if (t < 64) {
    atomicAdd(&S[64 + d],  smu[0][d] + smu[1][d] + smu[2][d] + smu[3][d]);
    atomicAdd(&S[128 + d], smp[0][d] + smp[1][d] + smp[2][d] + smp[3][d]);
  }
}

// ---------------- colnorm + small sums (one block, 256 threads) ----------------
__global__ void k_colnorm(const float* __restrict__ beta_u, const float* __restrict__ beta_i,
                          const float* __restrict__ partR, float* __restrict__ S,
                          float* __restrict__ c_u, float* __restrict__ c_p) {
  __shared__ float a[256], b[256], c[256];
  int t = threadIdx.x;
  float su = 0.f, si = 0.f, sr = 0.f;
  for (int j = t; j < BATCH; j += 256) { su += beta_u[j]; si += beta_i[j]; }
  for (int j = t; j < NGB; j += 256) sr += partR[j];
  a[t] = su; b[t] = si; c[t] = sr;
  __syncthreads();
  for (int off = 128; off > 0; off >>= 1) {
    if (t < off) { a[t] += a[t + off]; b[t] += b[t + off]; c[t] += c[t + off]; }
    __syncthreads();
  }
  if (t == 0) { S[0] = c[0]; S[1] = a[0]; S[2] = b[0]; }
  // colnorm: waves 0,1 (uniform branch per wave)
  if (t < 128) {
    int d = t & 63;
    float v = (t < 64) ? S[64 + d] : S[128 + d];
    float n = wred64(v * v);
    float inv = 1.f / fmaxf(sqrtf(n), 1e-12f);
    if (t < 64) c_u[d] = v * inv;
    else        c_p[d] = v * inv;
  }
}

// ---------------- per-row sims (wave per row) ----------------
__global__ void k_sims(const float* __restrict__ An_u, const float* __restrict__ Pn_u,
                       const float* __restrict__ An_p, const float* __restrict__ Pn_p,
                       const float* __restrict__ c_u, const float* __restrict__ c_p,
                       const int* __restrict__ perm, const int* __restrict__ inv,
                       float* __restrict__ dis_u, float* __restrict__ col_u,
                       float* __restrict__ posd_u, float* __restrict__ cross_u,
                       float* __restrict__ dis_p, float* __restrict__ col_p,
                       float* __restrict__ posd_p, float* __restrict__ cross_p) {
  int gid = blockIdx.x * blockDim.x + threadIdx.x;
  int r = gid >> 6, d = gid & 63;
  int pr = perm[r], ir = inv[r];
  float au = An_u[r * DIM + d], pu = Pn_u[r * DIM + d];
  float ap = An_p[r * DIM + d], pp = Pn_p[r * DIM + d];
  float r0 = au * An_u[pr * DIM + d];
  float r1 = au * c_u[d];
  float r2 = au * pu;
  float r3 = au * Pn_u[ir * DIM + d];
  float r4 = ap * An_p[pr * DIM + d];
  float r5 = ap * c_p[d];
  float r6 = ap * pp;
  float r7 = ap * Pn_p[ir * DIM + d];
  for (int o = 32; o > 0; o >>= 1) {
    r0 += __shfl_xor(r0, o); r1 += __shfl_xor(r1, o); r2 += __shfl_xor(r2, o);
    r3 += __shfl_xor(r3, o); r4 += __shfl_xor(r4, o); r5 += __shfl_xor(r5, o);
    r6 += __shfl_xor(r6, o); r7 += __shfl_xor(r7, o);
  }
  if (d == 0) {
    dis_u[r] = r0 * INVT; col_u[r] = r1 * INVT; posd_u[r] = r2 * INVT; cross_u[r] = r3 * INVT;
    dis_p[r] = r4 * INVT; col_p[r] = r5 * INVT; posd_p[r] = r6 * INVT; cross_p[r] = r7 * INVT;
  }
}

// ---------------- MFMA fused matmul + fixed-shift sumexp over G = An @ Pn^T / T ----------
__global__ __launch_bounds__(256) void k_lse_mfma(const unsigned short* __restrict__ Anh,
                                                  const unsigned short* __restrict__ Pnh,
                                                  float* __restrict__ s_row) {
  const float C1 = INVT * 1.4426950408889634f;   // INVT*log2(e)
  int rb = blockIdx.x >> 3, cb = blockIdx.x & 7;
  int w = threadIdx.x >> 6, lane = threadIdx.x & 63;
  int r0 = rb * 64 + w * 16;
  int arow = r0 + (lane & 15);
  int koff = (lane >> 4) * 8;
  v8s a_lo = *(const v8s*)&Anh[arow * DIM + koff];
  v8s a_hi = *(const v8s*)&Anh[arow * DIM + koff + 32];
  float s0 = 0.f, s1 = 0.f, s2 = 0.f, s3 = 0.f;
  int cbase = cb * 512;
#pragma unroll 2
  for (int c0 = cbase; c0 < cbase + 512; c0 += 16) {
    int brow = c0 + (lane & 15);
    v8s b_lo = *(const v8s*)&Pnh[brow * DIM + koff];
    v8s b_hi = *(const v8s*)&Pnh[brow * DIM + koff + 32];
    f32x4 acc = {0.f, 0.f, 0.f, 0.f};
    acc = __builtin_amdgcn_mfma_f32_16x16x32_bf16(a_lo, b_lo, acc, 0, 0, 0);
    acc = __builtin_amdgcn_mfma_f32_16x16x32_bf16(a_hi, b_hi, acc, 0, 0, 0);
    s0 += exp2f(fmaf(acc[0], C1, -C1));
    s1 += exp2f(fmaf(acc[1], C1, -C1));
    s2 += exp2f(fmaf(acc[2], C1, -C1));
    s3 += exp2f(fmaf(acc[3], C1, -C1));
  }
  // sum the 16 col-slots of each row (C/D: col=lane&15, row=(lane>>4)*4+reg)
  for (int o = 1; o <= 8; o <<= 1) {
    s0 += __shfl_xor(s0, o); s1 += __shfl_xor(s1, o);
    s2 += __shfl_xor(s2, o); s3 += __shfl_xor(s3, o);
  }
  if ((lane & 15) == 0) {
    int rq = r0 + (lane >> 4) * 4;
    atomicAdd(&s_row[rq + 0], s0);
    atomicAdd(&s_row[rq + 1], s1);
    atomicAdd(&s_row[rq + 2], s2);
    atomicAdd(&s_row[rq + 3], s3);
  }
}

// ---------------- final combine (single block) — OUTPUT IS FLOAT32 ----------------
__global__ void k_final(const float* __restrict__ m_u, const float* __restrict__ s_u,
                        const float* __restrict__ dis_u, const float* __restrict__ col_u,
                        const float* __restrict__ posd_u, const float* __restrict__ cross_u,
                        const float* __restrict__ m_p, const float* __restrict__ s_p,
                        const float* __restrict__ dis_p, const float* __restrict__ col_p,
                        const float* __restrict__ posd_p, const float* __restrict__ cross_p,
                        const float* __restrict__ pos_sc, const float* __restrict__ neg_sc,
                        const float* __restrict__ nms, const int* __restrict__ inv,
                        const float* __restrict__ S, float* __restrict__ out) {
  __shared__ float red[6][256];
  int t = threadIdx.x;
  float lpu = 0.f, lnu = 0.f, lpp = 0.f, lnp = 0.f, bp = 0.f, bn = 0.f;
  for (int r = t; r < BATCH; r += 256) {
    int ir = inv[r];
    {
      float M = m_u[r], Sv = s_u[r];
      float d2 = col_u[r];
      float d1 = dis_u[r];
      float nm2 = fmaxf(M, fmaxf(d1, d2));
      float ss = Sv * __expf(M - nm2) + __expf(d1 - nm2) + __expf(d2 - nm2);
      lpu += nm2 + logf(ss) - posd_u[r];
      float d1n = dis_u[ir];
      nm2 = fmaxf(M, fmaxf(d1n, d2));
      ss = Sv * __expf(M - nm2) + __expf(d1n - nm2) + __expf(d2 - nm2);
      lnu += nm2 + logf(ss) - cross_u[r];
    }
    {
      float M = m_p[r], Sv = s_p[r];
      float d2 = col_p[r];
      float d1 = dis_p[r];
      float nm2 = fmaxf(M, fmaxf(d1, d2));
      float ss = Sv * __expf(M - nm2) + __expf(d1 - nm2) + __expf(d2 - nm2);
      lpp += nm2 + logf(ss) - posd_p[r];
      float d1n = dis_p[ir];
      nm2 = fmaxf(M, fmaxf(d1n, d2));
      ss = Sv * __expf(M - nm2) + __expf(d1n - nm2) + __expf(d2 - nm2);
      lnp += nm2 + logf(ss) - cross_p[r];
    }
    float ps = pos_sc[r];
    bp += softplusf(neg_sc[r] - ps);
    bn += softplusf(nms[r] - ps);
  }
  red[0][t] = lpu; red[1][t] = lnu; red[2][t] = lpp;
  red[3][t] = lnp; red[4][t] = bp;  red[5][t] = bn;
  __syncthreads();
  for (int off = 128; off > 0; off >>= 1) {
    if (t < off)
      for (int c = 0; c < 6; c++) red[c][t] += red[c][t + off];
    __syncthreads();
  }
  if (t == 0) {
    const float inv_b = 1.f / (float)BATCH;
    float mbu = S[1] * inv_b;            // mean(beta_u)
    float b   = S[2] * inv_b;            // mean(beta_i)
    float cl_u = mbu * (red[0][0] * inv_b) + (1.f - mbu) * (red[1][0] * inv_b);
    float cl_p = b   * (red[2][0] * inv_b) + (1.f - b)   * (red[3][0] * inv_b);
    float main_m = b * (red[4][0] * inv_b) + (1.f - b) * (red[5][0] * inv_b);
    float reg = REGC * S[0] * inv_b;
    float loss = main_m + LAMBDA * (cl_u + cl_p) + reg;
    out[0] = loss;                       // float32
  }
}

extern "C" void kernel_launch(void* const* d_in, const int* in_sizes, int n_in,
                              void* d_out, int out_size, void* d_ws, size_t ws_size,
                              hipStream_t stream) {
  const float* uemb   = (const float*)d_in[0];
  const float* iemb   = (const float*)d_in[1];
  const int*   rows   = (const int*)d_in[2];
  const int*   cols   = (const int*)d_in[3];
  const int*   user   = (const int*)d_in[5];
  const int*   pos    = (const int*)d_in[6];
  const int*   neg    = (const int*)d_in[7];
  const float* beta_u = (const float*)d_in[8];
  const float* beta_i = (const float*)d_in[9];
  const int*   perm   = (const int*)d_in[10];
  const float* cu     = (const float*)d_in[11];
  const float* cp     = (const float*)d_in[12];

  char* w = (char*)d_ws;
  size_t off = 0;
  auto alloc = [&](size_t bytes) -> char* {
    char* p = w + off;
    off += (bytes + 255) & ~(size_t)255;
    return p;
  };
  unsigned short* x0h = (unsigned short*)alloc((size_t)ND * 2);
  unsigned short* x1h = (unsigned short*)alloc((size_t)ND * 2);
  unsigned short* x2h = (unsigned short*)alloc((size_t)ND * 2);
  unsigned short* x3h = (unsigned short*)alloc((size_t)ND * 2);
  int*   ev      = (int*)  alloc((size_t)NNZ * 4);
  int*   row_ptr = (int*)  alloc((size_t)(NN + 1) * 4);
  float* rsq     = (float*)alloc((size_t)NN * 4);
  float* sqd     = (float*)alloc((size_t)NN * 4);
  int*   bhist   = (int*)  alloc((size_t)NB * 4);
  int*   bbase   = (int*)  alloc((size_t)(NB + 1) * 4);
  int*   bcur    = (int*)  alloc((size_t)NB * 4);
  float* partR   = (float*)alloc((size_t)NGB * 4);
  float* ue      = (float*)alloc((size_t)BATCH * DIM * 4);
  float* pe      = (float*)alloc((size_t)BATCH * DIM * 4);
  float* ne      = (float*)alloc((size_t)BATCH * DIM * 4);
  float* An_u    = (float*)alloc((size_t)BATCH * DIM * 4);
  float* Pn_u    = (float*)alloc((size_t)BATCH * DIM * 4);
  float* An_p    = (float*)alloc((size_t)BATCH * DIM * 4);
  float* Pn_p    = (float*)alloc((size_t)BATCH * DIM * 4);
  unsigned short* An_uh = (unsigned short*)alloc((size_t)BATCH * DIM * 2);
  unsigned short* Pn_uh = (unsigned short*)alloc((size_t)BATCH * DIM * 2);
  unsigned short* An_ph = (unsigned short*)alloc((size_t)BATCH * DIM * 2);
  unsigned short* Pn_ph = (unsigned short*)alloc((size_t)BATCH * DIM * 2);
  float* pos_sc  = (float*)alloc((size_t)BATCH * 4);
  float* neg_sc  = (float*)alloc((size_t)BATCH * 4);
  float* nms     = (float*)alloc((size_t)BATCH * 4);
  float* dis_u   = (float*)alloc((size_t)BATCH * 4);
  float* col_u   = (float*)alloc((size_t)BATCH * 4);
  float* posd_u  = (float*)alloc((size_t)BATCH * 4);
  float* cross_u = (float*)alloc((size_t)BATCH * 4);
  float* m_u     = (float*)alloc((size_t)BATCH * 4);
  float* s_u     = (float*)alloc((size_t)BATCH * 4);
  float* dis_p   = (float*)alloc((size_t)BATCH * 4);
  float* col_p   = (float*)alloc((size_t)BATCH * 4);
  float* posd_p  = (float*)alloc((size_t)BATCH * 4);
  float* cross_p = (float*)alloc((size_t)BATCH * 4);
  float* m_p     = (float*)alloc((size_t)BATCH * 4);
  float* s_p     = (float*)alloc((size_t)BATCH * 4);
  int*   invp    = (int*)  alloc((size_t)BATCH * 4);
  float* c_u     = (float*)alloc(256);
  float* c_p     = (float*)alloc(256);
  float* S       = (float*)alloc(1024);

  // tmp (int per edge, 12.8MB) aliases x0h (19.2MB) — dead until k_inith,
  // which runs AFTER the CSR build.
  int* tmp = (int*)x0h;

  // 1. zero bucket hist + preset LSE state + invperm
  k_zero<<<(NN + 255) / 256, 256, 0, stream>>>(bhist, S, m_u, s_u, m_p, s_p, perm, invp);
  // 2. CSR build: bucket hist -> scan -> 2-pass bucket sort (row_ptr + deg tables in pass B)
  k_bhist<<<BHB, 256, 0, stream>>>(rows, bhist);
  k_bscan<<<1, 512, 0, stream>>>(bhist, bbase, bcur, row_ptr);
  k_bucketA<<<(NNZ + ACHUNK - 1) / ACHUNK, 256, 0, stream>>>(rows, cols, bcur, tmp);
  k_bucketB<<<NB, 512, 0, stream>>>(bbase, tmp, ev, row_ptr, rsq, sqd);
  // 3. init w0 = rsqrt(deg) * x0 (fp16)
  k_inith<<<(ND / 4 + 255) / 256, 256, 0, stream>>>((const float4*)uemb, (const float4*)iemb,
                                                    rsq, (uint2*)x0h);
  // 4. three GCN layers in w-space (unweighted sums, uniform 1/deg scale)
  k_spmv<<<SPMVB, 256, 0, stream>>>(row_ptr, ev, x0h, x1h);
  k_spmv<<<SPMVB, 256, 0, stream>>>(row_ptr, ev, x1h, x2h);
  k_spmv<<<SPMVB, 256, 0, stream>>>(row_ptr, ev, x2h, x3h);
  // 5. batch gather (x = x0 + sqrt(deg)*(w1+w2+w3), batch rows only)
  k_gather<<<NGB, 256, 0, stream>>>((const float4*)uemb, (const float4*)iemb,
                                    (const uint2*)x1h, (const uint2*)x2h,
                                    (const uint2*)x3h, sqd, user, pos, neg,
                                    (float4*)ue, (float4*)pe, (float4*)ne, partR);
  // 6. mixes, scores, normalization (+ bf16 copies for MFMA)
  k_mixnorm<<<(BATCH * DIM) / 256, 256, 0, stream>>>(ue, pe, ne, beta_u, beta_i, perm,
                                                     An_u, Pn_u, An_p, Pn_p,
                                                     An_uh, Pn_uh, An_ph, Pn_ph,
                                                     pos_sc, neg_sc, nms);
  k_colpart<<<BATCH / 64, 256, 0, stream>>>(ue, pe, cu, cp, S);
  k_colnorm<<<1, 256, 0, stream>>>(beta_u, beta_i, partR, S, c_u, c_p);
  k_sims<<<(BATCH * DIM) / 256, 256, 0, stream>>>(An_u, Pn_u, An_p, Pn_p, c_u, c_p,
                                                  perm, invp,
                                                  dis_u, col_u, posd_u, cross_u,
                                                  dis_p, col_p, posd_p, cross_p);
  // 7. MFMA matmul + fixed-shift sumexp (user side, pos side)
  k_lse_mfma<<<512, 256, 0, stream>>>(An_uh, Pn_uh, s_u);
  k_lse_mfma<<<512, 256, 0, stream>>>(An_ph, Pn_ph, s_p);
  // 8. final combine
  k_final<<<1, 256, 0, stream>>>(m_u, s_u, dis_u, col_u, posd_u, cross_u,
                                 m_p, s_p, dis_p, col_p, posd_p, cross_p,
                                 pos_sc, neg_sc, nms, invp, S,
                                 (float*)d_out);
}